// Round 1
// baseline (314.965 us; speedup 1.0000x reference)
//
#include <hip/hip_runtime.h>

#define BB 16
#define TE 512
#define TD 64
#define HE 512

// ---------------------------------------------------------------------------
// Generic tiled fp32 GEMM: C[M,N] = A[M,K] * Bm[K,N], batched over blockIdx.z
// with per-batch element strides. BM=BN=64, BK=16, 256 threads, 4x4 per thread.
// Requires M%64==0, N%64==0, K%16==0 (true for all uses here).
// ---------------------------------------------------------------------------
__global__ __launch_bounds__(256)
void gemm_f32(const float* __restrict__ A, const float* __restrict__ Bm,
              float* __restrict__ C, int M, int N, int K,
              long long sAb, long long sBb, long long sCb)
{
    __shared__ float As[64][17];   // +1 pad: avoid 4-way bank conflict on column reads
    __shared__ float Bs[16][64];

    const int tid = threadIdx.x;
    const int tx  = tid & 15;
    const int ty  = tid >> 4;
    const int row0 = blockIdx.y * 64;
    const int col0 = blockIdx.x * 64;

    A  += (long long)blockIdx.z * sAb;
    Bm += (long long)blockIdx.z * sBb;
    C  += (long long)blockIdx.z * sCb;

    float acc[4][4] = {};

    for (int k0 = 0; k0 < K; k0 += 16) {
        // A tile: 64x16 floats, one float4 per thread
        {
            const int r = tid >> 2;
            const int c = (tid & 3) * 4;
            const float4 av = *(const float4*)&A[(long long)(row0 + r) * K + k0 + c];
            As[r][c + 0] = av.x; As[r][c + 1] = av.y;
            As[r][c + 2] = av.z; As[r][c + 3] = av.w;
        }
        // B tile: 16x64 floats, one float4 per thread
        {
            const int r = tid >> 4;
            const int c = (tid & 15) * 4;
            *(float4*)&Bs[r][c] = *(const float4*)&Bm[(long long)(k0 + r) * N + col0 + c];
        }
        __syncthreads();

#pragma unroll
        for (int kk = 0; kk < 16; ++kk) {
            const float a0 = As[ty * 4 + 0][kk];
            const float a1 = As[ty * 4 + 1][kk];
            const float a2 = As[ty * 4 + 2][kk];
            const float a3 = As[ty * 4 + 3][kk];
            const float4 b = *(const float4*)&Bs[kk][tx * 4];
            acc[0][0] += a0 * b.x; acc[0][1] += a0 * b.y; acc[0][2] += a0 * b.z; acc[0][3] += a0 * b.w;
            acc[1][0] += a1 * b.x; acc[1][1] += a1 * b.y; acc[1][2] += a1 * b.z; acc[1][3] += a1 * b.w;
            acc[2][0] += a2 * b.x; acc[2][1] += a2 * b.y; acc[2][2] += a2 * b.z; acc[2][3] += a2 * b.w;
            acc[3][0] += a3 * b.x; acc[3][1] += a3 * b.y; acc[3][2] += a3 * b.z; acc[3][3] += a3 * b.w;
        }
        __syncthreads();
    }

#pragma unroll
    for (int i = 0; i < 4; ++i) {
        float4 o;
        o.x = acc[i][0]; o.y = acc[i][1]; o.z = acc[i][2]; o.w = acc[i][3];
        *(float4*)&C[(long long)(row0 + ty * 4 + i) * N + col0 + tx * 4] = o;
    }
}

// ---------------------------------------------------------------------------
// tanh via exp2-based fast exp: tanh(x) = 1 - 2/(exp(2x)+1), clamped
// ---------------------------------------------------------------------------
__device__ __forceinline__ float tanh_fast(float x) {
    const float cx = fminf(fmaxf(x, -15.f), 15.f);
    const float e2 = __expf(2.f * cx);
    return 1.f - __fdividef(2.f, e2 + 1.f);
}

// ---------------------------------------------------------------------------
// Scores + softmax: one block per (b, d).
// e[b,d,t] = softmax_t( sum_h V[h] * tanh(Ws[b,t,h] + Uh[b,d,h]) )
// Per-lane Uh/V fragments (8 floats each) live in registers — invariant over t.
// ---------------------------------------------------------------------------
__global__ __launch_bounds__(256)
void scores_softmax(const float* __restrict__ Ws, const float* __restrict__ Uh,
                    const float* __restrict__ V, float* __restrict__ e_out)
{
    const int d   = blockIdx.x;
    const int b   = blockIdx.y;
    const int tid = threadIdx.x;
    const int lane = tid & 63;
    const int wave = tid >> 6;

    __shared__ float ebuf[TE];
    __shared__ float red[2][4];

    const float* uhrow = Uh + ((long long)b * TD + d) * HE + lane * 8;
    const float4 u0 = *(const float4*)(uhrow);
    const float4 u1 = *(const float4*)(uhrow + 4);
    const float4 v0 = *(const float4*)&V[lane * 8];
    const float4 v1 = *(const float4*)&V[lane * 8 + 4];

    const float* wsb = Ws + (long long)b * TE * HE;

    for (int t = wave; t < TE; t += 4) {
        const float* wrow = wsb + (long long)t * HE + lane * 8;
        const float4 w0 = *(const float4*)(wrow);
        const float4 w1 = *(const float4*)(wrow + 4);

        float s = v0.x * tanh_fast(w0.x + u0.x);
        s += v0.y * tanh_fast(w0.y + u0.y);
        s += v0.z * tanh_fast(w0.z + u0.z);
        s += v0.w * tanh_fast(w0.w + u0.w);
        s += v1.x * tanh_fast(w1.x + u1.x);
        s += v1.y * tanh_fast(w1.y + u1.y);
        s += v1.z * tanh_fast(w1.z + u1.z);
        s += v1.w * tanh_fast(w1.w + u1.w);

#pragma unroll
        for (int off = 32; off; off >>= 1) s += __shfl_xor(s, off);
        if (lane == 0) ebuf[t] = s;
    }
    __syncthreads();

    // softmax over ebuf[0..511]; each thread owns elements tid and tid+256
    const float e0 = ebuf[tid];
    const float e1 = ebuf[tid + 256];

    float m = fmaxf(e0, e1);
#pragma unroll
    for (int off = 32; off; off >>= 1) m = fmaxf(m, __shfl_xor(m, off));
    if (lane == 0) red[0][wave] = m;
    __syncthreads();
    m = fmaxf(fmaxf(red[0][0], red[0][1]), fmaxf(red[0][2], red[0][3]));

    const float p0 = __expf(e0 - m);
    const float p1 = __expf(e1 - m);
    float s = p0 + p1;
#pragma unroll
    for (int off = 32; off; off >>= 1) s += __shfl_xor(s, off);
    if (lane == 0) red[1][wave] = s;
    __syncthreads();
    s = red[1][0] + red[1][1] + red[1][2] + red[1][3];

    const float inv = __fdividef(1.f, s);
    float* eo = e_out + ((long long)b * TD + d) * TE;
    eo[tid]       = p0 * inv;
    eo[tid + 256] = p1 * inv;
}

// ---------------------------------------------------------------------------
extern "C" void kernel_launch(void* const* d_in, const int* in_sizes, int n_in,
                              void* d_out, int out_size, void* d_ws, size_t ws_size,
                              hipStream_t stream)
{
    const float* enc = (const float*)d_in[0];  // [B,TE,HE]
    const float* dec = (const float*)d_in[1];  // [B,TD,HD=HE]
    const float* Wa  = (const float*)d_in[2];  // [HE,HE]
    const float* Ua  = (const float*)d_in[3];  // [HD,HE]
    const float* Va  = (const float*)d_in[4];  // [HE,1] -> flat [HE]

    float* out   = (float*)d_out;
    float* c_out = out;                                   // [B,TD,HE]
    float* e_out = out + (size_t)BB * TD * HE;            // [B,TD,TE]

    // workspace: Ws [B,TE,HE] (16 MB) then Uh [B,TD,HE] (2 MB)
    float* Ws = (float*)d_ws;
    float* Uh = Ws + (size_t)BB * TE * HE;

    dim3 blk(256);

    // Ws = enc @ W_a   (M = B*TE = 8192, N = HE, K = HE)
    gemm_f32<<<dim3(HE / 64, (BB * TE) / 64, 1), blk, 0, stream>>>(
        enc, Wa, Ws, BB * TE, HE, HE, 0, 0, 0);

    // Uh = dec @ U_a   (M = B*TD = 1024)
    gemm_f32<<<dim3(HE / 64, (BB * TD) / 64, 1), blk, 0, stream>>>(
        dec, Ua, Uh, BB * TD, HE, HE, 0, 0, 0);

    // scores + softmax -> e_out
    scores_softmax<<<dim3(TD, BB), blk, 0, stream>>>(Ws, Uh, Va, e_out);

    // c[b] = e[b] @ enc[b]   (batched: M = TD = 64, N = HE, K = TE)
    gemm_f32<<<dim3(HE / 64, TD / 64, BB), blk, 0, stream>>>(
        e_out, enc, c_out, TD, HE, TE,
        (long long)TD * TE, (long long)TE * HE, (long long)TD * HE);
}

// Round 4
// 207.593 us; speedup vs baseline: 1.5172x; 1.5172x over previous
//
#include <hip/hip_runtime.h>

#define BB 16
#define TE 512
#define TD 64
#define HE 512

// 2*log2(e): folded into Ws/Uh GEMM epilogue so scores kernel can use raw v_exp (2^x)
#define PRESCALE 2.8853900817779268f

__device__ __forceinline__ float fexp2(float x) {
#if __has_builtin(__builtin_amdgcn_exp2f)
    return __builtin_amdgcn_exp2f(x);
#else
    return exp2f(x);
#endif
}
__device__ __forceinline__ float frcp(float x) {
#if __has_builtin(__builtin_amdgcn_rcpf)
    return __builtin_amdgcn_rcpf(x);
#else
    return __fdividef(1.f, x);
#endif
}

// ---------------------------------------------------------------------------
// Tiled fp32 GEMM: C = scale * (A @ B), batched over blockIdx.z.
// BM=BN=64, BK=16, 256 threads, 4x4 per thread. A-tile stored TRANSPOSED in
// LDS so the per-kk m-fragment is one ds_read_b128 (was 4 scalar reads).
// ---------------------------------------------------------------------------
__global__ __launch_bounds__(256)
void gemm_f32(const float* __restrict__ A, const float* __restrict__ Bm,
              float* __restrict__ C, int M, int N, int K,
              long long sAb, long long sBb, long long sCb, float scale)
{
    __shared__ float As[16][68];   // transposed: As[k][m], pad->2-way max on reads
    __shared__ float Bs[16][68];

    const int tid = threadIdx.x;
    const int tx  = tid & 15;
    const int ty  = tid >> 4;
    const int row0 = blockIdx.y * 64;
    const int col0 = blockIdx.x * 64;

    A  += (long long)blockIdx.z * sAb;
    Bm += (long long)blockIdx.z * sBb;
    C  += (long long)blockIdx.z * sCb;

    float acc[4][4] = {};

    for (int k0 = 0; k0 < K; k0 += 16) {
        {   // A tile 64x16 -> As[k][m] (transposed store)
            const int r = tid >> 2;
            const int c = (tid & 3) * 4;
            const float4 av = *(const float4*)&A[(long long)(row0 + r) * K + k0 + c];
            As[c + 0][r] = av.x; As[c + 1][r] = av.y;
            As[c + 2][r] = av.z; As[c + 3][r] = av.w;
        }
        {   // B tile 16x64
            const int r = tid >> 4;
            const int c = (tid & 15) * 4;
            *(float4*)&Bs[r][c] = *(const float4*)&Bm[(long long)(k0 + r) * N + col0 + c];
        }
        __syncthreads();

#pragma unroll
        for (int kk = 0; kk < 16; ++kk) {
            const float4 a = *(const float4*)&As[kk][ty * 4];
            const float4 b = *(const float4*)&Bs[kk][tx * 4];
            acc[0][0] += a.x * b.x; acc[0][1] += a.x * b.y; acc[0][2] += a.x * b.z; acc[0][3] += a.x * b.w;
            acc[1][0] += a.y * b.x; acc[1][1] += a.y * b.y; acc[1][2] += a.y * b.z; acc[1][3] += a.y * b.w;
            acc[2][0] += a.z * b.x; acc[2][1] += a.z * b.y; acc[2][2] += a.z * b.z; acc[2][3] += a.z * b.w;
            acc[3][0] += a.w * b.x; acc[3][1] += a.w * b.y; acc[3][2] += a.w * b.z; acc[3][3] += a.w * b.w;
        }
        __syncthreads();
    }

#pragma unroll
    for (int i = 0; i < 4; ++i) {
        float4 o;
        o.x = acc[i][0] * scale; o.y = acc[i][1] * scale;
        o.z = acc[i][2] * scale; o.w = acc[i][3] * scale;
        *(float4*)&C[(long long)(row0 + ty * 4 + i) * N + col0 + tx * 4] = o;
    }
}

// ---------------------------------------------------------------------------
// Raw scores: raw[b,d,t] = sum_h (-2 V[h]) * 1/(exp2(Ws'[b,t,h]+Uh'[b,d,h])+1)
// where Ws',Uh' are prescaled by 2*log2(e). softmax(raw) == reference e
// (the dropped sum(V) term is constant over t -> softmax-invariant).
// Block: 32-t x 32-d tile, all h. Thread: 4 t x 1 d accumulators, h serial.
// LDS tiles XOR-swizzled for conflict-free ds_read_b128.
// ---------------------------------------------------------------------------
__global__ __launch_bounds__(256)
void scores_raw(const float* __restrict__ Ws, const float* __restrict__ Uh,
                const float* __restrict__ V, float* __restrict__ e_raw)
{
    __shared__ float Ws_s[32][64];   // [t][h-chunk], col4 ^= (row>>2)&7
    __shared__ float Uh_s[32][64];   // [d][h-chunk], col4 ^= row&7
    __shared__ float Vr_s[HE];       // -2*V

    const int tid = threadIdx.x;
    const int tg  = tid & 7;     // t-group: t = tt0 + tg*4 + i
    const int dg  = tid >> 3;    // d = d0 + dg   (0..31)

    const int tt0 = blockIdx.x * 32;
    const int d0  = blockIdx.y * 32;
    const int b   = blockIdx.z;

    const float* Wsg = Ws + (long long)b * TE * HE;
    const float* Uhg = Uh + ((long long)b * TD + d0) * HE;

    // stage -2*V once
    if (tid < 128) {
        const float4 v = *(const float4*)&V[tid * 4];
        float4 o; o.x = -2.f * v.x; o.y = -2.f * v.y; o.z = -2.f * v.z; o.w = -2.f * v.w;
        *(float4*)&Vr_s[tid * 4] = o;
    }

    float acc[4] = {0.f, 0.f, 0.f, 0.f};
    const int wswz = tg & 7;
    const int uswz = dg & 7;

    for (int hc = 0; hc < HE; hc += 64) {
        __syncthreads();
#pragma unroll
        for (int k = 0; k < 2; ++k) {
            const int idx = tid + k * 256;
            const int r   = idx >> 4;
            const int c4  = idx & 15;
            const float4 wv = *(const float4*)&Wsg[(long long)(tt0 + r) * HE + hc + c4 * 4];
            *(float4*)&Ws_s[r][(c4 ^ ((r >> 2) & 7)) * 4] = wv;
            const float4 uv = *(const float4*)&Uhg[(long long)r * HE + hc + c4 * 4];
            *(float4*)&Uh_s[r][(c4 ^ (r & 7)) * 4] = uv;
        }
        __syncthreads();

#pragma unroll 4
        for (int hs = 0; hs < 64; hs += 4) {
            const int h4 = hs >> 2;
            const float4 vv = *(const float4*)&Vr_s[hc + hs];
            const float4 u  = *(const float4*)&Uh_s[dg][(h4 ^ uswz) * 4];
#pragma unroll
            for (int i = 0; i < 4; ++i) {
                const float4 w = *(const float4*)&Ws_s[tg * 4 + i][(h4 ^ wswz) * 4];
                acc[i] = fmaf(vv.x, frcp(fexp2(w.x + u.x) + 1.f), acc[i]);
                acc[i] = fmaf(vv.y, frcp(fexp2(w.y + u.y) + 1.f), acc[i]);
                acc[i] = fmaf(vv.z, frcp(fexp2(w.z + u.z) + 1.f), acc[i]);
                acc[i] = fmaf(vv.w, frcp(fexp2(w.w + u.w) + 1.f), acc[i]);
            }
        }
    }

    float4 o; o.x = acc[0]; o.y = acc[1]; o.z = acc[2]; o.w = acc[3];
    *(float4*)&e_raw[((long long)b * TD + d0 + dg) * TE + tt0 + tg * 4] = o;
}

// ---------------------------------------------------------------------------
// In-place row softmax over e[rows=B*TD][TE=512]. One wave per row.
// ---------------------------------------------------------------------------
__global__ __launch_bounds__(256)
void softmax_rows(float* __restrict__ e)
{
    const int lane = threadIdx.x & 63;
    const int wave = threadIdx.x >> 6;
    const long long row = blockIdx.x * 4 + wave;

    float* p = e + row * TE;
    float4 a = *(const float4*)&p[lane * 4];
    float4 c = *(const float4*)&p[lane * 4 + 256];

    float m = fmaxf(fmaxf(fmaxf(a.x, a.y), fmaxf(a.z, a.w)),
                    fmaxf(fmaxf(c.x, c.y), fmaxf(c.z, c.w)));
#pragma unroll
    for (int off = 32; off; off >>= 1) m = fmaxf(m, __shfl_xor(m, off));

    a.x = __expf(a.x - m); a.y = __expf(a.y - m); a.z = __expf(a.z - m); a.w = __expf(a.w - m);
    c.x = __expf(c.x - m); c.y = __expf(c.y - m); c.z = __expf(c.z - m); c.w = __expf(c.w - m);

    float s = (a.x + a.y + a.z + a.w) + (c.x + c.y + c.z + c.w);
#pragma unroll
    for (int off = 32; off; off >>= 1) s += __shfl_xor(s, off);

    const float inv = __fdividef(1.f, s);
    a.x *= inv; a.y *= inv; a.z *= inv; a.w *= inv;
    c.x *= inv; c.y *= inv; c.z *= inv; c.w *= inv;
    *(float4*)&p[lane * 4] = a;
    *(float4*)&p[lane * 4 + 256] = c;
}

// ---------------------------------------------------------------------------
extern "C" void kernel_launch(void* const* d_in, const int* in_sizes, int n_in,
                              void* d_out, int out_size, void* d_ws, size_t ws_size,
                              hipStream_t stream)
{
    const float* enc = (const float*)d_in[0];  // [B,TE,HE]
    const float* dec = (const float*)d_in[1];  // [B,TD,HD=HE]
    const float* Wa  = (const float*)d_in[2];  // [HE,HE]
    const float* Ua  = (const float*)d_in[3];  // [HD,HE]
    const float* Va  = (const float*)d_in[4];  // [HE,1] -> flat [HE]

    float* out   = (float*)d_out;
    float* c_out = out;                        // [B,TD,HE]
    float* e_out = out + (size_t)BB * TD * HE; // [B,TD,TE]

    float* Ws = (float*)d_ws;                  // [B,TE,HE] prescaled (16 MB)
    float* Uh = Ws + (size_t)BB * TE * HE;     // [B,TD,HE] prescaled (2 MB)

    dim3 blk(256);

    // Ws' = PRESCALE * enc @ W_a
    gemm_f32<<<dim3(HE / 64, (BB * TE) / 64, 1), blk, 0, stream>>>(
        enc, Wa, Ws, BB * TE, HE, HE, 0, 0, 0, PRESCALE);

    // Uh' = PRESCALE * dec @ U_a
    gemm_f32<<<dim3(HE / 64, (BB * TD) / 64, 1), blk, 0, stream>>>(
        dec, Ua, Uh, BB * TD, HE, HE, 0, 0, 0, PRESCALE);

    // raw scores -> e_out slot
    scores_raw<<<dim3(TE / 32, TD / 32, BB), blk, 0, stream>>>(Ws, Uh, Va, e_out);

    // softmax in place
    softmax_rows<<<dim3(BB * TD / 4), blk, 0, stream>>>(e_out);

    // c[b] = e[b] @ enc[b]
    gemm_f32<<<dim3(HE / 64, TD / 64, BB), blk, 0, stream>>>(
        e_out, enc, c_out, TD, HE, TE,
        (long long)TD * TE, (long long)TE * HE, (long long)TD * HE, 1.0f);
}

// Round 5
// 183.388 us; speedup vs baseline: 1.7175x; 1.1320x over previous
//
#include <hip/hip_runtime.h>
#include <hip/hip_bf16.h>

#define BB 16
#define TE 512
#define TD 64
#define HE 512

// 2*log2(e): folded into Ws/Uh GEMM epilogue so scores kernel can use raw v_exp (2^x)
#define PRESCALE 2.8853900817779268f

typedef __attribute__((ext_vector_type(8))) short bf16x8;
typedef __attribute__((ext_vector_type(4))) float f32x4;

__device__ __forceinline__ float fexp2(float x) {
#if __has_builtin(__builtin_amdgcn_exp2f)
    return __builtin_amdgcn_exp2f(x);
#else
    return exp2f(x);
#endif
}
__device__ __forceinline__ float frcp(float x) {
#if __has_builtin(__builtin_amdgcn_rcpf)
    return __builtin_amdgcn_rcpf(x);
#else
    return __fdividef(1.f, x);
#endif
}

// split fp32 -> bf16 hi + bf16 lo (x ~= hi + lo, ~2^-17 relative)
__device__ __forceinline__ void split2(float x, unsigned short& h, unsigned short& l) {
    __hip_bfloat16 hb = __float2bfloat16(x);
    h = *(unsigned short*)&hb;
    float r = x - __bfloat162float(hb);
    __hip_bfloat16 lb = __float2bfloat16(r);
    l = *(unsigned short*)&lb;
}

__device__ __forceinline__ void gload16(const unsigned short* g, void* l) {
    __builtin_amdgcn_global_load_lds(
        (const __attribute__((address_space(1))) unsigned int*)g,
        (__attribute__((address_space(3))) unsigned int*)l, 16, 0, 0);
}

// ---------------------------------------------------------------------------
// split_rm: X fp32 (flat, n = grid*1024 elems) -> H,L bf16 same layout
// ---------------------------------------------------------------------------
__global__ __launch_bounds__(256)
void split_rm(const float* __restrict__ X, unsigned short* __restrict__ H,
              unsigned short* __restrict__ L)
{
    const size_t i = ((size_t)blockIdx.x * 256 + threadIdx.x) * 4;
    const float4 v = *(const float4*)&X[i];
    ushort4 h, l;
    split2(v.x, h.x, l.x); split2(v.y, h.y, l.y);
    split2(v.z, h.z, l.z); split2(v.w, h.w, l.w);
    *(ushort4*)&H[i] = h;
    *(ushort4*)&L[i] = l;
}

// ---------------------------------------------------------------------------
// split_tr: X fp32 [z][R][C] -> H,L bf16 [z][C][R] (transposed per batch)
// 32x32 LDS tile transpose. R,C multiples of 32.
// ---------------------------------------------------------------------------
__global__ __launch_bounds__(256)
void split_tr(const float* __restrict__ X, unsigned short* __restrict__ H,
              unsigned short* __restrict__ L, int R, int C)
{
    __shared__ float t[32][33];
    const int tid = threadIdx.x;
    const int r0 = blockIdx.y * 32, c0 = blockIdx.x * 32;
    const size_t bo = (size_t)blockIdx.z * R * C;
    const int i = tid >> 3, j4 = (tid & 7) * 4;

    const float4 v = *(const float4*)&X[bo + (size_t)(r0 + i) * C + c0 + j4];
    t[i][j4 + 0] = v.x; t[i][j4 + 1] = v.y; t[i][j4 + 2] = v.z; t[i][j4 + 3] = v.w;
    __syncthreads();

    ushort4 h, l;
    split2(t[j4 + 0][i], h.x, l.x);
    split2(t[j4 + 1][i], h.y, l.y);
    split2(t[j4 + 2][i], h.z, l.z);
    split2(t[j4 + 3][i], h.w, l.w);
    const size_t o = bo + (size_t)(c0 + i) * R + r0 + j4;
    *(ushort4*)&H[o] = h;
    *(ushort4*)&L[o] = l;
}

// ---------------------------------------------------------------------------
// Split-bf16 MFMA GEMM: C = scale * (A @ B^T_layout), batched over blockIdx.z.
// A given as Ahi/Alo row-major [M][K]; B given TRANSPOSED as Bhi/Blo [N][K].
// A@B approximated by Ahi@Bhi + Ahi@Blo + Alo@Bhi (error ~2^-17 rel).
// Tile 128x128, BK=64, 256 thr = 4 waves (2x2), per wave 4x4 frags 16x16x32.
// LDS fragment-major: 16B block idx = kgroup*128 + row  (linear dest for
// global_load_lds; per-lane global source). M may be < 128 (loads clamped,
// stores guarded) as long as 2*M >= 128.
// ---------------------------------------------------------------------------
__global__ __launch_bounds__(256)
void gemm_mfma3(const unsigned short* __restrict__ Ahi, const unsigned short* __restrict__ Alo,
                const unsigned short* __restrict__ Bhi, const unsigned short* __restrict__ Blo,
                float* __restrict__ C, int M, int N, int K,
                long long sA, long long sB, long long sC, float scale)
{
    __shared__ char smem[65536];   // Ahi | Alo | Bhi | Blo, 16 KB each

    const int tid  = threadIdx.x;
    const int lane = tid & 63;
    const int wave = tid >> 6;
    const int wr = wave >> 1, wc = wave & 1;
    const int fr = lane & 15, fg = lane >> 4;
    const int row0 = blockIdx.y * 128;
    const int col0 = blockIdx.x * 128;

    Ahi += (size_t)blockIdx.z * sA; Alo += (size_t)blockIdx.z * sA;
    Bhi += (size_t)blockIdx.z * sB; Blo += (size_t)blockIdx.z * sB;
    C   += (size_t)blockIdx.z * sC;

    f32x4 acc[4][4];
#pragma unroll
    for (int mi = 0; mi < 4; ++mi)
#pragma unroll
        for (int ni = 0; ni < 4; ++ni)
            acc[mi][ni] = (f32x4){0.f, 0.f, 0.f, 0.f};

    for (int k0 = 0; k0 < K; k0 += 64) {
#pragma unroll
        for (int c = 0; c < 4; ++c) {
            const int bi  = (c * 4 + wave) * 64 + lane;
            const int g   = bi >> 7, idx = bi & 127;
            int mrow = row0 + idx; if (mrow >= M) mrow -= M;   // clamp (dup rows, unstored)
            const int ncol = col0 + idx;
            const size_t ao = (size_t)mrow * K + k0 + g * 8;
            const size_t bo = (size_t)ncol * K + k0 + g * 8;
            const int lb = (c * 4 + wave) * 1024;              // wave-uniform LDS base
            gload16(Ahi + ao, smem + lb);
            gload16(Alo + ao, smem + 16384 + lb);
            gload16(Bhi + bo, smem + 32768 + lb);
            gload16(Blo + bo, smem + 49152 + lb);
        }
        __syncthreads();

#pragma unroll
        for (int kk = 0; kk < 2; ++kk) {
            bf16x8 ah[4], al[4], bh[4], bl[4];
            const int gb = (kk * 4 + fg) << 7;
#pragma unroll
            for (int mi = 0; mi < 4; ++mi) {
                const int off = (gb + wr * 64 + mi * 16 + fr) * 16;
                ah[mi] = *(const bf16x8*)(smem + off);
                al[mi] = *(const bf16x8*)(smem + 16384 + off);
            }
#pragma unroll
            for (int ni = 0; ni < 4; ++ni) {
                const int off = (gb + wc * 64 + ni * 16 + fr) * 16;
                bh[ni] = *(const bf16x8*)(smem + 32768 + off);
                bl[ni] = *(const bf16x8*)(smem + 49152 + off);
            }
#pragma unroll
            for (int mi = 0; mi < 4; ++mi)
#pragma unroll
                for (int ni = 0; ni < 4; ++ni) {
                    acc[mi][ni] = __builtin_amdgcn_mfma_f32_16x16x32_bf16(ah[mi], bh[ni], acc[mi][ni], 0, 0, 0);
                    acc[mi][ni] = __builtin_amdgcn_mfma_f32_16x16x32_bf16(ah[mi], bl[ni], acc[mi][ni], 0, 0, 0);
                    acc[mi][ni] = __builtin_amdgcn_mfma_f32_16x16x32_bf16(al[mi], bh[ni], acc[mi][ni], 0, 0, 0);
                }
        }
        __syncthreads();
    }

    // epilogue: C/D layout col=lane&15, row=(lane>>4)*4+reg  [m89-verified]
#pragma unroll
    for (int mi = 0; mi < 4; ++mi) {
        const int rbase = row0 + wr * 64 + mi * 16 + fg * 4;
#pragma unroll
        for (int ni = 0; ni < 4; ++ni) {
            const int col = col0 + wc * 64 + ni * 16 + fr;
#pragma unroll
            for (int r = 0; r < 4; ++r) {
                const int row = rbase + r;
                if (row < M) C[(size_t)row * N + col] = acc[mi][ni][r] * scale;
            }
        }
    }
}

// ---------------------------------------------------------------------------
// Fallback fp32 GEMM (round-4 proven path, used if ws_size is too small)
// ---------------------------------------------------------------------------
__global__ __launch_bounds__(256)
void gemm_f32(const float* __restrict__ A, const float* __restrict__ Bm,
              float* __restrict__ C, int M, int N, int K,
              long long sAb, long long sBb, long long sCb, float scale)
{
    __shared__ float As[16][68];
    __shared__ float Bs[16][68];

    const int tid = threadIdx.x;
    const int tx  = tid & 15;
    const int ty  = tid >> 4;
    const int row0 = blockIdx.y * 64;
    const int col0 = blockIdx.x * 64;

    A  += (long long)blockIdx.z * sAb;
    Bm += (long long)blockIdx.z * sBb;
    C  += (long long)blockIdx.z * sCb;

    float acc[4][4] = {};

    for (int k0 = 0; k0 < K; k0 += 16) {
        {
            const int r = tid >> 2;
            const int c = (tid & 3) * 4;
            const float4 av = *(const float4*)&A[(long long)(row0 + r) * K + k0 + c];
            As[c + 0][r] = av.x; As[c + 1][r] = av.y;
            As[c + 2][r] = av.z; As[c + 3][r] = av.w;
        }
        {
            const int r = tid >> 4;
            const int c = (tid & 15) * 4;
            *(float4*)&Bs[r][c] = *(const float4*)&Bm[(long long)(k0 + r) * N + col0 + c];
        }
        __syncthreads();

#pragma unroll
        for (int kk = 0; kk < 16; ++kk) {
            const float4 a = *(const float4*)&As[kk][ty * 4];
            const float4 b = *(const float4*)&Bs[kk][tx * 4];
            acc[0][0] += a.x * b.x; acc[0][1] += a.x * b.y; acc[0][2] += a.x * b.z; acc[0][3] += a.x * b.w;
            acc[1][0] += a.y * b.x; acc[1][1] += a.y * b.y; acc[1][2] += a.y * b.z; acc[1][3] += a.y * b.w;
            acc[2][0] += a.z * b.x; acc[2][1] += a.z * b.y; acc[2][2] += a.z * b.z; acc[2][3] += a.z * b.w;
            acc[3][0] += a.w * b.x; acc[3][1] += a.w * b.y; acc[3][2] += a.w * b.z; acc[3][3] += a.w * b.w;
        }
        __syncthreads();
    }

#pragma unroll
    for (int i = 0; i < 4; ++i) {
        float4 o;
        o.x = acc[i][0] * scale; o.y = acc[i][1] * scale;
        o.z = acc[i][2] * scale; o.w = acc[i][3] * scale;
        *(float4*)&C[(long long)(row0 + ty * 4 + i) * N + col0 + tx * 4] = o;
    }
}

// ---------------------------------------------------------------------------
// Raw scores: raw[b,d,t] = sum_h (-2 V[h]) * 1/(exp2(Ws'[b,t,h]+Uh'[b,d,h])+1)
// (dropped sum(V) tanh-constant is softmax-invariant)
// ---------------------------------------------------------------------------
__global__ __launch_bounds__(256)
void scores_raw(const float* __restrict__ Ws, const float* __restrict__ Uh,
                const float* __restrict__ V, float* __restrict__ e_raw)
{
    __shared__ float Ws_s[32][64];
    __shared__ float Uh_s[32][64];
    __shared__ float Vr_s[HE];

    const int tid = threadIdx.x;
    const int tg  = tid & 7;
    const int dg  = tid >> 3;

    const int tt0 = blockIdx.x * 32;
    const int d0  = blockIdx.y * 32;
    const int b   = blockIdx.z;

    const float* Wsg = Ws + (long long)b * TE * HE;
    const float* Uhg = Uh + ((long long)b * TD + d0) * HE;

    if (tid < 128) {
        const float4 v = *(const float4*)&V[tid * 4];
        float4 o; o.x = -2.f * v.x; o.y = -2.f * v.y; o.z = -2.f * v.z; o.w = -2.f * v.w;
        *(float4*)&Vr_s[tid * 4] = o;
    }

    float acc[4] = {0.f, 0.f, 0.f, 0.f};
    const int wswz = tg & 7;
    const int uswz = dg & 7;

    for (int hc = 0; hc < HE; hc += 64) {
        __syncthreads();
#pragma unroll
        for (int k = 0; k < 2; ++k) {
            const int idx = tid + k * 256;
            const int r   = idx >> 4;
            const int c4  = idx & 15;
            const float4 wv = *(const float4*)&Wsg[(long long)(tt0 + r) * HE + hc + c4 * 4];
            *(float4*)&Ws_s[r][(c4 ^ ((r >> 2) & 7)) * 4] = wv;
            const float4 uv = *(const float4*)&Uhg[(long long)r * HE + hc + c4 * 4];
            *(float4*)&Uh_s[r][(c4 ^ (r & 7)) * 4] = uv;
        }
        __syncthreads();

#pragma unroll 4
        for (int hs = 0; hs < 64; hs += 4) {
            const int h4 = hs >> 2;
            const float4 vv = *(const float4*)&Vr_s[hc + hs];
            const float4 u  = *(const float4*)&Uh_s[dg][(h4 ^ uswz) * 4];
#pragma unroll
            for (int i = 0; i < 4; ++i) {
                const float4 w = *(const float4*)&Ws_s[tg * 4 + i][(h4 ^ wswz) * 4];
                acc[i] = fmaf(vv.x, frcp(fexp2(w.x + u.x) + 1.f), acc[i]);
                acc[i] = fmaf(vv.y, frcp(fexp2(w.y + u.y) + 1.f), acc[i]);
                acc[i] = fmaf(vv.z, frcp(fexp2(w.z + u.z) + 1.f), acc[i]);
                acc[i] = fmaf(vv.w, frcp(fexp2(w.w + u.w) + 1.f), acc[i]);
            }
        }
    }

    float4 o; o.x = acc[0]; o.y = acc[1]; o.z = acc[2]; o.w = acc[3];
    *(float4*)&e_raw[((long long)b * TD + d0 + dg) * TE + tt0 + tg * 4] = o;
}

// ---------------------------------------------------------------------------
// In-place row softmax; optionally emits bf16 hi/lo split of e for MFMA gemm3
// ---------------------------------------------------------------------------
__global__ __launch_bounds__(256)
void softmax_rows(float* __restrict__ e, unsigned short* __restrict__ H,
                  unsigned short* __restrict__ L)
{
    const int lane = threadIdx.x & 63;
    const int wave = threadIdx.x >> 6;
    const long long row = blockIdx.x * 4 + wave;

    float* p = e + row * TE;
    float4 a = *(const float4*)&p[lane * 4];
    float4 c = *(const float4*)&p[lane * 4 + 256];

    float m = fmaxf(fmaxf(fmaxf(a.x, a.y), fmaxf(a.z, a.w)),
                    fmaxf(fmaxf(c.x, c.y), fmaxf(c.z, c.w)));
#pragma unroll
    for (int off = 32; off; off >>= 1) m = fmaxf(m, __shfl_xor(m, off));

    a.x = __expf(a.x - m); a.y = __expf(a.y - m); a.z = __expf(a.z - m); a.w = __expf(a.w - m);
    c.x = __expf(c.x - m); c.y = __expf(c.y - m); c.z = __expf(c.z - m); c.w = __expf(c.w - m);

    float s = (a.x + a.y + a.z + a.w) + (c.x + c.y + c.z + c.w);
#pragma unroll
    for (int off = 32; off; off >>= 1) s += __shfl_xor(s, off);

    const float inv = __fdividef(1.f, s);
    a.x *= inv; a.y *= inv; a.z *= inv; a.w *= inv;
    c.x *= inv; c.y *= inv; c.z *= inv; c.w *= inv;
    *(float4*)&p[lane * 4] = a;
    *(float4*)&p[lane * 4 + 256] = c;

    if (H) {
        ushort4 h, l;
        split2(a.x, h.x, l.x); split2(a.y, h.y, l.y);
        split2(a.z, h.z, l.z); split2(a.w, h.w, l.w);
        *(ushort4*)&H[row * TE + lane * 4] = h;
        *(ushort4*)&L[row * TE + lane * 4] = l;
        split2(c.x, h.x, l.x); split2(c.y, h.y, l.y);
        split2(c.z, h.z, l.z); split2(c.w, h.w, l.w);
        *(ushort4*)&H[row * TE + lane * 4 + 256] = h;
        *(ushort4*)&L[row * TE + lane * 4 + 256] = l;
    }
}

// ---------------------------------------------------------------------------
extern "C" void kernel_launch(void* const* d_in, const int* in_sizes, int n_in,
                              void* d_out, int out_size, void* d_ws, size_t ws_size,
                              hipStream_t stream)
{
    const float* enc = (const float*)d_in[0];  // [B,TE,HE]
    const float* dec = (const float*)d_in[1];  // [B,TD,HD=HE]
    const float* Wa  = (const float*)d_in[2];  // [HE,HE]
    const float* Ua  = (const float*)d_in[3];  // [HD,HE]
    const float* Va  = (const float*)d_in[4];  // [HE,1] -> flat [HE]

    float* out   = (float*)d_out;
    float* c_out = out;                        // [B,TD,HE]
    float* e_out = out + (size_t)BB * TD * HE; // [B,TD,TE]

    char* w = (char*)d_ws;
    float* Ws  = (float*)(w);                                  // 16,777,216 B
    float* Uhp = (float*)(w + 16777216);                       //  2,097,152 B
    unsigned short* encAh = (unsigned short*)(w + 18874368);   //  8,388,608 B
    unsigned short* encAl = (unsigned short*)(w + 27262976);
    unsigned short* encTh = (unsigned short*)(w + 35651584);
    unsigned short* encTl = (unsigned short*)(w + 44040192);
    unsigned short* decAh = (unsigned short*)(w + 52428800);   //  1,048,576 B
    unsigned short* decAl = (unsigned short*)(w + 53477376);
    unsigned short* WaTh  = (unsigned short*)(w + 54525952);   //    524,288 B
    unsigned short* WaTl  = (unsigned short*)(w + 55050240);
    unsigned short* UaTh  = (unsigned short*)(w + 55574528);
    unsigned short* UaTl  = (unsigned short*)(w + 56098816);
    unsigned short* eh    = (unsigned short*)(w + 56623104);   //  1,048,576 B
    unsigned short* el    = (unsigned short*)(w + 57671680);
    const size_t REQUIRED = 58720256;

    dim3 blk(256);

    if (ws_size >= REQUIRED) {
        // --- split/transpose conversions ---
        split_rm<<<4096, blk, 0, stream>>>(enc, encAh, encAl);               // B*TE*HE
        split_rm<<<512, blk, 0, stream>>>(dec, decAh, decAl);                // B*TD*HE
        split_tr<<<dim3(16, 16, 1),  blk, 0, stream>>>(Wa,  WaTh, WaTl, HE, HE);
        split_tr<<<dim3(16, 16, 1),  blk, 0, stream>>>(Ua,  UaTh, UaTl, HE, HE);
        split_tr<<<dim3(16, 16, BB), blk, 0, stream>>>(enc, encTh, encTl, TE, HE);

        // Ws' = PRESCALE * enc @ W_a   (M=8192)
        gemm_mfma3<<<dim3(4, 64, 1), blk, 0, stream>>>(
            encAh, encAl, WaTh, WaTl, Ws, BB * TE, HE, HE, 0, 0, 0, PRESCALE);
        // Uh' = PRESCALE * dec @ U_a   (M=1024)
        gemm_mfma3<<<dim3(4, 8, 1), blk, 0, stream>>>(
            decAh, decAl, UaTh, UaTl, Uhp, BB * TD, HE, HE, 0, 0, 0, PRESCALE);

        scores_raw<<<dim3(TE / 32, TD / 32, BB), blk, 0, stream>>>(Ws, Uhp, Va, e_out);
        softmax_rows<<<dim3(BB * TD / 4), blk, 0, stream>>>(e_out, eh, el);

        // c[b] = e[b] @ enc[b]   (M=64 valid of 128-tile, batched)
        gemm_mfma3<<<dim3(4, 1, BB), blk, 0, stream>>>(
            eh, el, encTh, encTl, c_out, TD, HE, TE,
            (long long)TD * TE, (long long)TE * HE, (long long)TD * HE, 1.0f);
    } else {
        // --- fallback: proven fp32 path ---
        gemm_f32<<<dim3(HE / 64, (BB * TE) / 64, 1), blk, 0, stream>>>(
            enc, Wa, Ws, BB * TE, HE, HE, 0, 0, 0, PRESCALE);
        gemm_f32<<<dim3(HE / 64, (BB * TD) / 64, 1), blk, 0, stream>>>(
            dec, Ua, Uhp, BB * TD, HE, HE, 0, 0, 0, PRESCALE);
        scores_raw<<<dim3(TE / 32, TD / 32, BB), blk, 0, stream>>>(Ws, Uhp, Va, e_out);
        softmax_rows<<<dim3(BB * TD / 4), blk, 0, stream>>>(e_out, nullptr, nullptr);
        gemm_f32<<<dim3(HE / 64, TD / 64, BB), blk, 0, stream>>>(
            e_out, enc, c_out, TD, HE, TE,
            (long long)TD * TE, (long long)TE * HE, (long long)TD * HE, 1.0f);
    }
}

// Round 7
// 176.403 us; speedup vs baseline: 1.7855x; 1.0396x over previous
//
#include <hip/hip_runtime.h>
#include <hip/hip_bf16.h>

#define BB 16
#define TE 512
#define TD 64
#define HE 512

// 2*log2(e): folded into Ws/Uh GEMM epilogue (with exp2) so the scores inner
// loop needs no exp at all: tanh term via 1/(Ew*Eu+1).
#define PRESCALE 2.8853900817779268f

typedef __attribute__((ext_vector_type(8))) short bf16x8;
typedef __attribute__((ext_vector_type(4))) float f32x4;

__device__ __forceinline__ float fexp2(float x) {
#if __has_builtin(__builtin_amdgcn_exp2f)
    return __builtin_amdgcn_exp2f(x);
#else
    return exp2f(x);
#endif
}
__device__ __forceinline__ float frcp(float x) {
#if __has_builtin(__builtin_amdgcn_rcpf)
    return __builtin_amdgcn_rcpf(x);
#else
    return __fdividef(1.f, x);
#endif
}

// split fp32 -> bf16 hi + bf16 lo (x ~= hi + lo, ~2^-17 relative)
__device__ __forceinline__ void split2(float x, unsigned short& h, unsigned short& l) {
    __hip_bfloat16 hb = __float2bfloat16(x);
    h = *(unsigned short*)&hb;
    float r = x - __bfloat162float(hb);
    __hip_bfloat16 lb = __float2bfloat16(r);
    l = *(unsigned short*)&lb;
}

__device__ __forceinline__ void gload16(const unsigned short* g, void* l) {
    __builtin_amdgcn_global_load_lds(
        (const __attribute__((address_space(1))) unsigned int*)g,
        (__attribute__((address_space(3))) unsigned int*)l, 16, 0, 0);
}

// ---------------------------------------------------------------------------
// split_rm: X fp32 (flat, grid*1024 elems) -> H,L bf16 same layout
// ---------------------------------------------------------------------------
__global__ __launch_bounds__(256)
void split_rm(const float* __restrict__ X, unsigned short* __restrict__ H,
              unsigned short* __restrict__ L)
{
    const size_t i = ((size_t)blockIdx.x * 256 + threadIdx.x) * 4;
    const float4 v = *(const float4*)&X[i];
    ushort4 h, l;
    split2(v.x, h.x, l.x); split2(v.y, h.y, l.y);
    split2(v.z, h.z, l.z); split2(v.w, h.w, l.w);
    *(ushort4*)&H[i] = h;
    *(ushort4*)&L[i] = l;
}

// ---------------------------------------------------------------------------
// split_tr: X fp32 [z][R][C] -> H,L bf16 [z][C][R] (transposed per batch)
// ---------------------------------------------------------------------------
__global__ __launch_bounds__(256)
void split_tr(const float* __restrict__ X, unsigned short* __restrict__ H,
              unsigned short* __restrict__ L, int R, int C)
{
    __shared__ float t[32][33];
    const int tid = threadIdx.x;
    const int r0 = blockIdx.y * 32, c0 = blockIdx.x * 32;
    const size_t bo = (size_t)blockIdx.z * R * C;
    const int i = tid >> 3, j4 = (tid & 7) * 4;

    const float4 v = *(const float4*)&X[bo + (size_t)(r0 + i) * C + c0 + j4];
    t[i][j4 + 0] = v.x; t[i][j4 + 1] = v.y; t[i][j4 + 2] = v.z; t[i][j4 + 3] = v.w;
    __syncthreads();

    ushort4 h, l;
    split2(t[j4 + 0][i], h.x, l.x);
    split2(t[j4 + 1][i], h.y, l.y);
    split2(t[j4 + 2][i], h.z, l.z);
    split2(t[j4 + 3][i], h.w, l.w);
    const size_t o = bo + (size_t)(c0 + i) * R + r0 + j4;
    *(ushort4*)&H[o] = h;
    *(ushort4*)&L[o] = l;
}

// ---------------------------------------------------------------------------
// split_enc: one read of X produces BOTH row-major (Ah/Al) and transposed
// (Th/Tl) bf16 hi/lo splits. Saves a full 16 MB re-read of enc.
// ---------------------------------------------------------------------------
__global__ __launch_bounds__(256)
void split_enc(const float* __restrict__ X,
               unsigned short* __restrict__ Ah, unsigned short* __restrict__ Al,
               unsigned short* __restrict__ Th, unsigned short* __restrict__ Tl,
               int R, int C)
{
    __shared__ float t[32][33];
    const int tid = threadIdx.x;
    const int r0 = blockIdx.y * 32, c0 = blockIdx.x * 32;
    const size_t bo = (size_t)blockIdx.z * R * C;
    const int i = tid >> 3, j4 = (tid & 7) * 4;

    const size_t irm = bo + (size_t)(r0 + i) * C + c0 + j4;
    const float4 v = *(const float4*)&X[irm];

    ushort4 h, l;
    split2(v.x, h.x, l.x); split2(v.y, h.y, l.y);
    split2(v.z, h.z, l.z); split2(v.w, h.w, l.w);
    *(ushort4*)&Ah[irm] = h;
    *(ushort4*)&Al[irm] = l;

    t[i][j4 + 0] = v.x; t[i][j4 + 1] = v.y; t[i][j4 + 2] = v.z; t[i][j4 + 3] = v.w;
    __syncthreads();

    split2(t[j4 + 0][i], h.x, l.x);
    split2(t[j4 + 1][i], h.y, l.y);
    split2(t[j4 + 2][i], h.z, l.z);
    split2(t[j4 + 3][i], h.w, l.w);
    const size_t o = bo + (size_t)(c0 + i) * R + r0 + j4;
    *(ushort4*)&Th[o] = h;
    *(ushort4*)&Tl[o] = l;
}

// ---------------------------------------------------------------------------
// Split-bf16 MFMA GEMM: C = f(scale * (A @ B^T_layout)), f = id or exp2.
// A: Ahi/Alo row-major [M][K]; B TRANSPOSED: Bhi/Blo [N][K].
// A@B ~= Ahi@Bhi + Ahi@Blo + Alo@Bhi. Tile 128x128, BK=64, 4 waves (2x2).
// ---------------------------------------------------------------------------
__global__ __launch_bounds__(256)
void gemm_mfma3(const unsigned short* __restrict__ Ahi, const unsigned short* __restrict__ Alo,
                const unsigned short* __restrict__ Bhi, const unsigned short* __restrict__ Blo,
                float* __restrict__ C, int M, int N, int K,
                long long sA, long long sB, long long sC, float scale, int emode)
{
    __shared__ char smem[65536];   // Ahi | Alo | Bhi | Blo, 16 KB each

    const int tid  = threadIdx.x;
    const int lane = tid & 63;
    const int wave = tid >> 6;
    const int wr = wave >> 1, wc = wave & 1;
    const int fr = lane & 15, fg = lane >> 4;
    const int row0 = blockIdx.y * 128;
    const int col0 = blockIdx.x * 128;

    Ahi += (size_t)blockIdx.z * sA; Alo += (size_t)blockIdx.z * sA;
    Bhi += (size_t)blockIdx.z * sB; Blo += (size_t)blockIdx.z * sB;
    C   += (size_t)blockIdx.z * sC;

    f32x4 acc[4][4];
#pragma unroll
    for (int mi = 0; mi < 4; ++mi)
#pragma unroll
        for (int ni = 0; ni < 4; ++ni)
            acc[mi][ni] = (f32x4){0.f, 0.f, 0.f, 0.f};

    for (int k0 = 0; k0 < K; k0 += 64) {
#pragma unroll
        for (int c = 0; c < 4; ++c) {
            const int bi  = (c * 4 + wave) * 64 + lane;
            const int g   = bi >> 7, idx = bi & 127;
            int mrow = row0 + idx; if (mrow >= M) mrow -= M;   // clamp (dup rows, unstored)
            const int ncol = col0 + idx;
            const size_t ao = (size_t)mrow * K + k0 + g * 8;
            const size_t bo = (size_t)ncol * K + k0 + g * 8;
            const int lb = (c * 4 + wave) * 1024;              // wave-uniform LDS base
            gload16(Ahi + ao, smem + lb);
            gload16(Alo + ao, smem + 16384 + lb);
            gload16(Bhi + bo, smem + 32768 + lb);
            gload16(Blo + bo, smem + 49152 + lb);
        }
        __syncthreads();

#pragma unroll
        for (int kk = 0; kk < 2; ++kk) {
            bf16x8 ah[4], al[4], bh[4], bl[4];
            const int gb = (kk * 4 + fg) << 7;
#pragma unroll
            for (int mi = 0; mi < 4; ++mi) {
                const int off = (gb + wr * 64 + mi * 16 + fr) * 16;
                ah[mi] = *(const bf16x8*)(smem + off);
                al[mi] = *(const bf16x8*)(smem + 16384 + off);
            }
#pragma unroll
            for (int ni = 0; ni < 4; ++ni) {
                const int off = (gb + wc * 64 + ni * 16 + fr) * 16;
                bh[ni] = *(const bf16x8*)(smem + 32768 + off);
                bl[ni] = *(const bf16x8*)(smem + 49152 + off);
            }
#pragma unroll
            for (int mi = 0; mi < 4; ++mi)
#pragma unroll
                for (int ni = 0; ni < 4; ++ni) {
                    acc[mi][ni] = __builtin_amdgcn_mfma_f32_16x16x32_bf16(ah[mi], bh[ni], acc[mi][ni], 0, 0, 0);
                    acc[mi][ni] = __builtin_amdgcn_mfma_f32_16x16x32_bf16(ah[mi], bl[ni], acc[mi][ni], 0, 0, 0);
                    acc[mi][ni] = __builtin_amdgcn_mfma_f32_16x16x32_bf16(al[mi], bh[ni], acc[mi][ni], 0, 0, 0);
                }
        }
        __syncthreads();
    }

    // epilogue: C/D layout col=lane&15, row=(lane>>4)*4+reg  [m89-verified]
#pragma unroll
    for (int mi = 0; mi < 4; ++mi) {
        const int rbase = row0 + wr * 64 + mi * 16 + fg * 4;
#pragma unroll
        for (int ni = 0; ni < 4; ++ni) {
            const int col = col0 + wc * 64 + ni * 16 + fr;
#pragma unroll
            for (int r = 0; r < 4; ++r) {
                const int row = rbase + r;
                if (row < M) {
                    float val = acc[mi][ni][r] * scale;
                    if (emode) val = fexp2(val);
                    C[(size_t)row * N + col] = val;
                }
            }
        }
    }
}

// ---------------------------------------------------------------------------
// Fallback fp32 GEMM (proven path, used if ws_size is too small)
// ---------------------------------------------------------------------------
__global__ __launch_bounds__(256)
void gemm_f32(const float* __restrict__ A, const float* __restrict__ Bm,
              float* __restrict__ C, int M, int N, int K,
              long long sAb, long long sBb, long long sCb, float scale, int emode)
{
    __shared__ float As[16][68];
    __shared__ float Bs[16][68];

    const int tid = threadIdx.x;
    const int tx  = tid & 15;
    const int ty  = tid >> 4;
    const int row0 = blockIdx.y * 64;
    const int col0 = blockIdx.x * 64;

    A  += (long long)blockIdx.z * sAb;
    Bm += (long long)blockIdx.z * sBb;
    C  += (long long)blockIdx.z * sCb;

    float acc[4][4] = {};

    for (int k0 = 0; k0 < K; k0 += 16) {
        {
            const int r = tid >> 2;
            const int c = (tid & 3) * 4;
            const float4 av = *(const float4*)&A[(long long)(row0 + r) * K + k0 + c];
            As[c + 0][r] = av.x; As[c + 1][r] = av.y;
            As[c + 2][r] = av.z; As[c + 3][r] = av.w;
        }
        {
            const int r = tid >> 4;
            const int c = (tid & 15) * 4;
            *(float4*)&Bs[r][c] = *(const float4*)&Bm[(long long)(k0 + r) * N + col0 + c];
        }
        __syncthreads();

#pragma unroll
        for (int kk = 0; kk < 16; ++kk) {
            const float4 a = *(const float4*)&As[kk][ty * 4];
            const float4 b = *(const float4*)&Bs[kk][tx * 4];
            acc[0][0] += a.x * b.x; acc[0][1] += a.x * b.y; acc[0][2] += a.x * b.z; acc[0][3] += a.x * b.w;
            acc[1][0] += a.y * b.x; acc[1][1] += a.y * b.y; acc[1][2] += a.y * b.z; acc[1][3] += a.y * b.w;
            acc[2][0] += a.z * b.x; acc[2][1] += a.z * b.y; acc[2][2] += a.z * b.z; acc[2][3] += a.z * b.w;
            acc[3][0] += a.w * b.x; acc[3][1] += a.w * b.y; acc[3][2] += a.w * b.z; acc[3][3] += a.w * b.w;
        }
        __syncthreads();
    }

#pragma unroll
    for (int i = 0; i < 4; ++i) {
        float4 o;
        o.x = acc[i][0] * scale; o.y = acc[i][1] * scale;
        o.z = acc[i][2] * scale; o.w = acc[i][3] * scale;
        if (emode) { o.x = fexp2(o.x); o.y = fexp2(o.y); o.z = fexp2(o.z); o.w = fexp2(o.w); }
        *(float4*)&C[(long long)(row0 + ty * 4 + i) * N + col0 + tx * 4] = o;
    }
}

// ---------------------------------------------------------------------------
// Raw scores: raw[b,d,t] = sum_h (-2 V[h]) / (Ew[b,t,h]*Eu[b,d,h] + 1)
// where Ew = exp2(PRESCALE*Ws), Eu = exp2(PRESCALE*Uh) (computed in GEMM
// epilogues). 3 VALU ops/elem, 1 transcendental. Double-buffered LDS staging:
// next chunk's global loads issued before compute, ds_write + 1 barrier after.
// ---------------------------------------------------------------------------
__global__ __launch_bounds__(256)
void scores_raw(const float* __restrict__ Ew, const float* __restrict__ Eu,
                const float* __restrict__ V, float* __restrict__ e_raw)
{
    __shared__ float Ws_s[2][32][64];   // [buf][t][h], col4 ^= (row>>2)&7
    __shared__ float Uh_s[2][32][64];   // [buf][d][h], col4 ^= row&7
    __shared__ float Vr_s[HE];          // -2*V

    const int tid = threadIdx.x;
    const int tg  = tid & 7;     // 4 t each
    const int dg  = tid >> 3;    // d offset 0..31

    const int tt0 = blockIdx.x * 32;
    const int d0  = blockIdx.y * 32;
    const int b   = blockIdx.z;

    const float* Wsg = Ew + (long long)b * TE * HE;
    const float* Uhg = Eu + ((long long)b * TD + d0) * HE;

    if (tid < 128) {
        const float4 v = *(const float4*)&V[tid * 4];
        float4 o; o.x = -2.f * v.x; o.y = -2.f * v.y; o.z = -2.f * v.z; o.w = -2.f * v.w;
        *(float4*)&Vr_s[tid * 4] = o;
    }

    // staging geometry: 2 float4 per thread per matrix per chunk
    int srow[2], scol[2];
#pragma unroll
    for (int k = 0; k < 2; ++k) {
        const int idx = tid + k * 256;
        srow[k] = idx >> 4;
        scol[k] = idx & 15;
    }

    float4 wreg[2], ureg[2];
#pragma unroll
    for (int k = 0; k < 2; ++k) {
        wreg[k] = *(const float4*)&Wsg[(long long)(tt0 + srow[k]) * HE + scol[k] * 4];
        ureg[k] = *(const float4*)&Uhg[(long long)srow[k] * HE + scol[k] * 4];
    }
#pragma unroll
    for (int k = 0; k < 2; ++k) {
        *(float4*)&Ws_s[0][srow[k]][(scol[k] ^ ((srow[k] >> 2) & 7)) * 4] = wreg[k];
        *(float4*)&Uh_s[0][srow[k]][(scol[k] ^ (srow[k] & 7)) * 4] = ureg[k];
    }
    __syncthreads();

    float acc[4] = {0.f, 0.f, 0.f, 0.f};
    const int wswz = tg & 7;
    const int uswz = dg & 7;

    for (int hc = 0; hc < HE / 64; ++hc) {
        const int cur = hc & 1;
        if (hc < HE / 64 - 1) {
            const int hb = (hc + 1) * 64;
#pragma unroll
            for (int k = 0; k < 2; ++k) {
                wreg[k] = *(const float4*)&Wsg[(long long)(tt0 + srow[k]) * HE + hb + scol[k] * 4];
                ureg[k] = *(const float4*)&Uhg[(long long)srow[k] * HE + hb + scol[k] * 4];
            }
        }
#pragma unroll
        for (int hs = 0; hs < 16; ++hs) {
            const float4 vv = *(const float4*)&Vr_s[hc * 64 + hs * 4];
            const float4 u  = *(const float4*)&Uh_s[cur][dg][(hs ^ uswz) * 4];
#pragma unroll
            for (int i = 0; i < 4; ++i) {
                const float4 w = *(const float4*)&Ws_s[cur][tg * 4 + i][(hs ^ wswz) * 4];
                acc[i] = fmaf(vv.x, frcp(fmaf(w.x, u.x, 1.f)), acc[i]);
                acc[i] = fmaf(vv.y, frcp(fmaf(w.y, u.y, 1.f)), acc[i]);
                acc[i] = fmaf(vv.z, frcp(fmaf(w.z, u.z, 1.f)), acc[i]);
                acc[i] = fmaf(vv.w, frcp(fmaf(w.w, u.w, 1.f)), acc[i]);
            }
        }
        if (hc < HE / 64 - 1) {
            const int nxt = cur ^ 1;
#pragma unroll
            for (int k = 0; k < 2; ++k) {
                *(float4*)&Ws_s[nxt][srow[k]][(scol[k] ^ ((srow[k] >> 2) & 7)) * 4] = wreg[k];
                *(float4*)&Uh_s[nxt][srow[k]][(scol[k] ^ (srow[k] & 7)) * 4] = ureg[k];
            }
            __syncthreads();
        }
    }

    float4 o; o.x = acc[0]; o.y = acc[1]; o.z = acc[2]; o.w = acc[3];
    *(float4*)&e_raw[((long long)b * TD + d0 + dg) * TE + tt0 + tg * 4] = o;
}

// ---------------------------------------------------------------------------
// In-place row softmax; optionally emits bf16 hi/lo split of e for MFMA gemm3
// ---------------------------------------------------------------------------
__global__ __launch_bounds__(256)
void softmax_rows(float* __restrict__ e, unsigned short* __restrict__ H,
                  unsigned short* __restrict__ L)
{
    const int lane = threadIdx.x & 63;
    const int wave = threadIdx.x >> 6;
    const long long row = blockIdx.x * 4 + wave;

    float* p = e + row * TE;
    float4 a = *(const float4*)&p[lane * 4];
    float4 c = *(const float4*)&p[lane * 4 + 256];

    float m = fmaxf(fmaxf(fmaxf(a.x, a.y), fmaxf(a.z, a.w)),
                    fmaxf(fmaxf(c.x, c.y), fmaxf(c.z, c.w)));
#pragma unroll
    for (int off = 32; off; off >>= 1) m = fmaxf(m, __shfl_xor(m, off));

    a.x = __expf(a.x - m); a.y = __expf(a.y - m); a.z = __expf(a.z - m); a.w = __expf(a.w - m);
    c.x = __expf(c.x - m); c.y = __expf(c.y - m); c.z = __expf(c.z - m); c.w = __expf(c.w - m);

    float s = (a.x + a.y + a.z + a.w) + (c.x + c.y + c.z + c.w);
#pragma unroll
    for (int off = 32; off; off >>= 1) s += __shfl_xor(s, off);

    const float inv = __fdividef(1.f, s);
    a.x *= inv; a.y *= inv; a.z *= inv; a.w *= inv;
    c.x *= inv; c.y *= inv; c.z *= inv; c.w *= inv;
    *(float4*)&p[lane * 4] = a;
    *(float4*)&p[lane * 4 + 256] = c;

    if (H) {
        ushort4 h, l;
        split2(a.x, h.x, l.x); split2(a.y, h.y, l.y);
        split2(a.z, h.z, l.z); split2(a.w, h.w, l.w);
        *(ushort4*)&H[row * TE + lane * 4] = h;
        *(ushort4*)&L[row * TE + lane * 4] = l;
        split2(c.x, h.x, l.x); split2(c.y, h.y, l.y);
        split2(c.z, h.z, l.z); split2(c.w, h.w, l.w);
        *(ushort4*)&H[row * TE + lane * 4 + 256] = h;
        *(ushort4*)&L[row * TE + lane * 4 + 256] = l;
    }
}

// ---------------------------------------------------------------------------
extern "C" void kernel_launch(void* const* d_in, const int* in_sizes, int n_in,
                              void* d_out, int out_size, void* d_ws, size_t ws_size,
                              hipStream_t stream)
{
    const float* enc = (const float*)d_in[0];  // [B,TE,HE]
    const float* dec = (const float*)d_in[1];  // [B,TD,HD=HE]
    const float* Wa  = (const float*)d_in[2];  // [HE,HE]
    const float* Ua  = (const float*)d_in[3];  // [HD,HE]
    const float* Va  = (const float*)d_in[4];  // [HE,1] -> flat [HE]

    float* out   = (float*)d_out;
    float* c_out = out;                        // [B,TD,HE]
    float* e_out = out + (size_t)BB * TD * HE; // [B,TD,TE]

    char* w = (char*)d_ws;
    float* Ew  = (float*)(w);                                  // 16,777,216 B (exp2'd Ws)
    float* Eu  = (float*)(w + 16777216);                       //  2,097,152 B (exp2'd Uh)
    unsigned short* encAh = (unsigned short*)(w + 18874368);   //  8,388,608 B
    unsigned short* encAl = (unsigned short*)(w + 27262976);
    unsigned short* encTh = (unsigned short*)(w + 35651584);
    unsigned short* encTl = (unsigned short*)(w + 44040192);
    unsigned short* decAh = (unsigned short*)(w + 52428800);   //  1,048,576 B
    unsigned short* decAl = (unsigned short*)(w + 53477376);
    unsigned short* WaTh  = (unsigned short*)(w + 54525952);   //    524,288 B
    unsigned short* WaTl  = (unsigned short*)(w + 55050240);
    unsigned short* UaTh  = (unsigned short*)(w + 55574528);
    unsigned short* UaTl  = (unsigned short*)(w + 56098816);
    unsigned short* eh    = (unsigned short*)(w + 56623104);   //  1,048,576 B
    unsigned short* el    = (unsigned short*)(w + 57671680);
    const size_t REQUIRED = 58720256;

    dim3 blk(256);

    if (ws_size >= REQUIRED) {
        // --- split/transpose conversions ---
        split_enc<<<dim3(16, 16, BB), blk, 0, stream>>>(enc, encAh, encAl, encTh, encTl, TE, HE);
        split_rm<<<512, blk, 0, stream>>>(dec, decAh, decAl);
        split_tr<<<dim3(16, 16, 1), blk, 0, stream>>>(Wa, WaTh, WaTl, HE, HE);
        split_tr<<<dim3(16, 16, 1), blk, 0, stream>>>(Ua, UaTh, UaTl, HE, HE);

        // Ew = exp2(PRESCALE * enc @ W_a)   (M=8192)
        gemm_mfma3<<<dim3(4, 64, 1), blk, 0, stream>>>(
            encAh, encAl, WaTh, WaTl, Ew, BB * TE, HE, HE, 0, 0, 0, PRESCALE, 1);
        // Eu = exp2(PRESCALE * dec @ U_a)   (M=1024)
        gemm_mfma3<<<dim3(4, 8, 1), blk, 0, stream>>>(
            decAh, decAl, UaTh, UaTl, Eu, BB * TD, HE, HE, 0, 0, 0, PRESCALE, 1);

        scores_raw<<<dim3(TE / 32, TD / 32, BB), blk, 0, stream>>>(Ew, Eu, Va, e_out);
        softmax_rows<<<dim3(BB * TD / 4), blk, 0, stream>>>(e_out, eh, el);

        // c[b] = e[b] @ enc[b]   (M=64 valid of 128-tile, batched)
        gemm_mfma3<<<dim3(4, 1, BB), blk, 0, stream>>>(
            eh, el, encTh, encTl, c_out, TD, HE, TE,
            (long long)TD * TE, (long long)TE * HE, (long long)TD * HE, 1.0f, 0);
    } else {
        // --- fallback: fp32 path ---
        gemm_f32<<<dim3(HE / 64, (BB * TE) / 64, 1), blk, 0, stream>>>(
            enc, Wa, Ew, BB * TE, HE, HE, 0, 0, 0, PRESCALE, 1);
        gemm_f32<<<dim3(HE / 64, (BB * TD) / 64, 1), blk, 0, stream>>>(
            dec, Ua, Eu, BB * TD, HE, HE, 0, 0, 0, PRESCALE, 1);
        scores_raw<<<dim3(TE / 32, TD / 32, BB), blk, 0, stream>>>(Ew, Eu, Va, e_out);
        softmax_rows<<<dim3(BB * TD / 4), blk, 0, stream>>>(e_out, nullptr, nullptr);
        gemm_f32<<<dim3(HE / 64, TD / 64, BB), blk, 0, stream>>>(
            e_out, enc, c_out, TD, HE, TE,
            (long long)TD * TE, (long long)TE * HE, (long long)TD * HE, 1.0f, 0);
    }
}

// Round 9
// 160.302 us; speedup vs baseline: 1.9648x; 1.1004x over previous
//
#include <hip/hip_runtime.h>
#include <hip/hip_bf16.h>

#define BB 16
#define TE 512
#define TD 64
#define HE 512

// 2*log2(e): folded into Ws/Uh GEMM epilogue (with exp2) so the scores inner
// loop needs no exp at all: tanh term via 1/(Ew*Eu+1).
#define PRESCALE 2.8853900817779268f

typedef __attribute__((ext_vector_type(8))) short bf16x8;
typedef __attribute__((ext_vector_type(4))) float f32x4;

__device__ __forceinline__ float fexp2(float x) {
#if __has_builtin(__builtin_amdgcn_exp2f)
    return __builtin_amdgcn_exp2f(x);
#else
    return exp2f(x);
#endif
}
__device__ __forceinline__ float frcp(float x) {
#if __has_builtin(__builtin_amdgcn_rcpf)
    return __builtin_amdgcn_rcpf(x);
#else
    return __fdividef(1.f, x);
#endif
}

// split fp32 -> bf16 hi + bf16 lo (x ~= hi + lo, ~2^-17 relative)
__device__ __forceinline__ void split2(float x, unsigned short& h, unsigned short& l) {
    __hip_bfloat16 hb = __float2bfloat16(x);
    h = *(unsigned short*)&hb;
    float r = x - __bfloat162float(hb);
    __hip_bfloat16 lb = __float2bfloat16(r);
    l = *(unsigned short*)&lb;
}

__device__ __forceinline__ void gload16(const unsigned short* g, void* l) {
    __builtin_amdgcn_global_load_lds(
        (const __attribute__((address_space(1))) unsigned int*)g,
        (__attribute__((address_space(3))) unsigned int*)l, 16, 0, 0);
}

// ---------------------------------------------------------------------------
// split_rm: X fp32 (flat, grid*1024 elems) -> H,L bf16 same layout
// ---------------------------------------------------------------------------
__global__ __launch_bounds__(256)
void split_rm(const float* __restrict__ X, unsigned short* __restrict__ H,
              unsigned short* __restrict__ L)
{
    const size_t i = ((size_t)blockIdx.x * 256 + threadIdx.x) * 4;
    const float4 v = *(const float4*)&X[i];
    ushort4 h, l;
    split2(v.x, h.x, l.x); split2(v.y, h.y, l.y);
    split2(v.z, h.z, l.z); split2(v.w, h.w, l.w);
    *(ushort4*)&H[i] = h;
    *(ushort4*)&L[i] = l;
}

// ---------------------------------------------------------------------------
// split_tr: X fp32 [z][R][C] -> H,L bf16 [z][C][R] (transposed per batch)
// ---------------------------------------------------------------------------
__global__ __launch_bounds__(256)
void split_tr(const float* __restrict__ X, unsigned short* __restrict__ H,
              unsigned short* __restrict__ L, int R, int C)
{
    __shared__ float t[32][33];
    const int tid = threadIdx.x;
    const int r0 = blockIdx.y * 32, c0 = blockIdx.x * 32;
    const size_t bo = (size_t)blockIdx.z * R * C;
    const int i = tid >> 3, j4 = (tid & 7) * 4;

    const float4 v = *(const float4*)&X[bo + (size_t)(r0 + i) * C + c0 + j4];
    t[i][j4 + 0] = v.x; t[i][j4 + 1] = v.y; t[i][j4 + 2] = v.z; t[i][j4 + 3] = v.w;
    __syncthreads();

    ushort4 h, l;
    split2(t[j4 + 0][i], h.x, l.x);
    split2(t[j4 + 1][i], h.y, l.y);
    split2(t[j4 + 2][i], h.z, l.z);
    split2(t[j4 + 3][i], h.w, l.w);
    const size_t o = bo + (size_t)(c0 + i) * R + r0 + j4;
    *(ushort4*)&H[o] = h;
    *(ushort4*)&L[o] = l;
}

// ---------------------------------------------------------------------------
// split_enc: one read of X produces BOTH row-major (Ah/Al) and transposed
// (Th/Tl) bf16 hi/lo splits. Saves a full 16 MB re-read of enc.
// ---------------------------------------------------------------------------
__global__ __launch_bounds__(256)
void split_enc(const float* __restrict__ X,
               unsigned short* __restrict__ Ah, unsigned short* __restrict__ Al,
               unsigned short* __restrict__ Th, unsigned short* __restrict__ Tl,
               int R, int C)
{
    __shared__ float t[32][33];
    const int tid = threadIdx.x;
    const int r0 = blockIdx.y * 32, c0 = blockIdx.x * 32;
    const size_t bo = (size_t)blockIdx.z * R * C;
    const int i = tid >> 3, j4 = (tid & 7) * 4;

    const size_t irm = bo + (size_t)(r0 + i) * C + c0 + j4;
    const float4 v = *(const float4*)&X[irm];

    ushort4 h, l;
    split2(v.x, h.x, l.x); split2(v.y, h.y, l.y);
    split2(v.z, h.z, l.z); split2(v.w, h.w, l.w);
    *(ushort4*)&Ah[irm] = h;
    *(ushort4*)&Al[irm] = l;

    t[i][j4 + 0] = v.x; t[i][j4 + 1] = v.y; t[i][j4 + 2] = v.z; t[i][j4 + 3] = v.w;
    __syncthreads();

    split2(t[j4 + 0][i], h.x, l.x);
    split2(t[j4 + 1][i], h.y, l.y);
    split2(t[j4 + 2][i], h.z, l.z);
    split2(t[j4 + 3][i], h.w, l.w);
    const size_t o = bo + (size_t)(c0 + i) * R + r0 + j4;
    *(ushort4*)&Th[o] = h;
    *(ushort4*)&Tl[o] = l;
}

// ---------------------------------------------------------------------------
// Split-bf16 MFMA GEMM: C = f(scale * (A @ B^T_layout)), f = id or exp2.
// A: Ahi/Alo row-major [M][K]; B TRANSPOSED: Bhi/Blo [N][K].
// A@B ~= Ahi@Bhi + Ahi@Blo + Alo@Bhi. Tile 128x128, BK=64, 4 waves (2x2).
// ---------------------------------------------------------------------------
__global__ __launch_bounds__(256)
void gemm_mfma3(const unsigned short* __restrict__ Ahi, const unsigned short* __restrict__ Alo,
                const unsigned short* __restrict__ Bhi, const unsigned short* __restrict__ Blo,
                float* __restrict__ C, int M, int N, int K,
                long long sA, long long sB, long long sC, float scale, int emode)
{
    __shared__ char smem[65536];   // Ahi | Alo | Bhi | Blo, 16 KB each

    const int tid  = threadIdx.x;
    const int lane = tid & 63;
    const int wave = tid >> 6;
    const int wr = wave >> 1, wc = wave & 1;
    const int fr = lane & 15, fg = lane >> 4;
    const int row0 = blockIdx.y * 128;
    const int col0 = blockIdx.x * 128;

    Ahi += (size_t)blockIdx.z * sA; Alo += (size_t)blockIdx.z * sA;
    Bhi += (size_t)blockIdx.z * sB; Blo += (size_t)blockIdx.z * sB;
    C   += (size_t)blockIdx.z * sC;

    f32x4 acc[4][4];
#pragma unroll
    for (int mi = 0; mi < 4; ++mi)
#pragma unroll
        for (int ni = 0; ni < 4; ++ni)
            acc[mi][ni] = (f32x4){0.f, 0.f, 0.f, 0.f};

    for (int k0 = 0; k0 < K; k0 += 64) {
#pragma unroll
        for (int c = 0; c < 4; ++c) {
            const int bi  = (c * 4 + wave) * 64 + lane;
            const int g   = bi >> 7, idx = bi & 127;
            int mrow = row0 + idx; if (mrow >= M) mrow -= M;   // clamp (dup rows, unstored)
            const int ncol = col0 + idx;
            const size_t ao = (size_t)mrow * K + k0 + g * 8;
            const size_t bo = (size_t)ncol * K + k0 + g * 8;
            const int lb = (c * 4 + wave) * 1024;              // wave-uniform LDS base
            gload16(Ahi + ao, smem + lb);
            gload16(Alo + ao, smem + 16384 + lb);
            gload16(Bhi + bo, smem + 32768 + lb);
            gload16(Blo + bo, smem + 49152 + lb);
        }
        __syncthreads();

#pragma unroll
        for (int kk = 0; kk < 2; ++kk) {
            bf16x8 ah[4], al[4], bh[4], bl[4];
            const int gb = (kk * 4 + fg) << 7;
#pragma unroll
            for (int mi = 0; mi < 4; ++mi) {
                const int off = (gb + wr * 64 + mi * 16 + fr) * 16;
                ah[mi] = *(const bf16x8*)(smem + off);
                al[mi] = *(const bf16x8*)(smem + 16384 + off);
            }
#pragma unroll
            for (int ni = 0; ni < 4; ++ni) {
                const int off = (gb + wc * 64 + ni * 16 + fr) * 16;
                bh[ni] = *(const bf16x8*)(smem + 32768 + off);
                bl[ni] = *(const bf16x8*)(smem + 49152 + off);
            }
#pragma unroll
            for (int mi = 0; mi < 4; ++mi)
#pragma unroll
                for (int ni = 0; ni < 4; ++ni) {
                    acc[mi][ni] = __builtin_amdgcn_mfma_f32_16x16x32_bf16(ah[mi], bh[ni], acc[mi][ni], 0, 0, 0);
                    acc[mi][ni] = __builtin_amdgcn_mfma_f32_16x16x32_bf16(ah[mi], bl[ni], acc[mi][ni], 0, 0, 0);
                    acc[mi][ni] = __builtin_amdgcn_mfma_f32_16x16x32_bf16(al[mi], bh[ni], acc[mi][ni], 0, 0, 0);
                }
        }
        __syncthreads();
    }

    // epilogue: C/D layout col=lane&15, row=(lane>>4)*4+reg  [m89-verified]
#pragma unroll
    for (int mi = 0; mi < 4; ++mi) {
        const int rbase = row0 + wr * 64 + mi * 16 + fg * 4;
#pragma unroll
        for (int ni = 0; ni < 4; ++ni) {
            const int col = col0 + wc * 64 + ni * 16 + fr;
#pragma unroll
            for (int r = 0; r < 4; ++r) {
                const int row = rbase + r;
                if (row < M) {
                    float val = acc[mi][ni][r] * scale;
                    if (emode) val = fexp2(val);
                    C[(size_t)row * N + col] = val;
                }
            }
        }
    }
}

// ---------------------------------------------------------------------------
// Fallback fp32 GEMM (proven path, used if ws_size is too small)
// ---------------------------------------------------------------------------
__global__ __launch_bounds__(256)
void gemm_f32(const float* __restrict__ A, const float* __restrict__ Bm,
              float* __restrict__ C, int M, int N, int K,
              long long sAb, long long sBb, long long sCb, float scale, int emode)
{
    __shared__ float As[16][68];
    __shared__ float Bs[16][68];

    const int tid = threadIdx.x;
    const int tx  = tid & 15;
    const int ty  = tid >> 4;
    const int row0 = blockIdx.y * 64;
    const int col0 = blockIdx.x * 64;

    A  += (long long)blockIdx.z * sAb;
    Bm += (long long)blockIdx.z * sBb;
    C  += (long long)blockIdx.z * sCb;

    float acc[4][4] = {};

    for (int k0 = 0; k0 < K; k0 += 16) {
        {
            const int r = tid >> 2;
            const int c = (tid & 3) * 4;
            const float4 av = *(const float4*)&A[(long long)(row0 + r) * K + k0 + c];
            As[c + 0][r] = av.x; As[c + 1][r] = av.y;
            As[c + 2][r] = av.z; As[c + 3][r] = av.w;
        }
        {
            const int r = tid >> 4;
            const int c = (tid & 15) * 4;
            *(float4*)&Bs[r][c] = *(const float4*)&Bm[(long long)(k0 + r) * N + col0 + c];
        }
        __syncthreads();

#pragma unroll
        for (int kk = 0; kk < 16; ++kk) {
            const float4 a = *(const float4*)&As[kk][ty * 4];
            const float4 b = *(const float4*)&Bs[kk][tx * 4];
            acc[0][0] += a.x * b.x; acc[0][1] += a.x * b.y; acc[0][2] += a.x * b.z; acc[0][3] += a.x * b.w;
            acc[1][0] += a.y * b.x; acc[1][1] += a.y * b.y; acc[1][2] += a.y * b.z; acc[1][3] += a.y * b.w;
            acc[2][0] += a.z * b.x; acc[2][1] += a.z * b.y; acc[2][2] += a.z * b.z; acc[2][3] += a.z * b.w;
            acc[3][0] += a.w * b.x; acc[3][1] += a.w * b.y; acc[3][2] += a.w * b.z; acc[3][3] += a.w * b.w;
        }
        __syncthreads();
    }

#pragma unroll
    for (int i = 0; i < 4; ++i) {
        float4 o;
        o.x = acc[i][0] * scale; o.y = acc[i][1] * scale;
        o.z = acc[i][2] * scale; o.w = acc[i][3] * scale;
        if (emode) { o.x = fexp2(o.x); o.y = fexp2(o.y); o.z = fexp2(o.z); o.w = fexp2(o.w); }
        *(float4*)&C[(long long)(row0 + ty * 4 + i) * N + col0 + tx * 4] = o;
    }
}

// ---------------------------------------------------------------------------
// Raw scores: raw[b,d,t] = sum_h (-2 V[h]) / (Ew[b,t,h]*Eu[b,d,h] + 1)
// where Ew = exp2(PRESCALE*Ws), Eu = exp2(PRESCALE*Uh) from GEMM epilogues.
// 3 VALU ops/elem, 1 transcendental. SINGLE-buffered round-4 structure
// (VGPR ~32, proven 0 bank conflicts) — round-7's reg-prefetch dbuf blew
// VGPR to 212 and collapsed occupancy; reverted.
// ---------------------------------------------------------------------------
__global__ __launch_bounds__(256)
void scores_raw(const float* __restrict__ Ew, const float* __restrict__ Eu,
                const float* __restrict__ V, float* __restrict__ e_raw)
{
    __shared__ float Ws_s[32][64];   // [t][h-chunk], col4 ^= (row>>2)&7
    __shared__ float Uh_s[32][64];   // [d][h-chunk], col4 ^= row&7
    __shared__ float Vr_s[HE];       // -2*V

    const int tid = threadIdx.x;
    const int tg  = tid & 7;     // t-group: t = tt0 + tg*4 + i
    const int dg  = tid >> 3;    // d = d0 + dg   (0..31)

    const int tt0 = blockIdx.x * 32;
    const int d0  = blockIdx.y * 32;
    const int b   = blockIdx.z;

    const float* Wsg = Ew + (long long)b * TE * HE;
    const float* Uhg = Eu + ((long long)b * TD + d0) * HE;

    if (tid < 128) {
        const float4 v = *(const float4*)&V[tid * 4];
        float4 o; o.x = -2.f * v.x; o.y = -2.f * v.y; o.z = -2.f * v.z; o.w = -2.f * v.w;
        *(float4*)&Vr_s[tid * 4] = o;
    }

    float acc[4] = {0.f, 0.f, 0.f, 0.f};
    const int wswz = tg & 7;
    const int uswz = dg & 7;

    for (int hc = 0; hc < HE; hc += 64) {
        __syncthreads();
#pragma unroll
        for (int k = 0; k < 2; ++k) {
            const int idx = tid + k * 256;
            const int r   = idx >> 4;
            const int c4  = idx & 15;
            const float4 wv = *(const float4*)&Wsg[(long long)(tt0 + r) * HE + hc + c4 * 4];
            *(float4*)&Ws_s[r][(c4 ^ ((r >> 2) & 7)) * 4] = wv;
            const float4 uv = *(const float4*)&Uhg[(long long)r * HE + hc + c4 * 4];
            *(float4*)&Uh_s[r][(c4 ^ (r & 7)) * 4] = uv;
        }
        __syncthreads();

#pragma unroll 4
        for (int hs = 0; hs < 64; hs += 4) {
            const int h4 = hs >> 2;
            const float4 vv = *(const float4*)&Vr_s[hc + hs];
            const float4 u  = *(const float4*)&Uh_s[dg][(h4 ^ uswz) * 4];
#pragma unroll
            for (int i = 0; i < 4; ++i) {
                const float4 w = *(const float4*)&Ws_s[tg * 4 + i][(h4 ^ wswz) * 4];
                acc[i] = fmaf(vv.x, frcp(fmaf(w.x, u.x, 1.f)), acc[i]);
                acc[i] = fmaf(vv.y, frcp(fmaf(w.y, u.y, 1.f)), acc[i]);
                acc[i] = fmaf(vv.z, frcp(fmaf(w.z, u.z, 1.f)), acc[i]);
                acc[i] = fmaf(vv.w, frcp(fmaf(w.w, u.w, 1.f)), acc[i]);
            }
        }
    }

    float4 o; o.x = acc[0]; o.y = acc[1]; o.z = acc[2]; o.w = acc[3];
    *(float4*)&e_raw[((long long)b * TD + d0 + dg) * TE + tt0 + tg * 4] = o;
}

// ---------------------------------------------------------------------------
// In-place row softmax; optionally emits bf16 hi/lo split of e for MFMA gemm3
// ---------------------------------------------------------------------------
__global__ __launch_bounds__(256)
void softmax_rows(float* __restrict__ e, unsigned short* __restrict__ H,
                  unsigned short* __restrict__ L)
{
    const int lane = threadIdx.x & 63;
    const int wave = threadIdx.x >> 6;
    const long long row = blockIdx.x * 4 + wave;

    float* p = e + row * TE;
    float4 a = *(const float4*)&p[lane * 4];
    float4 c = *(const float4*)&p[lane * 4 + 256];

    float m = fmaxf(fmaxf(fmaxf(a.x, a.y), fmaxf(a.z, a.w)),
                    fmaxf(fmaxf(c.x, c.y), fmaxf(c.z, c.w)));
#pragma unroll
    for (int off = 32; off; off >>= 1) m = fmaxf(m, __shfl_xor(m, off));

    a.x = __expf(a.x - m); a.y = __expf(a.y - m); a.z = __expf(a.z - m); a.w = __expf(a.w - m);
    c.x = __expf(c.x - m); c.y = __expf(c.y - m); c.z = __expf(c.z - m); c.w = __expf(c.w - m);

    float s = (a.x + a.y + a.z + a.w) + (c.x + c.y + c.z + c.w);
#pragma unroll
    for (int off = 32; off; off >>= 1) s += __shfl_xor(s, off);

    const float inv = __fdividef(1.f, s);
    a.x *= inv; a.y *= inv; a.z *= inv; a.w *= inv;
    c.x *= inv; c.y *= inv; c.z *= inv; c.w *= inv;
    *(float4*)&p[lane * 4] = a;
    *(float4*)&p[lane * 4 + 256] = c;

    if (H) {
        ushort4 h, l;
        split2(a.x, h.x, l.x); split2(a.y, h.y, l.y);
        split2(a.z, h.z, l.z); split2(a.w, h.w, l.w);
        *(ushort4*)&H[row * TE + lane * 4] = h;
        *(ushort4*)&L[row * TE + lane * 4] = l;
        split2(c.x, h.x, l.x); split2(c.y, h.y, l.y);
        split2(c.z, h.z, l.z); split2(c.w, h.w, l.w);
        *(ushort4*)&H[row * TE + lane * 4 + 256] = h;
        *(ushort4*)&L[row * TE + lane * 4 + 256] = l;
    }
}

// ---------------------------------------------------------------------------
extern "C" void kernel_launch(void* const* d_in, const int* in_sizes, int n_in,
                              void* d_out, int out_size, void* d_ws, size_t ws_size,
                              hipStream_t stream)
{
    const float* enc = (const float*)d_in[0];  // [B,TE,HE]
    const float* dec = (const float*)d_in[1];  // [B,TD,HD=HE]
    const float* Wa  = (const float*)d_in[2];  // [HE,HE]
    const float* Ua  = (const float*)d_in[3];  // [HD,HE]
    const float* Va  = (const float*)d_in[4];  // [HE,1] -> flat [HE]

    float* out   = (float*)d_out;
    float* c_out = out;                        // [B,TD,HE]
    float* e_out = out + (size_t)BB * TD * HE; // [B,TD,TE]

    char* w = (char*)d_ws;
    float* Ew  = (float*)(w);                                  // 16,777,216 B (exp2'd Ws)
    float* Eu  = (float*)(w + 16777216);                       //  2,097,152 B (exp2'd Uh)
    unsigned short* encAh = (unsigned short*)(w + 18874368);   //  8,388,608 B
    unsigned short* encAl = (unsigned short*)(w + 27262976);
    unsigned short* encTh = (unsigned short*)(w + 35651584);
    unsigned short* encTl = (unsigned short*)(w + 44040192);
    unsigned short* decAh = (unsigned short*)(w + 52428800);   //  1,048,576 B
    unsigned short* decAl = (unsigned short*)(w + 53477376);
    unsigned short* WaTh  = (unsigned short*)(w + 54525952);   //    524,288 B
    unsigned short* WaTl  = (unsigned short*)(w + 55050240);
    unsigned short* UaTh  = (unsigned short*)(w + 55574528);
    unsigned short* UaTl  = (unsigned short*)(w + 56098816);
    unsigned short* eh    = (unsigned short*)(w + 56623104);   //  1,048,576 B
    unsigned short* el    = (unsigned short*)(w + 57671680);
    const size_t REQUIRED = 58720256;

    dim3 blk(256);

    if (ws_size >= REQUIRED) {
        // --- split/transpose conversions ---
        split_enc<<<dim3(16, 16, BB), blk, 0, stream>>>(enc, encAh, encAl, encTh, encTl, TE, HE);
        split_rm<<<512, blk, 0, stream>>>(dec, decAh, decAl);
        split_tr<<<dim3(16, 16, 1), blk, 0, stream>>>(Wa, WaTh, WaTl, HE, HE);
        split_tr<<<dim3(16, 16, 1), blk, 0, stream>>>(Ua, UaTh, UaTl, HE, HE);

        // Ew = exp2(PRESCALE * enc @ W_a)   (M=8192)
        gemm_mfma3<<<dim3(4, 64, 1), blk, 0, stream>>>(
            encAh, encAl, WaTh, WaTl, Ew, BB * TE, HE, HE, 0, 0, 0, PRESCALE, 1);
        // Eu = exp2(PRESCALE * dec @ U_a)   (M=1024)
        gemm_mfma3<<<dim3(4, 8, 1), blk, 0, stream>>>(
            decAh, decAl, UaTh, UaTl, Eu, BB * TD, HE, HE, 0, 0, 0, PRESCALE, 1);

        scores_raw<<<dim3(TE / 32, TD / 32, BB), blk, 0, stream>>>(Ew, Eu, Va, e_out);
        softmax_rows<<<dim3(BB * TD / 4), blk, 0, stream>>>(e_out, eh, el);

        // c[b] = e[b] @ enc[b]   (M=64 valid of 128-tile, batched)
        gemm_mfma3<<<dim3(4, 1, BB), blk, 0, stream>>>(
            eh, el, encTh, encTl, c_out, TD, HE, TE,
            (long long)TD * TE, (long long)TE * HE, (long long)TD * HE, 1.0f, 0);
    } else {
        // --- fallback: fp32 path ---
        gemm_f32<<<dim3(HE / 64, (BB * TE) / 64, 1), blk, 0, stream>>>(
            enc, Wa, Ew, BB * TE, HE, HE, 0, 0, 0, PRESCALE, 1);
        gemm_f32<<<dim3(HE / 64, (BB * TD) / 64, 1), blk, 0, stream>>>(
            dec, Ua, Eu, BB * TD, HE, HE, 0, 0, 0, PRESCALE, 1);
        scores_raw<<<dim3(TE / 32, TD / 32, BB), blk, 0, stream>>>(Ew, Eu, Va, e_out);
        softmax_rows<<<dim3(BB * TD / 4), blk, 0, stream>>>(e_out, nullptr, nullptr);
        gemm_f32<<<dim3(HE / 64, TD / 64, BB), blk, 0, stream>>>(
            e_out, enc, c_out, TD, HE, TE,
            (long long)TD * TE, (long long)TE * HE, (long long)TD * HE, 1.0f, 0);
    }
}

// Round 10
// 124.574 us; speedup vs baseline: 2.5283x; 1.2868x over previous
//
#include <hip/hip_runtime.h>
#include <hip/hip_bf16.h>

#define BB 16
#define TE 512
#define TD 64
#define HE 512

// 2*log2(e): folded into Ws/Uh GEMM epilogue (with exp2) so the scores inner
// loop needs no exp at all: tanh term via 1/(Ew*Eu+1).
#define PRESCALE 2.8853900817779268f

typedef __attribute__((ext_vector_type(8))) short bf16x8;
typedef __attribute__((ext_vector_type(4))) float f32x4;

__device__ __forceinline__ float fexp2(float x) {
#if __has_builtin(__builtin_amdgcn_exp2f)
    return __builtin_amdgcn_exp2f(x);
#else
    return exp2f(x);
#endif
}
__device__ __forceinline__ float frcp(float x) {
#if __has_builtin(__builtin_amdgcn_rcpf)
    return __builtin_amdgcn_rcpf(x);
#else
    return __fdividef(1.f, x);
#endif
}

// split fp32 -> bf16 hi + bf16 lo (x ~= hi + lo, ~2^-17 relative)
__device__ __forceinline__ void split2(float x, unsigned short& h, unsigned short& l) {
    __hip_bfloat16 hb = __float2bfloat16(x);
    h = *(unsigned short*)&hb;
    float r = x - __bfloat162float(hb);
    __hip_bfloat16 lb = __float2bfloat16(r);
    l = *(unsigned short*)&lb;
}

__device__ __forceinline__ void gload16(const unsigned short* g, void* l) {
    __builtin_amdgcn_global_load_lds(
        (const __attribute__((address_space(1))) unsigned int*)g,
        (__attribute__((address_space(3))) unsigned int*)l, 16, 0, 0);
}

// ===========================================================================
// k8-interleaved operand layout:  Xp[s][r][j] = X[r][s*8+j],  s = k/8, j = k%8
// flat index = (s*R + r)*8 + j.  Makes gemm staging loads fully coalesced:
// one global_load_lds = 64 lanes * 16B contiguous (consecutive rows, fixed s).
// ===========================================================================

// ---------------------------------------------------------------------------
// split_rm_k8: X fp32 row-major [M][K] -> A-k8 hi/lo
// ---------------------------------------------------------------------------
__global__ __launch_bounds__(256)
void split_rm_k8(const float* __restrict__ X, unsigned short* __restrict__ H,
                 unsigned short* __restrict__ L, int M, int K)
{
    const size_t i = ((size_t)blockIdx.x * 256 + threadIdx.x) * 4;
    const int m = (int)(i / K);
    const int k = (int)(i % K);
    const float4 v = *(const float4*)&X[i];
    ushort4 h, l;
    split2(v.x, h.x, l.x); split2(v.y, h.y, l.y);
    split2(v.z, h.z, l.z); split2(v.w, h.w, l.w);
    const size_t o = ((size_t)(k >> 3) * M + m) * 8 + (k & 7);
    *(ushort4*)&H[o] = h;
    *(ushort4*)&L[o] = l;
}

// ---------------------------------------------------------------------------
// split_tr_k8: X fp32 [z][R][C] -> B-k8 of X^T per batch:
// B[n=c][k=r], dst = z*R*C + ((r>>3)*C + c)*8 + (r&7)
// ---------------------------------------------------------------------------
__global__ __launch_bounds__(256)
void split_tr_k8(const float* __restrict__ X, unsigned short* __restrict__ H,
                 unsigned short* __restrict__ L, int R, int C)
{
    __shared__ float t[32][33];
    const int tid = threadIdx.x;
    const int r0 = blockIdx.y * 32, c0 = blockIdx.x * 32;
    const size_t bo = (size_t)blockIdx.z * R * C;
    const int i = tid >> 3, j4 = (tid & 7) * 4;

    const float4 v = *(const float4*)&X[bo + (size_t)(r0 + i) * C + c0 + j4];
    t[i][j4 + 0] = v.x; t[i][j4 + 1] = v.y; t[i][j4 + 2] = v.z; t[i][j4 + 3] = v.w;
    __syncthreads();

    ushort4 h, l;
    split2(t[j4 + 0][i], h.x, l.x);
    split2(t[j4 + 1][i], h.y, l.y);
    split2(t[j4 + 2][i], h.z, l.z);
    split2(t[j4 + 3][i], h.w, l.w);
    const int r = r0 + j4;                 // k index of B
    const size_t o = bo + ((size_t)(r >> 3) * C + c0 + i) * 8 + (r & 7);
    *(ushort4*)&H[o] = h;
    *(ushort4*)&L[o] = l;
}

// ---------------------------------------------------------------------------
// split_enc_k8: enc [B][TE][HE] -> (a) A-k8 over fused rows m=b*TE+t (K=HE),
// (b) per-batch B-k8 of enc^T (B[n=h][k=t], K=TE).
// ---------------------------------------------------------------------------
__global__ __launch_bounds__(256)
void split_enc_k8(const float* __restrict__ X,
                  unsigned short* __restrict__ Ah, unsigned short* __restrict__ Al,
                  unsigned short* __restrict__ Th, unsigned short* __restrict__ Tl)
{
    __shared__ float t[32][33];
    const int tid = threadIdx.x;
    const int r0 = blockIdx.y * 32, c0 = blockIdx.x * 32;   // r: t, c: h
    const int b  = blockIdx.z;
    const size_t bo = (size_t)b * TE * HE;
    const int i = tid >> 3, j4 = (tid & 7) * 4;

    const float4 v = *(const float4*)&X[bo + (size_t)(r0 + i) * HE + c0 + j4];

    ushort4 h, l;
    split2(v.x, h.x, l.x); split2(v.y, h.y, l.y);
    split2(v.z, h.z, l.z); split2(v.w, h.w, l.w);
    {   // A-k8: m = b*TE + r0+i, k = c0+j4
        const int m = b * TE + r0 + i;
        const int k = c0 + j4;
        const size_t o = ((size_t)(k >> 3) * (BB * TE) + m) * 8 + (k & 7);
        *(ushort4*)&Ah[o] = h;
        *(ushort4*)&Al[o] = l;
    }

    t[i][j4 + 0] = v.x; t[i][j4 + 1] = v.y; t[i][j4 + 2] = v.z; t[i][j4 + 3] = v.w;
    __syncthreads();

    split2(t[j4 + 0][i], h.x, l.x);
    split2(t[j4 + 1][i], h.y, l.y);
    split2(t[j4 + 2][i], h.z, l.z);
    split2(t[j4 + 3][i], h.w, l.w);
    {   // B-k8 of enc^T: n = c0+i, k = r0+j4 (t)
        const int k = r0 + j4;
        const size_t o = bo + ((size_t)(k >> 3) * HE + c0 + i) * 8 + (k & 7);
        *(ushort4*)&Th[o] = h;
        *(ushort4*)&Tl[o] = l;
    }
}

// ---------------------------------------------------------------------------
// Split-bf16 MFMA GEMM on k8-interleaved operands, 2-phase double-buffered.
// C = f(scale * (A @ B^T_layout)), f = id or exp2.
// A: Ahi/Alo A-k8 [K/8][M][8]; B: Bhi/Blo B-k8 [K/8][N][8].
// A@B ~= Ahi@Bhi + Ahi@Blo + Alo@Bhi. Tile 128x128, BK=32, 4 waves (2x2),
// LDS 2 x 32KB (Ahi|Alo|Bhi|Blo 8KB each). Staging loads are contiguous
// 1KB per wave-instruction (coalesced); LDS dest linear (rule #21).
// ---------------------------------------------------------------------------
__global__ __launch_bounds__(256)
void gemm_mfma3(const unsigned short* __restrict__ Ahi, const unsigned short* __restrict__ Alo,
                const unsigned short* __restrict__ Bhi, const unsigned short* __restrict__ Blo,
                float* __restrict__ C, int M, int N, int K,
                long long sA, long long sB, long long sC, float scale, int emode)
{
    __shared__ char smem[2][32768];

    const int tid  = threadIdx.x;
    const int lane = tid & 63;
    const int wave = tid >> 6;
    const int wr = wave >> 1, wc = wave & 1;
    const int fr = lane & 15, fg = lane >> 4;
    const int row0 = blockIdx.y * 128;
    const int col0 = blockIdx.x * 128;

    Ahi += (size_t)blockIdx.z * sA; Alo += (size_t)blockIdx.z * sA;
    Bhi += (size_t)blockIdx.z * sB; Blo += (size_t)blockIdx.z * sB;
    C   += (size_t)blockIdx.z * sC;

    f32x4 acc[4][4];
#pragma unroll
    for (int mi = 0; mi < 4; ++mi)
#pragma unroll
        for (int ni = 0; ni < 4; ++ni)
            acc[mi][ni] = (f32x4){0.f, 0.f, 0.f, 0.f};

    // stage one 32-k-slice (4 k-groups) into buffer `buf`
    auto STAGE = [&](int buf, int k0) {
#pragma unroll
        for (int c = 0; c < 2; ++c) {
            const int bi  = (c * 4 + wave) * 64 + lane;    // 0..511
            const int g   = bi >> 7;                       // k-group 0..3
            const int idx = bi & 127;                      // row within tile
            int mrow = row0 + idx; if (mrow >= M) mrow -= M;
            const int ncol = col0 + idx;
            const size_t ao = ((size_t)((k0 >> 3) + g) * M + mrow) * 8;
            const size_t bo = ((size_t)((k0 >> 3) + g) * N + ncol) * 8;
            const int lb = (c * 4 + wave) * 1024;          // wave-uniform LDS base
            gload16(Ahi + ao, smem[buf] + lb);
            gload16(Alo + ao, smem[buf] + 8192 + lb);
            gload16(Bhi + bo, smem[buf] + 16384 + lb);
            gload16(Blo + bo, smem[buf] + 24576 + lb);
        }
    };

    STAGE(0, 0);
    __syncthreads();

    int buf = 0;
    for (int k0 = 0; k0 < K; k0 += 32) {
        if (k0 + 32 < K) STAGE(buf ^ 1, k0 + 32);   // prefetch next slice

        const int gb = fg << 7;                      // 16B-block base = fg*128
        bf16x8 ah[4], al[4], bh[4], bl[4];
#pragma unroll
        for (int mi = 0; mi < 4; ++mi) {
            const int off = (gb + wr * 64 + mi * 16 + fr) * 16;
            ah[mi] = *(const bf16x8*)(smem[buf] + off);
            al[mi] = *(const bf16x8*)(smem[buf] + 8192 + off);
        }
#pragma unroll
        for (int ni = 0; ni < 4; ++ni) {
            const int off = (gb + wc * 64 + ni * 16 + fr) * 16;
            bh[ni] = *(const bf16x8*)(smem[buf] + 16384 + off);
            bl[ni] = *(const bf16x8*)(smem[buf] + 24576 + off);
        }
#pragma unroll
        for (int mi = 0; mi < 4; ++mi)
#pragma unroll
            for (int ni = 0; ni < 4; ++ni) {
                acc[mi][ni] = __builtin_amdgcn_mfma_f32_16x16x32_bf16(ah[mi], bh[ni], acc[mi][ni], 0, 0, 0);
                acc[mi][ni] = __builtin_amdgcn_mfma_f32_16x16x32_bf16(ah[mi], bl[ni], acc[mi][ni], 0, 0, 0);
                acc[mi][ni] = __builtin_amdgcn_mfma_f32_16x16x32_bf16(al[mi], bh[ni], acc[mi][ni], 0, 0, 0);
            }
        __syncthreads();
        buf ^= 1;
    }

    // epilogue: C/D layout col=lane&15, row=(lane>>4)*4+reg  [m89-verified]
#pragma unroll
    for (int mi = 0; mi < 4; ++mi) {
        const int rbase = row0 + wr * 64 + mi * 16 + fg * 4;
#pragma unroll
        for (int ni = 0; ni < 4; ++ni) {
            const int col = col0 + wc * 64 + ni * 16 + fr;
#pragma unroll
            for (int r = 0; r < 4; ++r) {
                const int row = rbase + r;
                if (row < M) {
                    float val = acc[mi][ni][r] * scale;
                    if (emode) val = fexp2(val);
                    C[(size_t)row * N + col] = val;
                }
            }
        }
    }
}

// ---------------------------------------------------------------------------
// Fallback fp32 GEMM (proven path, used if ws_size is too small)
// ---------------------------------------------------------------------------
__global__ __launch_bounds__(256)
void gemm_f32(const float* __restrict__ A, const float* __restrict__ Bm,
              float* __restrict__ C, int M, int N, int K,
              long long sAb, long long sBb, long long sCb, float scale, int emode)
{
    __shared__ float As[16][68];
    __shared__ float Bs[16][68];

    const int tid = threadIdx.x;
    const int tx  = tid & 15;
    const int ty  = tid >> 4;
    const int row0 = blockIdx.y * 64;
    const int col0 = blockIdx.x * 64;

    A  += (long long)blockIdx.z * sAb;
    Bm += (long long)blockIdx.z * sBb;
    C  += (long long)blockIdx.z * sCb;

    float acc[4][4] = {};

    for (int k0 = 0; k0 < K; k0 += 16) {
        {
            const int r = tid >> 2;
            const int c = (tid & 3) * 4;
            const float4 av = *(const float4*)&A[(long long)(row0 + r) * K + k0 + c];
            As[c + 0][r] = av.x; As[c + 1][r] = av.y;
            As[c + 2][r] = av.z; As[c + 3][r] = av.w;
        }
        {
            const int r = tid >> 4;
            const int c = (tid & 15) * 4;
            *(float4*)&Bs[r][c] = *(const float4*)&Bm[(long long)(k0 + r) * N + col0 + c];
        }
        __syncthreads();

#pragma unroll
        for (int kk = 0; kk < 16; ++kk) {
            const float4 a = *(const float4*)&As[kk][ty * 4];
            const float4 b = *(const float4*)&Bs[kk][tx * 4];
            acc[0][0] += a.x * b.x; acc[0][1] += a.x * b.y; acc[0][2] += a.x * b.z; acc[0][3] += a.x * b.w;
            acc[1][0] += a.y * b.x; acc[1][1] += a.y * b.y; acc[1][2] += a.y * b.z; acc[1][3] += a.y * b.w;
            acc[2][0] += a.z * b.x; acc[2][1] += a.z * b.y; acc[2][2] += a.z * b.z; acc[2][3] += a.z * b.w;
            acc[3][0] += a.w * b.x; acc[3][1] += a.w * b.y; acc[3][2] += a.w * b.z; acc[3][3] += a.w * b.w;
        }
        __syncthreads();
    }

#pragma unroll
    for (int i = 0; i < 4; ++i) {
        float4 o;
        o.x = acc[i][0] * scale; o.y = acc[i][1] * scale;
        o.z = acc[i][2] * scale; o.w = acc[i][3] * scale;
        if (emode) { o.x = fexp2(o.x); o.y = fexp2(o.y); o.z = fexp2(o.z); o.w = fexp2(o.w); }
        *(float4*)&C[(long long)(row0 + ty * 4 + i) * N + col0 + tx * 4] = o;
    }
}

// ---------------------------------------------------------------------------
// Raw scores: raw[b,d,t] = sum_h (-2 V[h]) / (Ew[b,t,h]*Eu[b,d,h] + 1)
// 3 VALU ops/elem, 1 transcendental. Proven round-9 structure (48.6 us).
// ---------------------------------------------------------------------------
__global__ __launch_bounds__(256)
void scores_raw(const float* __restrict__ Ew, const float* __restrict__ Eu,
                const float* __restrict__ V, float* __restrict__ e_raw)
{
    __shared__ float Ws_s[32][64];   // [t][h-chunk], col4 ^= (row>>2)&7
    __shared__ float Uh_s[32][64];   // [d][h-chunk], col4 ^= row&7
    __shared__ float Vr_s[HE];       // -2*V

    const int tid = threadIdx.x;
    const int tg  = tid & 7;     // t-group: t = tt0 + tg*4 + i
    const int dg  = tid >> 3;    // d = d0 + dg   (0..31)

    const int tt0 = blockIdx.x * 32;
    const int d0  = blockIdx.y * 32;
    const int b   = blockIdx.z;

    const float* Wsg = Ew + (long long)b * TE * HE;
    const float* Uhg = Eu + ((long long)b * TD + d0) * HE;

    if (tid < 128) {
        const float4 v = *(const float4*)&V[tid * 4];
        float4 o; o.x = -2.f * v.x; o.y = -2.f * v.y; o.z = -2.f * v.z; o.w = -2.f * v.w;
        *(float4*)&Vr_s[tid * 4] = o;
    }

    float acc[4] = {0.f, 0.f, 0.f, 0.f};
    const int wswz = tg & 7;
    const int uswz = dg & 7;

    for (int hc = 0; hc < HE; hc += 64) {
        __syncthreads();
#pragma unroll
        for (int k = 0; k < 2; ++k) {
            const int idx = tid + k * 256;
            const int r   = idx >> 4;
            const int c4  = idx & 15;
            const float4 wv = *(const float4*)&Wsg[(long long)(tt0 + r) * HE + hc + c4 * 4];
            *(float4*)&Ws_s[r][(c4 ^ ((r >> 2) & 7)) * 4] = wv;
            const float4 uv = *(const float4*)&Uhg[(long long)r * HE + hc + c4 * 4];
            *(float4*)&Uh_s[r][(c4 ^ (r & 7)) * 4] = uv;
        }
        __syncthreads();

#pragma unroll 4
        for (int hs = 0; hs < 64; hs += 4) {
            const int h4 = hs >> 2;
            const float4 vv = *(const float4*)&Vr_s[hc + hs];
            const float4 u  = *(const float4*)&Uh_s[dg][(h4 ^ uswz) * 4];
#pragma unroll
            for (int i = 0; i < 4; ++i) {
                const float4 w = *(const float4*)&Ws_s[tg * 4 + i][(h4 ^ wswz) * 4];
                acc[i] = fmaf(vv.x, frcp(fmaf(w.x, u.x, 1.f)), acc[i]);
                acc[i] = fmaf(vv.y, frcp(fmaf(w.y, u.y, 1.f)), acc[i]);
                acc[i] = fmaf(vv.z, frcp(fmaf(w.z, u.z, 1.f)), acc[i]);
                acc[i] = fmaf(vv.w, frcp(fmaf(w.w, u.w, 1.f)), acc[i]);
            }
        }
    }

    float4 o; o.x = acc[0]; o.y = acc[1]; o.z = acc[2]; o.w = acc[3];
    *(float4*)&e_raw[((long long)b * TD + d0 + dg) * TE + tt0 + tg * 4] = o;
}

// ---------------------------------------------------------------------------
// In-place row softmax; optionally emits A-k8 bf16 hi/lo split of e for gemm3
// (per-batch [TE/8][TD][8]).
// ---------------------------------------------------------------------------
__global__ __launch_bounds__(256)
void softmax_rows(float* __restrict__ e, unsigned short* __restrict__ H,
                  unsigned short* __restrict__ L)
{
    const int lane = threadIdx.x & 63;
    const int wave = threadIdx.x >> 6;
    const long long row = blockIdx.x * 4 + wave;

    float* p = e + row * TE;
    float4 a = *(const float4*)&p[lane * 4];
    float4 c = *(const float4*)&p[lane * 4 + 256];

    float m = fmaxf(fmaxf(fmaxf(a.x, a.y), fmaxf(a.z, a.w)),
                    fmaxf(fmaxf(c.x, c.y), fmaxf(c.z, c.w)));
#pragma unroll
    for (int off = 32; off; off >>= 1) m = fmaxf(m, __shfl_xor(m, off));

    a.x = __expf(a.x - m); a.y = __expf(a.y - m); a.z = __expf(a.z - m); a.w = __expf(a.w - m);
    c.x = __expf(c.x - m); c.y = __expf(c.y - m); c.z = __expf(c.z - m); c.w = __expf(c.w - m);

    float s = (a.x + a.y + a.z + a.w) + (c.x + c.y + c.z + c.w);
#pragma unroll
    for (int off = 32; off; off >>= 1) s += __shfl_xor(s, off);

    const float inv = __fdividef(1.f, s);
    a.x *= inv; a.y *= inv; a.z *= inv; a.w *= inv;
    c.x *= inv; c.y *= inv; c.z *= inv; c.w *= inv;
    *(float4*)&p[lane * 4] = a;
    *(float4*)&p[lane * 4 + 256] = c;

    if (H) {
        const int b = (int)(row >> 6);
        const int d = (int)(row & 63);
        const size_t base = (size_t)b * (TD * TE);
        ushort4 h, l;
        {
            const int t0 = lane * 4;
            const size_t o = base + ((size_t)(t0 >> 3) * TD + d) * 8 + (t0 & 7);
            split2(a.x, h.x, l.x); split2(a.y, h.y, l.y);
            split2(a.z, h.z, l.z); split2(a.w, h.w, l.w);
            *(ushort4*)&H[o] = h;
            *(ushort4*)&L[o] = l;
        }
        {
            const int t0 = lane * 4 + 256;
            const size_t o = base + ((size_t)(t0 >> 3) * TD + d) * 8 + (t0 & 7);
            split2(c.x, h.x, l.x); split2(c.y, h.y, l.y);
            split2(c.z, h.z, l.z); split2(c.w, h.w, l.w);
            *(ushort4*)&H[o] = h;
            *(ushort4*)&L[o] = l;
        }
    }
}

// ---------------------------------------------------------------------------
extern "C" void kernel_launch(void* const* d_in, const int* in_sizes, int n_in,
                              void* d_out, int out_size, void* d_ws, size_t ws_size,
                              hipStream_t stream)
{
    const float* enc = (const float*)d_in[0];  // [B,TE,HE]
    const float* dec = (const float*)d_in[1];  // [B,TD,HD=HE]
    const float* Wa  = (const float*)d_in[2];  // [HE,HE]
    const float* Ua  = (const float*)d_in[3];  // [HD,HE]
    const float* Va  = (const float*)d_in[4];  // [HE,1] -> flat [HE]

    float* out   = (float*)d_out;
    float* c_out = out;                        // [B,TD,HE]
    float* e_out = out + (size_t)BB * TD * HE; // [B,TD,TE]

    char* w = (char*)d_ws;
    float* Ew  = (float*)(w);                                  // 16,777,216 B (exp2'd Ws)
    float* Eu  = (float*)(w + 16777216);                       //  2,097,152 B (exp2'd Uh)
    unsigned short* encAh = (unsigned short*)(w + 18874368);   //  8,388,608 B  (A-k8)
    unsigned short* encAl = (unsigned short*)(w + 27262976);
    unsigned short* encTh = (unsigned short*)(w + 35651584);   //  (B-k8 per batch)
    unsigned short* encTl = (unsigned short*)(w + 44040192);
    unsigned short* decAh = (unsigned short*)(w + 52428800);   //  1,048,576 B
    unsigned short* decAl = (unsigned short*)(w + 53477376);
    unsigned short* WaTh  = (unsigned short*)(w + 54525952);   //    524,288 B
    unsigned short* WaTl  = (unsigned short*)(w + 55050240);
    unsigned short* UaTh  = (unsigned short*)(w + 55574528);
    unsigned short* UaTl  = (unsigned short*)(w + 56098816);
    unsigned short* eh    = (unsigned short*)(w + 56623104);   //  1,048,576 B (A-k8/batch)
    unsigned short* el    = (unsigned short*)(w + 57671680);
    const size_t REQUIRED = 58720256;

    dim3 blk(256);

    if (ws_size >= REQUIRED) {
        // --- split/transpose conversions (k8-interleaved outputs) ---
        split_enc_k8<<<dim3(16, 16, BB), blk, 0, stream>>>(enc, encAh, encAl, encTh, encTl);
        split_rm_k8<<<512, blk, 0, stream>>>(dec, decAh, decAl, BB * TD, HE);
        split_tr_k8<<<dim3(16, 16, 1), blk, 0, stream>>>(Wa, WaTh, WaTl, HE, HE);
        split_tr_k8<<<dim3(16, 16, 1), blk, 0, stream>>>(Ua, UaTh, UaTl, HE, HE);

        // Ew = exp2(PRESCALE * enc @ W_a)   (M=8192)
        gemm_mfma3<<<dim3(4, 64, 1), blk, 0, stream>>>(
            encAh, encAl, WaTh, WaTl, Ew, BB * TE, HE, HE, 0, 0, 0, PRESCALE, 1);
        // Eu = exp2(PRESCALE * dec @ U_a)   (M=1024)
        gemm_mfma3<<<dim3(4, 8, 1), blk, 0, stream>>>(
            decAh, decAl, UaTh, UaTl, Eu, BB * TD, HE, HE, 0, 0, 0, PRESCALE, 1);

        scores_raw<<<dim3(TE / 32, TD / 32, BB), blk, 0, stream>>>(Ew, Eu, Va, e_out);
        softmax_rows<<<dim3(BB * TD / 4), blk, 0, stream>>>(e_out, eh, el);

        // c[b] = e[b] @ enc[b]   (M=64 valid of 128-tile, batched)
        gemm_mfma3<<<dim3(4, 1, BB), blk, 0, stream>>>(
            eh, el, encTh, encTl, c_out, TD, HE, TE,
            (long long)TD * TE, (long long)TE * HE, (long long)TD * HE, 1.0f, 0);
    } else {
        // --- fallback: fp32 path ---
        gemm_f32<<<dim3(HE / 64, (BB * TE) / 64, 1), blk, 0, stream>>>(
            enc, Wa, Ew, BB * TE, HE, HE, 0, 0, 0, PRESCALE, 1);
        gemm_f32<<<dim3(HE / 64, (BB * TD) / 64, 1), blk, 0, stream>>>(
            dec, Ua, Eu, BB * TD, HE, HE, 0, 0, 0, PRESCALE, 1);
        scores_raw<<<dim3(TE / 32, TD / 32, BB), blk, 0, stream>>>(Ew, Eu, Va, e_out);
        softmax_rows<<<dim3(BB * TD / 4), blk, 0, stream>>>(e_out, nullptr, nullptr);
        gemm_f32<<<dim3(HE / 64, TD / 64, BB), blk, 0, stream>>>(
            e_out, enc, c_out, TD, HE, TE,
            (long long)TD * TE, (long long)TE * HE, (long long)TD * HE, 1.0f, 0);
    }
}

// Round 11
// 114.478 us; speedup vs baseline: 2.7513x; 1.0882x over previous
//
#include <hip/hip_runtime.h>
#include <hip/hip_bf16.h>

#define BB 16
#define TE 512
#define TD 64
#define HE 512

// 2*log2(e): folded into Ws/Uh GEMM epilogue (with exp2) so the scores inner
// loop needs no exp at all: tanh term via 1/(Ew*Eu+1).
#define PRESCALE 2.8853900817779268f

typedef __attribute__((ext_vector_type(8))) short bf16x8;
typedef __attribute__((ext_vector_type(4))) float f32x4;

__device__ __forceinline__ float fexp2(float x) {
#if __has_builtin(__builtin_amdgcn_exp2f)
    return __builtin_amdgcn_exp2f(x);
#else
    return exp2f(x);
#endif
}
__device__ __forceinline__ float frcp(float x) {
#if __has_builtin(__builtin_amdgcn_rcpf)
    return __builtin_amdgcn_rcpf(x);
#else
    return __fdividef(1.f, x);
#endif
}

// split fp32 -> bf16 hi + bf16 lo (x ~= hi + lo, ~2^-17 relative)
__device__ __forceinline__ void split2(float x, unsigned short& h, unsigned short& l) {
    __hip_bfloat16 hb = __float2bfloat16(x);
    h = *(unsigned short*)&hb;
    float r = x - __bfloat162float(hb);
    __hip_bfloat16 lb = __float2bfloat16(r);
    l = *(unsigned short*)&lb;
}

__device__ __forceinline__ void gload16(const unsigned short* g, void* l) {
    __builtin_amdgcn_global_load_lds(
        (const __attribute__((address_space(1))) unsigned int*)g,
        (__attribute__((address_space(3))) unsigned int*)l, 16, 0, 0);
}

// ===========================================================================
// k8-interleaved operand layout:  Xp[s][r][j] = X[r][s*8+j],  s = k/8, j = k%8
// flat index = (s*R + r)*8 + j.  Makes gemm staging loads fully coalesced.
// ===========================================================================

// ---------------------------------------------------------------------------
// split_rm_k8: X fp32 row-major [M][K] -> A-k8 hi/lo
// ---------------------------------------------------------------------------
__global__ __launch_bounds__(256)
void split_rm_k8(const float* __restrict__ X, unsigned short* __restrict__ H,
                 unsigned short* __restrict__ L, int M, int K)
{
    const size_t i = ((size_t)blockIdx.x * 256 + threadIdx.x) * 4;
    const int m = (int)(i / K);
    const int k = (int)(i % K);
    const float4 v = *(const float4*)&X[i];
    ushort4 h, l;
    split2(v.x, h.x, l.x); split2(v.y, h.y, l.y);
    split2(v.z, h.z, l.z); split2(v.w, h.w, l.w);
    const size_t o = ((size_t)(k >> 3) * M + m) * 8 + (k & 7);
    *(ushort4*)&H[o] = h;
    *(ushort4*)&L[o] = l;
}

// ---------------------------------------------------------------------------
// split_tr2_k8: two [R][C] fp32 matrices -> B-k8 of X^T (z selects which)
// ---------------------------------------------------------------------------
__global__ __launch_bounds__(256)
void split_tr2_k8(const float* __restrict__ X0, unsigned short* __restrict__ H0,
                  unsigned short* __restrict__ L0,
                  const float* __restrict__ X1, unsigned short* __restrict__ H1,
                  unsigned short* __restrict__ L1, int R, int C)
{
    __shared__ float t[32][33];
    const float* X = blockIdx.z ? X1 : X0;
    unsigned short* H = blockIdx.z ? H1 : H0;
    unsigned short* L = blockIdx.z ? L1 : L0;

    const int tid = threadIdx.x;
    const int r0 = blockIdx.y * 32, c0 = blockIdx.x * 32;
    const int i = tid >> 3, j4 = (tid & 7) * 4;

    const float4 v = *(const float4*)&X[(size_t)(r0 + i) * C + c0 + j4];
    t[i][j4 + 0] = v.x; t[i][j4 + 1] = v.y; t[i][j4 + 2] = v.z; t[i][j4 + 3] = v.w;
    __syncthreads();

    ushort4 h, l;
    split2(t[j4 + 0][i], h.x, l.x);
    split2(t[j4 + 1][i], h.y, l.y);
    split2(t[j4 + 2][i], h.z, l.z);
    split2(t[j4 + 3][i], h.w, l.w);
    const int r = r0 + j4;                 // k index of B
    const size_t o = ((size_t)(r >> 3) * C + c0 + i) * 8 + (r & 7);
    *(ushort4*)&H[o] = h;
    *(ushort4*)&L[o] = l;
}

// ---------------------------------------------------------------------------
// split_enc_k8: enc [B][TE][HE] -> (a) A-k8 over fused rows m=b*TE+t (K=HE),
// (b) per-batch B-k8 of enc^T (B[n=h][k=t], K=TE).
// ---------------------------------------------------------------------------
__global__ __launch_bounds__(256)
void split_enc_k8(const float* __restrict__ X,
                  unsigned short* __restrict__ Ah, unsigned short* __restrict__ Al,
                  unsigned short* __restrict__ Th, unsigned short* __restrict__ Tl)
{
    __shared__ float t[32][33];
    const int tid = threadIdx.x;
    const int r0 = blockIdx.y * 32, c0 = blockIdx.x * 32;   // r: t, c: h
    const int b  = blockIdx.z;
    const size_t bo = (size_t)b * TE * HE;
    const int i = tid >> 3, j4 = (tid & 7) * 4;

    const float4 v = *(const float4*)&X[bo + (size_t)(r0 + i) * HE + c0 + j4];

    ushort4 h, l;
    split2(v.x, h.x, l.x); split2(v.y, h.y, l.y);
    split2(v.z, h.z, l.z); split2(v.w, h.w, l.w);
    {   // A-k8: m = b*TE + r0+i, k = c0+j4
        const int m = b * TE + r0 + i;
        const int k = c0 + j4;
        const size_t o = ((size_t)(k >> 3) * (BB * TE) + m) * 8 + (k & 7);
        *(ushort4*)&Ah[o] = h;
        *(ushort4*)&Al[o] = l;
    }

    t[i][j4 + 0] = v.x; t[i][j4 + 1] = v.y; t[i][j4 + 2] = v.z; t[i][j4 + 3] = v.w;
    __syncthreads();

    split2(t[j4 + 0][i], h.x, l.x);
    split2(t[j4 + 1][i], h.y, l.y);
    split2(t[j4 + 2][i], h.z, l.z);
    split2(t[j4 + 3][i], h.w, l.w);
    {   // B-k8 of enc^T: n = c0+i, k = r0+j4 (t)
        const int k = r0 + j4;
        const size_t o = bo + ((size_t)(k >> 3) * HE + c0 + i) * 8 + (k & 7);
        *(ushort4*)&Th[o] = h;
        *(ushort4*)&Tl[o] = l;
    }
}

// ---------------------------------------------------------------------------
// Split-bf16 MFMA GEMM on k8-interleaved operands, 2-phase double-buffered.
// C = f(scale * (A @ B^T_layout)), f = id or exp2.  Tile 128x128, BK=32.
// ---------------------------------------------------------------------------
__global__ __launch_bounds__(256)
void gemm_mfma3(const unsigned short* __restrict__ Ahi, const unsigned short* __restrict__ Alo,
                const unsigned short* __restrict__ Bhi, const unsigned short* __restrict__ Blo,
                float* __restrict__ C, int M, int N, int K,
                long long sA, long long sB, long long sC, float scale, int emode)
{
    __shared__ char smem[2][32768];

    const int tid  = threadIdx.x;
    const int lane = tid & 63;
    const int wave = tid >> 6;
    const int wr = wave >> 1, wc = wave & 1;
    const int fr = lane & 15, fg = lane >> 4;
    const int row0 = blockIdx.y * 128;
    const int col0 = blockIdx.x * 128;

    Ahi += (size_t)blockIdx.z * sA; Alo += (size_t)blockIdx.z * sA;
    Bhi += (size_t)blockIdx.z * sB; Blo += (size_t)blockIdx.z * sB;
    C   += (size_t)blockIdx.z * sC;

    f32x4 acc[4][4];
#pragma unroll
    for (int mi = 0; mi < 4; ++mi)
#pragma unroll
        for (int ni = 0; ni < 4; ++ni)
            acc[mi][ni] = (f32x4){0.f, 0.f, 0.f, 0.f};

    auto STAGE = [&](int buf, int k0) {
#pragma unroll
        for (int c = 0; c < 2; ++c) {
            const int bi  = (c * 4 + wave) * 64 + lane;    // 0..511
            const int g   = bi >> 7;                       // k-group 0..3
            const int idx = bi & 127;                      // row within tile
            int mrow = row0 + idx; if (mrow >= M) mrow -= M;
            const int ncol = col0 + idx;
            const size_t ao = ((size_t)((k0 >> 3) + g) * M + mrow) * 8;
            const size_t bo = ((size_t)((k0 >> 3) + g) * N + ncol) * 8;
            const int lb = (c * 4 + wave) * 1024;          // wave-uniform LDS base
            gload16(Ahi + ao, smem[buf] + lb);
            gload16(Alo + ao, smem[buf] + 8192 + lb);
            gload16(Bhi + bo, smem[buf] + 16384 + lb);
            gload16(Blo + bo, smem[buf] + 24576 + lb);
        }
    };

    STAGE(0, 0);
    __syncthreads();

    int buf = 0;
    for (int k0 = 0; k0 < K; k0 += 32) {
        if (k0 + 32 < K) STAGE(buf ^ 1, k0 + 32);   // prefetch next slice

        const int gb = fg << 7;
        bf16x8 ah[4], al[4], bh[4], bl[4];
#pragma unroll
        for (int mi = 0; mi < 4; ++mi) {
            const int off = (gb + wr * 64 + mi * 16 + fr) * 16;
            ah[mi] = *(const bf16x8*)(smem[buf] + off);
            al[mi] = *(const bf16x8*)(smem[buf] + 8192 + off);
        }
#pragma unroll
        for (int ni = 0; ni < 4; ++ni) {
            const int off = (gb + wc * 64 + ni * 16 + fr) * 16;
            bh[ni] = *(const bf16x8*)(smem[buf] + 16384 + off);
            bl[ni] = *(const bf16x8*)(smem[buf] + 24576 + off);
        }
#pragma unroll
        for (int mi = 0; mi < 4; ++mi)
#pragma unroll
            for (int ni = 0; ni < 4; ++ni) {
                acc[mi][ni] = __builtin_amdgcn_mfma_f32_16x16x32_bf16(ah[mi], bh[ni], acc[mi][ni], 0, 0, 0);
                acc[mi][ni] = __builtin_amdgcn_mfma_f32_16x16x32_bf16(ah[mi], bl[ni], acc[mi][ni], 0, 0, 0);
                acc[mi][ni] = __builtin_amdgcn_mfma_f32_16x16x32_bf16(al[mi], bh[ni], acc[mi][ni], 0, 0, 0);
            }
        __syncthreads();
        buf ^= 1;
    }

    // epilogue: C/D layout col=lane&15, row=(lane>>4)*4+reg  [m89-verified]
#pragma unroll
    for (int mi = 0; mi < 4; ++mi) {
        const int rbase = row0 + wr * 64 + mi * 16 + fg * 4;
#pragma unroll
        for (int ni = 0; ni < 4; ++ni) {
            const int col = col0 + wc * 64 + ni * 16 + fr;
#pragma unroll
            for (int r = 0; r < 4; ++r) {
                const int row = rbase + r;
                if (row < M) {
                    float val = acc[mi][ni][r] * scale;
                    if (emode) val = fexp2(val);
                    C[(size_t)row * N + col] = val;
                }
            }
        }
    }
}

// ---------------------------------------------------------------------------
// Fallback fp32 GEMM (used if ws_size is too small)
// ---------------------------------------------------------------------------
__global__ __launch_bounds__(256)
void gemm_f32(const float* __restrict__ A, const float* __restrict__ Bm,
              float* __restrict__ C, int M, int N, int K,
              long long sAb, long long sBb, long long sCb, float scale, int emode)
{
    __shared__ float As[16][68];
    __shared__ float Bs[16][68];

    const int tid = threadIdx.x;
    const int tx  = tid & 15;
    const int ty  = tid >> 4;
    const int row0 = blockIdx.y * 64;
    const int col0 = blockIdx.x * 64;

    A  += (long long)blockIdx.z * sAb;
    Bm += (long long)blockIdx.z * sBb;
    C  += (long long)blockIdx.z * sCb;

    float acc[4][4] = {};

    for (int k0 = 0; k0 < K; k0 += 16) {
        {
            const int r = tid >> 2;
            const int c = (tid & 3) * 4;
            const float4 av = *(const float4*)&A[(long long)(row0 + r) * K + k0 + c];
            As[c + 0][r] = av.x; As[c + 1][r] = av.y;
            As[c + 2][r] = av.z; As[c + 3][r] = av.w;
        }
        {
            const int r = tid >> 4;
            const int c = (tid & 15) * 4;
            *(float4*)&Bs[r][c] = *(const float4*)&Bm[(long long)(k0 + r) * N + col0 + c];
        }
        __syncthreads();

#pragma unroll
        for (int kk = 0; kk < 16; ++kk) {
            const float4 a = *(const float4*)&As[kk][ty * 4];
            const float4 b = *(const float4*)&Bs[kk][tx * 4];
            acc[0][0] += a.x * b.x; acc[0][1] += a.x * b.y; acc[0][2] += a.x * b.z; acc[0][3] += a.x * b.w;
            acc[1][0] += a.y * b.x; acc[1][1] += a.y * b.y; acc[1][2] += a.y * b.z; acc[1][3] += a.y * b.w;
            acc[2][0] += a.z * b.x; acc[2][1] += a.z * b.y; acc[2][2] += a.z * b.z; acc[2][3] += a.z * b.w;
            acc[3][0] += a.w * b.x; acc[3][1] += a.w * b.y; acc[3][2] += a.w * b.z; acc[3][3] += a.w * b.w;
        }
        __syncthreads();
    }

#pragma unroll
    for (int i = 0; i < 4; ++i) {
        float4 o;
        o.x = acc[i][0] * scale; o.y = acc[i][1] * scale;
        o.z = acc[i][2] * scale; o.w = acc[i][3] * scale;
        if (emode) { o.x = fexp2(o.x); o.y = fexp2(o.y); o.z = fexp2(o.z); o.w = fexp2(o.w); }
        *(float4*)&C[(long long)(row0 + ty * 4 + i) * N + col0 + tx * 4] = o;
    }
}

// ---------------------------------------------------------------------------
// Raw score PARTIALS over an h-half: part[half][b,d,t] =
//   sum_{h in half} (-2 V[h]) / (Ew[b,t,h]*Eu[b,d,h] + 1)
// h-split x2 doubles grid to 1024 blocks (4/CU, 16 waves/CU) to lift
// occupancy 18% -> ~40%. Inner loop / thread map / swizzle unchanged.
// ---------------------------------------------------------------------------
__global__ __launch_bounds__(256)
void scores_raw(const float* __restrict__ Ew, const float* __restrict__ Eu,
                const float* __restrict__ V, float* __restrict__ part)
{
    __shared__ float Ws_s[32][64];   // [t][h-chunk], col4 ^= (row>>2)&7
    __shared__ float Uh_s[32][64];   // [d][h-chunk], col4 ^= row&7
    __shared__ float Vr_s[HE];       // -2*V

    const int tid = threadIdx.x;
    const int tg  = tid & 7;     // t-group: t = tt0 + tg*4 + i
    const int dg  = tid >> 3;    // d = d0 + dg   (0..31)

    const int tt0  = blockIdx.x * 32;
    const int half = blockIdx.y & 1;
    const int d0   = (blockIdx.y >> 1) * 32;
    const int b    = blockIdx.z;

    const float* Wsg = Ew + (long long)b * TE * HE;
    const float* Uhg = Eu + ((long long)b * TD + d0) * HE;

    if (tid < 128) {
        const float4 v = *(const float4*)&V[tid * 4];
        float4 o; o.x = -2.f * v.x; o.y = -2.f * v.y; o.z = -2.f * v.z; o.w = -2.f * v.w;
        *(float4*)&Vr_s[tid * 4] = o;
    }

    float acc[4] = {0.f, 0.f, 0.f, 0.f};
    const int wswz = tg & 7;
    const int uswz = dg & 7;
    const int hbase = half * (HE / 2);

    for (int hc = hbase; hc < hbase + HE / 2; hc += 64) {
        __syncthreads();
#pragma unroll
        for (int k = 0; k < 2; ++k) {
            const int idx = tid + k * 256;
            const int r   = idx >> 4;
            const int c4  = idx & 15;
            const float4 wv = *(const float4*)&Wsg[(long long)(tt0 + r) * HE + hc + c4 * 4];
            *(float4*)&Ws_s[r][(c4 ^ ((r >> 2) & 7)) * 4] = wv;
            const float4 uv = *(const float4*)&Uhg[(long long)r * HE + hc + c4 * 4];
            *(float4*)&Uh_s[r][(c4 ^ (r & 7)) * 4] = uv;
        }
        __syncthreads();

#pragma unroll 4
        for (int hs = 0; hs < 64; hs += 4) {
            const int h4 = hs >> 2;
            const float4 vv = *(const float4*)&Vr_s[hc + hs];
            const float4 u  = *(const float4*)&Uh_s[dg][(h4 ^ uswz) * 4];
#pragma unroll
            for (int i = 0; i < 4; ++i) {
                const float4 w = *(const float4*)&Ws_s[tg * 4 + i][(h4 ^ wswz) * 4];
                acc[i] = fmaf(vv.x, frcp(fmaf(w.x, u.x, 1.f)), acc[i]);
                acc[i] = fmaf(vv.y, frcp(fmaf(w.y, u.y, 1.f)), acc[i]);
                acc[i] = fmaf(vv.z, frcp(fmaf(w.z, u.z, 1.f)), acc[i]);
                acc[i] = fmaf(vv.w, frcp(fmaf(w.w, u.w, 1.f)), acc[i]);
            }
        }
    }

    float* dst = part + (size_t)half * (BB * TD * TE);
    float4 o; o.x = acc[0]; o.y = acc[1]; o.z = acc[2]; o.w = acc[3];
    *(float4*)&dst[((long long)b * TD + d0 + dg) * TE + tt0 + tg * 4] = o;
}

// ---------------------------------------------------------------------------
// Row softmax over summed partials -> e (fp32) + optional A-k8 bf16 hi/lo of e
// ---------------------------------------------------------------------------
__global__ __launch_bounds__(256)
void softmax_rows(const float* __restrict__ part, float* __restrict__ e,
                  unsigned short* __restrict__ H, unsigned short* __restrict__ L)
{
    const int lane = threadIdx.x & 63;
    const int wave = threadIdx.x >> 6;
    const long long row = blockIdx.x * 4 + wave;

    const float* p0 = part + row * TE;
    const float* p1 = part + (size_t)(BB * TD * TE) + row * TE;
    float4 a  = *(const float4*)&p0[lane * 4];
    float4 c  = *(const float4*)&p0[lane * 4 + 256];
    const float4 a1 = *(const float4*)&p1[lane * 4];
    const float4 c1 = *(const float4*)&p1[lane * 4 + 256];
    a.x += a1.x; a.y += a1.y; a.z += a1.z; a.w += a1.w;
    c.x += c1.x; c.y += c1.y; c.z += c1.z; c.w += c1.w;

    float m = fmaxf(fmaxf(fmaxf(a.x, a.y), fmaxf(a.z, a.w)),
                    fmaxf(fmaxf(c.x, c.y), fmaxf(c.z, c.w)));
#pragma unroll
    for (int off = 32; off; off >>= 1) m = fmaxf(m, __shfl_xor(m, off));

    a.x = __expf(a.x - m); a.y = __expf(a.y - m); a.z = __expf(a.z - m); a.w = __expf(a.w - m);
    c.x = __expf(c.x - m); c.y = __expf(c.y - m); c.z = __expf(c.z - m); c.w = __expf(c.w - m);

    float s = (a.x + a.y + a.z + a.w) + (c.x + c.y + c.z + c.w);
#pragma unroll
    for (int off = 32; off; off >>= 1) s += __shfl_xor(s, off);

    const float inv = __fdividef(1.f, s);
    a.x *= inv; a.y *= inv; a.z *= inv; a.w *= inv;
    c.x *= inv; c.y *= inv; c.z *= inv; c.w *= inv;
    float* pe = e + row * TE;
    *(float4*)&pe[lane * 4] = a;
    *(float4*)&pe[lane * 4 + 256] = c;

    if (H) {
        const int b = (int)(row >> 6);
        const int d = (int)(row & 63);
        const size_t base = (size_t)b * (TD * TE);
        ushort4 h, l;
        {
            const int t0 = lane * 4;
            const size_t o = base + ((size_t)(t0 >> 3) * TD + d) * 8 + (t0 & 7);
            split2(a.x, h.x, l.x); split2(a.y, h.y, l.y);
            split2(a.z, h.z, l.z); split2(a.w, h.w, l.w);
            *(ushort4*)&H[o] = h;
            *(ushort4*)&L[o] = l;
        }
        {
            const int t0 = lane * 4 + 256;
            const size_t o = base + ((size_t)(t0 >> 3) * TD + d) * 8 + (t0 & 7);
            split2(c.x, h.x, l.x); split2(c.y, h.y, l.y);
            split2(c.z, h.z, l.z); split2(c.w, h.w, l.w);
            *(ushort4*)&H[o] = h;
            *(ushort4*)&L[o] = l;
        }
    }
}

// ---------------------------------------------------------------------------
extern "C" void kernel_launch(void* const* d_in, const int* in_sizes, int n_in,
                              void* d_out, int out_size, void* d_ws, size_t ws_size,
                              hipStream_t stream)
{
    const float* enc = (const float*)d_in[0];  // [B,TE,HE]
    const float* dec = (const float*)d_in[1];  // [B,TD,HD=HE]
    const float* Wa  = (const float*)d_in[2];  // [HE,HE]
    const float* Ua  = (const float*)d_in[3];  // [HD,HE]
    const float* Va  = (const float*)d_in[4];  // [HE,1] -> flat [HE]

    float* out   = (float*)d_out;
    float* c_out = out;                        // [B,TD,HE]
    float* e_out = out + (size_t)BB * TD * HE; // [B,TD,TE]

    char* w = (char*)d_ws;
    float* Ew  = (float*)(w);                                  // 16,777,216 B (exp2'd Ws)
    float* Eu  = (float*)(w + 16777216);                       //  2,097,152 B (exp2'd Uh)
    unsigned short* encAh = (unsigned short*)(w + 18874368);   //  8,388,608 B  (A-k8)
    unsigned short* encAl = (unsigned short*)(w + 27262976);
    unsigned short* encTh = (unsigned short*)(w + 35651584);   //  (B-k8 per batch)
    unsigned short* encTl = (unsigned short*)(w + 44040192);
    unsigned short* decAh = (unsigned short*)(w + 52428800);   //  1,048,576 B
    unsigned short* decAl = (unsigned short*)(w + 53477376);
    unsigned short* WaTh  = (unsigned short*)(w + 54525952);   //    524,288 B
    unsigned short* WaTl  = (unsigned short*)(w + 55050240);
    unsigned short* UaTh  = (unsigned short*)(w + 55574528);
    unsigned short* UaTl  = (unsigned short*)(w + 56098816);
    unsigned short* eh    = (unsigned short*)(w + 56623104);   //  1,048,576 B (A-k8/batch)
    unsigned short* el    = (unsigned short*)(w + 57671680);
    // score partials (2 x 2 MB) reuse decA/WaT/UaT region (dead after gemm2)
    float* part = (float*)(w + 52428800);
    const size_t REQUIRED = 58720256;

    dim3 blk(256);

    if (ws_size >= REQUIRED) {
        // --- split/transpose conversions (k8-interleaved outputs) ---
        split_enc_k8<<<dim3(16, 16, BB), blk, 0, stream>>>(enc, encAh, encAl, encTh, encTl);
        split_rm_k8<<<512, blk, 0, stream>>>(dec, decAh, decAl, BB * TD, HE);
        split_tr2_k8<<<dim3(16, 16, 2), blk, 0, stream>>>(Wa, WaTh, WaTl, Ua, UaTh, UaTl, HE, HE);

        // Ew = exp2(PRESCALE * enc @ W_a)   (M=8192)
        gemm_mfma3<<<dim3(4, 64, 1), blk, 0, stream>>>(
            encAh, encAl, WaTh, WaTl, Ew, BB * TE, HE, HE, 0, 0, 0, PRESCALE, 1);
        // Eu = exp2(PRESCALE * dec @ U_a)   (M=1024)
        gemm_mfma3<<<dim3(4, 8, 1), blk, 0, stream>>>(
            decAh, decAl, UaTh, UaTl, Eu, BB * TD, HE, HE, 0, 0, 0, PRESCALE, 1);

        // raw score partials (h-split x2): grid y = d-tile*2 + half
        scores_raw<<<dim3(TE / 32, (TD / 32) * 2, BB), blk, 0, stream>>>(Ew, Eu, Va, part);
        softmax_rows<<<dim3(BB * TD / 4), blk, 0, stream>>>(part, e_out, eh, el);

        // c[b] = e[b] @ enc[b]   (M=64 valid of 128-tile, batched)
        gemm_mfma3<<<dim3(4, 1, BB), blk, 0, stream>>>(
            eh, el, encTh, encTl, c_out, TD, HE, TE,
            (long long)TD * TE, (long long)TE * HE, (long long)TD * HE, 1.0f, 0);
    } else {
        // --- fallback: fp32 path (partials placed after Eu; needs ~23 MB) ---
        float* pf = (float*)(w + 18874368);
        gemm_f32<<<dim3(HE / 64, (BB * TE) / 64, 1), blk, 0, stream>>>(
            enc, Wa, Ew, BB * TE, HE, HE, 0, 0, 0, PRESCALE, 1);
        gemm_f32<<<dim3(HE / 64, (BB * TD) / 64, 1), blk, 0, stream>>>(
            dec, Ua, Eu, BB * TD, HE, HE, 0, 0, 0, PRESCALE, 1);
        scores_raw<<<dim3(TE / 32, (TD / 32) * 2, BB), blk, 0, stream>>>(Ew, Eu, Va, pf);
        softmax_rows<<<dim3(BB * TD / 4), blk, 0, stream>>>(pf, e_out, nullptr, nullptr);
        gemm_f32<<<dim3(HE / 64, TD / 64, BB), blk, 0, stream>>>(
            e_out, enc, c_out, TD, HE, TE,
            (long long)TD * TE, (long long)TE * HE, (long long)TD * HE, 1.0f, 0);
    }
}

// Round 12
// 92.118 us; speedup vs baseline: 3.4192x; 1.2427x over previous
//
#include <hip/hip_runtime.h>
#include <hip/hip_bf16.h>

#define BB 16
#define TE 512
#define TD 64
#define HE 512

// 2*log2(e): folded into Ws/Uh GEMM epilogue (with exp2) so the scores inner
// loop needs no exp at all: tanh term via 1/(Ew*Eu+1).
#define PRESCALE 2.8853900817779268f

typedef __attribute__((ext_vector_type(8))) short bf16x8;
typedef __attribute__((ext_vector_type(4))) float f32x4;

__device__ __forceinline__ float fexp2(float x) {
#if __has_builtin(__builtin_amdgcn_exp2f)
    return __builtin_amdgcn_exp2f(x);
#else
    return exp2f(x);
#endif
}
__device__ __forceinline__ float frcp(float x) {
#if __has_builtin(__builtin_amdgcn_rcpf)
    return __builtin_amdgcn_rcpf(x);
#else
    return __fdividef(1.f, x);
#endif
}

// split fp32 -> bf16 hi + bf16 lo (x ~= hi + lo, ~2^-17 relative)
__device__ __forceinline__ void split2(float x, unsigned short& h, unsigned short& l) {
    __hip_bfloat16 hb = __float2bfloat16(x);
    h = *(unsigned short*)&hb;
    float r = x - __bfloat162float(hb);
    __hip_bfloat16 lb = __float2bfloat16(r);
    l = *(unsigned short*)&lb;
}

__device__ __forceinline__ void gload16(const unsigned short* g, void* l) {
    __builtin_amdgcn_global_load_lds(
        (const __attribute__((address_space(1))) unsigned int*)g,
        (__attribute__((address_space(3))) unsigned int*)l, 16, 0, 0);
}

// ===========================================================================
// k8-interleaved operand layout:  Xp[s][r][j] = X[r][s*8+j],  s = k/8, j = k%8
// flat index = (s*R + r)*8 + j.  Makes gemm staging loads fully coalesced.
// ===========================================================================

// ---------------------------------------------------------------------------
// split_enc_k8: enc [B][TE][HE] -> (a) A-k8 over fused rows m=b*TE+t (K=HE),
// (b) per-batch B-k8 of enc^T (B[n=h][k=t], K=TE).
// ---------------------------------------------------------------------------
__global__ __launch_bounds__(256)
void split_enc_k8(const float* __restrict__ X,
                  unsigned short* __restrict__ Ah, unsigned short* __restrict__ Al,
                  unsigned short* __restrict__ Th, unsigned short* __restrict__ Tl)
{
    __shared__ float t[32][33];
    const int tid = threadIdx.x;
    const int r0 = blockIdx.y * 32, c0 = blockIdx.x * 32;   // r: t, c: h
    const int b  = blockIdx.z;
    const size_t bo = (size_t)b * TE * HE;
    const int i = tid >> 3, j4 = (tid & 7) * 4;

    const float4 v = *(const float4*)&X[bo + (size_t)(r0 + i) * HE + c0 + j4];

    ushort4 h, l;
    split2(v.x, h.x, l.x); split2(v.y, h.y, l.y);
    split2(v.z, h.z, l.z); split2(v.w, h.w, l.w);
    {   // A-k8: m = b*TE + r0+i, k = c0+j4
        const int m = b * TE + r0 + i;
        const int k = c0 + j4;
        const size_t o = ((size_t)(k >> 3) * (BB * TE) + m) * 8 + (k & 7);
        *(ushort4*)&Ah[o] = h;
        *(ushort4*)&Al[o] = l;
    }

    t[i][j4 + 0] = v.x; t[i][j4 + 1] = v.y; t[i][j4 + 2] = v.z; t[i][j4 + 3] = v.w;
    __syncthreads();

    split2(t[j4 + 0][i], h.x, l.x);
    split2(t[j4 + 1][i], h.y, l.y);
    split2(t[j4 + 2][i], h.z, l.z);
    split2(t[j4 + 3][i], h.w, l.w);
    {   // B-k8 of enc^T: n = c0+i, k = r0+j4 (t)
        const int k = r0 + j4;
        const size_t o = bo + ((size_t)(k >> 3) * HE + c0 + i) * 8 + (k & 7);
        *(ushort4*)&Th[o] = h;
        *(ushort4*)&Tl[o] = l;
    }
}

// ---------------------------------------------------------------------------
// split_misc_k8: one launch for dec (A-k8) + Wa^T + Ua^T (B-k8).
// grid (16, 32, 3): z=0 -> Wa (y<16), z=1 -> Ua (y<16), z=2 -> dec rows.
// ---------------------------------------------------------------------------
__global__ __launch_bounds__(256)
void split_misc_k8(const float* __restrict__ dec,
                   unsigned short* __restrict__ dH, unsigned short* __restrict__ dL,
                   const float* __restrict__ Wa,
                   unsigned short* __restrict__ wH, unsigned short* __restrict__ wL,
                   const float* __restrict__ Ua,
                   unsigned short* __restrict__ uH, unsigned short* __restrict__ uL)
{
    const int tid = threadIdx.x;
    const int i = tid >> 3, j4 = (tid & 7) * 4;
    const int z = blockIdx.z;

    if (z == 2) {
        // dec row-major [1024][512] -> A-k8
        const int r0 = blockIdx.y * 32, c0 = blockIdx.x * 32;
        const int M = BB * TD;
        const float4 v = *(const float4*)&dec[(size_t)(r0 + i) * HE + c0 + j4];
        ushort4 h, l;
        split2(v.x, h.x, l.x); split2(v.y, h.y, l.y);
        split2(v.z, h.z, l.z); split2(v.w, h.w, l.w);
        const int m = r0 + i, k = c0 + j4;
        const size_t o = ((size_t)(k >> 3) * M + m) * 8 + (k & 7);
        *(ushort4*)&dH[o] = h;
        *(ushort4*)&dL[o] = l;
        return;
    }

    if (blockIdx.y >= 16) return;
    __shared__ float t[32][33];
    const float* X = z ? Ua : Wa;
    unsigned short* H = z ? uH : wH;
    unsigned short* L = z ? uL : wL;
    const int r0 = blockIdx.y * 32, c0 = blockIdx.x * 32;

    const float4 v = *(const float4*)&X[(size_t)(r0 + i) * HE + c0 + j4];
    t[i][j4 + 0] = v.x; t[i][j4 + 1] = v.y; t[i][j4 + 2] = v.z; t[i][j4 + 3] = v.w;
    __syncthreads();

    ushort4 h, l;
    split2(t[j4 + 0][i], h.x, l.x);
    split2(t[j4 + 1][i], h.y, l.y);
    split2(t[j4 + 2][i], h.z, l.z);
    split2(t[j4 + 3][i], h.w, l.w);
    const int r = r0 + j4;                 // k index of B
    const size_t o = ((size_t)(r >> 3) * HE + c0 + i) * 8 + (r & 7);
    *(ushort4*)&H[o] = h;
    *(ushort4*)&L[o] = l;
}

// ---------------------------------------------------------------------------
// Merged Ws+Uh GEMM: grid (4, 72). y<64 -> Ew tile of enc@Wa (M=8192);
// y>=64 -> Eu tile of dec@Ua (M=1024). Same N=K=512, scale, exp2 epilogue.
// Split-bf16 MFMA on k8 operands, 2-phase double-buffered, tile 128x128 BK=32.
// ---------------------------------------------------------------------------
__global__ __launch_bounds__(256)
void gemm_ws_uh(const unsigned short* __restrict__ eAh, const unsigned short* __restrict__ eAl,
                const unsigned short* __restrict__ wBh, const unsigned short* __restrict__ wBl,
                float* __restrict__ Ew,
                const unsigned short* __restrict__ dAh, const unsigned short* __restrict__ dAl,
                const unsigned short* __restrict__ uBh, const unsigned short* __restrict__ uBl,
                float* __restrict__ Eu)
{
    __shared__ char smem[2][32768];

    const int tid  = threadIdx.x;
    const int lane = tid & 63;
    const int wave = tid >> 6;
    const int wr = wave >> 1, wc = wave & 1;
    const int fr = lane & 15, fg = lane >> 4;

    const unsigned short *Ahi, *Alo, *Bhi, *Blo;
    float* C;
    int M, row0;
    if (blockIdx.y < 64) {
        Ahi = eAh; Alo = eAl; Bhi = wBh; Blo = wBl; C = Ew;
        M = BB * TE; row0 = blockIdx.y * 128;
    } else {
        Ahi = dAh; Alo = dAl; Bhi = uBh; Blo = uBl; C = Eu;
        M = BB * TD; row0 = (blockIdx.y - 64) * 128;
    }
    const int N = HE, K = HE;
    const int col0 = blockIdx.x * 128;

    f32x4 acc[4][4];
#pragma unroll
    for (int mi = 0; mi < 4; ++mi)
#pragma unroll
        for (int ni = 0; ni < 4; ++ni)
            acc[mi][ni] = (f32x4){0.f, 0.f, 0.f, 0.f};

    auto STAGE = [&](int buf, int k0) {
#pragma unroll
        for (int c = 0; c < 2; ++c) {
            const int bi  = (c * 4 + wave) * 64 + lane;
            const int g   = bi >> 7;
            const int idx = bi & 127;
            int mrow = row0 + idx; if (mrow >= M) mrow -= M;
            const int ncol = col0 + idx;
            const size_t ao = ((size_t)((k0 >> 3) + g) * M + mrow) * 8;
            const size_t bo = ((size_t)((k0 >> 3) + g) * N + ncol) * 8;
            const int lb = (c * 4 + wave) * 1024;
            gload16(Ahi + ao, smem[buf] + lb);
            gload16(Alo + ao, smem[buf] + 8192 + lb);
            gload16(Bhi + bo, smem[buf] + 16384 + lb);
            gload16(Blo + bo, smem[buf] + 24576 + lb);
        }
    };

    STAGE(0, 0);
    __syncthreads();

    int buf = 0;
    for (int k0 = 0; k0 < K; k0 += 32) {
        if (k0 + 32 < K) STAGE(buf ^ 1, k0 + 32);

        const int gb = fg << 7;
        bf16x8 ah[4], al[4], bh[4], bl[4];
#pragma unroll
        for (int mi = 0; mi < 4; ++mi) {
            const int off = (gb + wr * 64 + mi * 16 + fr) * 16;
            ah[mi] = *(const bf16x8*)(smem[buf] + off);
            al[mi] = *(const bf16x8*)(smem[buf] + 8192 + off);
        }
#pragma unroll
        for (int ni = 0; ni < 4; ++ni) {
            const int off = (gb + wc * 64 + ni * 16 + fr) * 16;
            bh[ni] = *(const bf16x8*)(smem[buf] + 16384 + off);
            bl[ni] = *(const bf16x8*)(smem[buf] + 24576 + off);
        }
#pragma unroll
        for (int mi = 0; mi < 4; ++mi)
#pragma unroll
            for (int ni = 0; ni < 4; ++ni) {
                acc[mi][ni] = __builtin_amdgcn_mfma_f32_16x16x32_bf16(ah[mi], bh[ni], acc[mi][ni], 0, 0, 0);
                acc[mi][ni] = __builtin_amdgcn_mfma_f32_16x16x32_bf16(ah[mi], bl[ni], acc[mi][ni], 0, 0, 0);
                acc[mi][ni] = __builtin_amdgcn_mfma_f32_16x16x32_bf16(al[mi], bh[ni], acc[mi][ni], 0, 0, 0);
            }
        __syncthreads();
        buf ^= 1;
    }

#pragma unroll
    for (int mi = 0; mi < 4; ++mi) {
        const int rbase = row0 + wr * 64 + mi * 16 + fg * 4;
#pragma unroll
        for (int ni = 0; ni < 4; ++ni) {
            const int col = col0 + wc * 64 + ni * 16 + fr;
#pragma unroll
            for (int r = 0; r < 4; ++r) {
                const int row = rbase + r;
                if (row < M) C[(size_t)row * N + col] = fexp2(acc[mi][ni][r] * PRESCALE);
            }
        }
    }
}

// ---------------------------------------------------------------------------
// Batched context GEMM (same structure, generic): C = A @ B^T_layout
// ---------------------------------------------------------------------------
__global__ __launch_bounds__(256)
void gemm_mfma3(const unsigned short* __restrict__ Ahi, const unsigned short* __restrict__ Alo,
                const unsigned short* __restrict__ Bhi, const unsigned short* __restrict__ Blo,
                float* __restrict__ C, int M, int N, int K,
                long long sA, long long sB, long long sC)
{
    __shared__ char smem[2][32768];

    const int tid  = threadIdx.x;
    const int lane = tid & 63;
    const int wave = tid >> 6;
    const int wr = wave >> 1, wc = wave & 1;
    const int fr = lane & 15, fg = lane >> 4;
    const int row0 = blockIdx.y * 128;
    const int col0 = blockIdx.x * 128;

    Ahi += (size_t)blockIdx.z * sA; Alo += (size_t)blockIdx.z * sA;
    Bhi += (size_t)blockIdx.z * sB; Blo += (size_t)blockIdx.z * sB;
    C   += (size_t)blockIdx.z * sC;

    f32x4 acc[4][4];
#pragma unroll
    for (int mi = 0; mi < 4; ++mi)
#pragma unroll
        for (int ni = 0; ni < 4; ++ni)
            acc[mi][ni] = (f32x4){0.f, 0.f, 0.f, 0.f};

    auto STAGE = [&](int buf, int k0) {
#pragma unroll
        for (int c = 0; c < 2; ++c) {
            const int bi  = (c * 4 + wave) * 64 + lane;
            const int g   = bi >> 7;
            const int idx = bi & 127;
            int mrow = row0 + idx; if (mrow >= M) mrow -= M;
            const int ncol = col0 + idx;
            const size_t ao = ((size_t)((k0 >> 3) + g) * M + mrow) * 8;
            const size_t bo = ((size_t)((k0 >> 3) + g) * N + ncol) * 8;
            const int lb = (c * 4 + wave) * 1024;
            gload16(Ahi + ao, smem[buf] + lb);
            gload16(Alo + ao, smem[buf] + 8192 + lb);
            gload16(Bhi + bo, smem[buf] + 16384 + lb);
            gload16(Blo + bo, smem[buf] + 24576 + lb);
        }
    };

    STAGE(0, 0);
    __syncthreads();

    int buf = 0;
    for (int k0 = 0; k0 < K; k0 += 32) {
        if (k0 + 32 < K) STAGE(buf ^ 1, k0 + 32);

        const int gb = fg << 7;
        bf16x8 ah[4], al[4], bh[4], bl[4];
#pragma unroll
        for (int mi = 0; mi < 4; ++mi) {
            const int off = (gb + wr * 64 + mi * 16 + fr) * 16;
            ah[mi] = *(const bf16x8*)(smem[buf] + off);
            al[mi] = *(const bf16x8*)(smem[buf] + 8192 + off);
        }
#pragma unroll
        for (int ni = 0; ni < 4; ++ni) {
            const int off = (gb + wc * 64 + ni * 16 + fr) * 16;
            bh[ni] = *(const bf16x8*)(smem[buf] + 16384 + off);
            bl[ni] = *(const bf16x8*)(smem[buf] + 24576 + off);
        }
#pragma unroll
        for (int mi = 0; mi < 4; ++mi)
#pragma unroll
            for (int ni = 0; ni < 4; ++ni) {
                acc[mi][ni] = __builtin_amdgcn_mfma_f32_16x16x32_bf16(ah[mi], bh[ni], acc[mi][ni], 0, 0, 0);
                acc[mi][ni] = __builtin_amdgcn_mfma_f32_16x16x32_bf16(ah[mi], bl[ni], acc[mi][ni], 0, 0, 0);
                acc[mi][ni] = __builtin_amdgcn_mfma_f32_16x16x32_bf16(al[mi], bh[ni], acc[mi][ni], 0, 0, 0);
            }
        __syncthreads();
        buf ^= 1;
    }

#pragma unroll
    for (int mi = 0; mi < 4; ++mi) {
        const int rbase = row0 + wr * 64 + mi * 16 + fg * 4;
#pragma unroll
        for (int ni = 0; ni < 4; ++ni) {
            const int col = col0 + wc * 64 + ni * 16 + fr;
#pragma unroll
            for (int r = 0; r < 4; ++r) {
                const int row = rbase + r;
                if (row < M) C[(size_t)row * N + col] = acc[mi][ni][r];
            }
        }
    }
}

// ---------------------------------------------------------------------------
// Fallback fp32 GEMM (used if ws_size is too small)
// ---------------------------------------------------------------------------
__global__ __launch_bounds__(256)
void gemm_f32(const float* __restrict__ A, const float* __restrict__ Bm,
              float* __restrict__ C, int M, int N, int K,
              long long sAb, long long sBb, long long sCb, float scale, int emode)
{
    __shared__ float As[16][68];
    __shared__ float Bs[16][68];

    const int tid = threadIdx.x;
    const int tx  = tid & 15;
    const int ty  = tid >> 4;
    const int row0 = blockIdx.y * 64;
    const int col0 = blockIdx.x * 64;

    A  += (long long)blockIdx.z * sAb;
    Bm += (long long)blockIdx.z * sBb;
    C  += (long long)blockIdx.z * sCb;

    float acc[4][4] = {};

    for (int k0 = 0; k0 < K; k0 += 16) {
        {
            const int r = tid >> 2;
            const int c = (tid & 3) * 4;
            const float4 av = *(const float4*)&A[(long long)(row0 + r) * K + k0 + c];
            As[c + 0][r] = av.x; As[c + 1][r] = av.y;
            As[c + 2][r] = av.z; As[c + 3][r] = av.w;
        }
        {
            const int r = tid >> 4;
            const int c = (tid & 15) * 4;
            *(float4*)&Bs[r][c] = *(const float4*)&Bm[(long long)(k0 + r) * N + col0 + c];
        }
        __syncthreads();

#pragma unroll
        for (int kk = 0; kk < 16; ++kk) {
            const float4 a = *(const float4*)&As[kk][ty * 4];
            const float4 b = *(const float4*)&Bs[kk][tx * 4];
            acc[0][0] += a.x * b.x; acc[0][1] += a.x * b.y; acc[0][2] += a.x * b.z; acc[0][3] += a.x * b.w;
            acc[1][0] += a.y * b.x; acc[1][1] += a.y * b.y; acc[1][2] += a.y * b.z; acc[1][3] += a.y * b.w;
            acc[2][0] += a.z * b.x; acc[2][1] += a.z * b.y; acc[2][2] += a.z * b.z; acc[2][3] += a.z * b.w;
            acc[3][0] += a.w * b.x; acc[3][1] += a.w * b.y; acc[3][2] += a.w * b.z; acc[3][3] += a.w * b.w;
        }
        __syncthreads();
    }

#pragma unroll
    for (int i = 0; i < 4; ++i) {
        float4 o;
        o.x = acc[i][0] * scale; o.y = acc[i][1] * scale;
        o.z = acc[i][2] * scale; o.w = acc[i][3] * scale;
        if (emode) { o.x = fexp2(o.x); o.y = fexp2(o.y); o.z = fexp2(o.z); o.w = fexp2(o.w); }
        *(float4*)&C[(long long)(row0 + ty * 4 + i) * N + col0 + tx * 4] = o;
    }
}

// ---------------------------------------------------------------------------
// Raw score PARTIALS over an h-quarter: part[q][b,d,t] =
//   sum_{h in quarter q} (-2 V[h]) / (Ew[b,t,h]*Eu[b,d,h] + 1)
// h-split x4 -> 2048 blocks (8/CU, 32 waves/CU = HW max occupancy for
// the 18.4 KB LDS footprint). Inner loop / thread map / swizzle unchanged.
// ---------------------------------------------------------------------------
__global__ __launch_bounds__(256)
void scores_raw(const float* __restrict__ Ew, const float* __restrict__ Eu,
                const float* __restrict__ V, float* __restrict__ part)
{
    __shared__ float Ws_s[32][64];   // [t][h-chunk], col4 ^= (row>>2)&7
    __shared__ float Uh_s[32][64];   // [d][h-chunk], col4 ^= row&7
    __shared__ float Vr_s[HE];       // -2*V

    const int tid = threadIdx.x;
    const int tg  = tid & 7;     // t-group: t = tt0 + tg*4 + i
    const int dg  = tid >> 3;    // d = d0 + dg   (0..31)

    const int tt0  = blockIdx.x * 32;
    const int quar = blockIdx.y & 3;
    const int d0   = (blockIdx.y >> 2) * 32;
    const int b    = blockIdx.z;

    const float* Wsg = Ew + (long long)b * TE * HE;
    const float* Uhg = Eu + ((long long)b * TD + d0) * HE;

    if (tid < 128) {
        const float4 v = *(const float4*)&V[tid * 4];
        float4 o; o.x = -2.f * v.x; o.y = -2.f * v.y; o.z = -2.f * v.z; o.w = -2.f * v.w;
        *(float4*)&Vr_s[tid * 4] = o;
    }

    float acc[4] = {0.f, 0.f, 0.f, 0.f};
    const int wswz = tg & 7;
    const int uswz = dg & 7;
    const int hbase = quar * (HE / 4);

    for (int hc = hbase; hc < hbase + HE / 4; hc += 64) {
        __syncthreads();
#pragma unroll
        for (int k = 0; k < 2; ++k) {
            const int idx = tid + k * 256;
            const int r   = idx >> 4;
            const int c4  = idx & 15;
            const float4 wv = *(const float4*)&Wsg[(long long)(tt0 + r) * HE + hc + c4 * 4];
            *(float4*)&Ws_s[r][(c4 ^ ((r >> 2) & 7)) * 4] = wv;
            const float4 uv = *(const float4*)&Uhg[(long long)r * HE + hc + c4 * 4];
            *(float4*)&Uh_s[r][(c4 ^ (r & 7)) * 4] = uv;
        }
        __syncthreads();

#pragma unroll 4
        for (int hs = 0; hs < 64; hs += 4) {
            const int h4 = hs >> 2;
            const float4 vv = *(const float4*)&Vr_s[hc + hs];
            const float4 u  = *(const float4*)&Uh_s[dg][(h4 ^ uswz) * 4];
#pragma unroll
            for (int i = 0; i < 4; ++i) {
                const float4 w = *(const float4*)&Ws_s[tg * 4 + i][(h4 ^ wswz) * 4];
                acc[i] = fmaf(vv.x, frcp(fmaf(w.x, u.x, 1.f)), acc[i]);
                acc[i] = fmaf(vv.y, frcp(fmaf(w.y, u.y, 1.f)), acc[i]);
                acc[i] = fmaf(vv.z, frcp(fmaf(w.z, u.z, 1.f)), acc[i]);
                acc[i] = fmaf(vv.w, frcp(fmaf(w.w, u.w, 1.f)), acc[i]);
            }
        }
    }

    float* dst = part + (size_t)quar * (BB * TD * TE);
    float4 o; o.x = acc[0]; o.y = acc[1]; o.z = acc[2]; o.w = acc[3];
    *(float4*)&dst[((long long)b * TD + d0 + dg) * TE + tt0 + tg * 4] = o;
}

// ---------------------------------------------------------------------------
// Row softmax over 4 summed partials -> e (fp32) + optional A-k8 bf16 split
// ---------------------------------------------------------------------------
__global__ __launch_bounds__(256)
void softmax_rows(const float* __restrict__ part, float* __restrict__ e,
                  unsigned short* __restrict__ H, unsigned short* __restrict__ L)
{
    const int lane = threadIdx.x & 63;
    const int wave = threadIdx.x >> 6;
    const long long row = blockIdx.x * 4 + wave;

    float4 a = {0.f, 0.f, 0.f, 0.f}, c = {0.f, 0.f, 0.f, 0.f};
#pragma unroll
    for (int q = 0; q < 4; ++q) {
        const float* p = part + (size_t)q * (BB * TD * TE) + row * TE;
        const float4 aq = *(const float4*)&p[lane * 4];
        const float4 cq = *(const float4*)&p[lane * 4 + 256];
        a.x += aq.x; a.y += aq.y; a.z += aq.z; a.w += aq.w;
        c.x += cq.x; c.y += cq.y; c.z += cq.z; c.w += cq.w;
    }

    float m = fmaxf(fmaxf(fmaxf(a.x, a.y), fmaxf(a.z, a.w)),
                    fmaxf(fmaxf(c.x, c.y), fmaxf(c.z, c.w)));
#pragma unroll
    for (int off = 32; off; off >>= 1) m = fmaxf(m, __shfl_xor(m, off));

    a.x = __expf(a.x - m); a.y = __expf(a.y - m); a.z = __expf(a.z - m); a.w = __expf(a.w - m);
    c.x = __expf(c.x - m); c.y = __expf(c.y - m); c.z = __expf(c.z - m); c.w = __expf(c.w - m);

    float s = (a.x + a.y + a.z + a.w) + (c.x + c.y + c.z + c.w);
#pragma unroll
    for (int off = 32; off; off >>= 1) s += __shfl_xor(s, off);

    const float inv = __fdividef(1.f, s);
    a.x *= inv; a.y *= inv; a.z *= inv; a.w *= inv;
    c.x *= inv; c.y *= inv; c.z *= inv; c.w *= inv;
    float* pe = e + row * TE;
    *(float4*)&pe[lane * 4] = a;
    *(float4*)&pe[lane * 4 + 256] = c;

    if (H) {
        const int b = (int)(row >> 6);
        const int d = (int)(row & 63);
        const size_t base = (size_t)b * (TD * TE);
        ushort4 h, l;
        {
            const int t0 = lane * 4;
            const size_t o = base + ((size_t)(t0 >> 3) * TD + d) * 8 + (t0 & 7);
            split2(a.x, h.x, l.x); split2(a.y, h.y, l.y);
            split2(a.z, h.z, l.z); split2(a.w, h.w, l.w);
            *(ushort4*)&H[o] = h;
            *(ushort4*)&L[o] = l;
        }
        {
            const int t0 = lane * 4 + 256;
            const size_t o = base + ((size_t)(t0 >> 3) * TD + d) * 8 + (t0 & 7);
            split2(c.x, h.x, l.x); split2(c.y, h.y, l.y);
            split2(c.z, h.z, l.z); split2(c.w, h.w, l.w);
            *(ushort4*)&H[o] = h;
            *(ushort4*)&L[o] = l;
        }
    }
}

// ---------------------------------------------------------------------------
extern "C" void kernel_launch(void* const* d_in, const int* in_sizes, int n_in,
                              void* d_out, int out_size, void* d_ws, size_t ws_size,
                              hipStream_t stream)
{
    const float* enc = (const float*)d_in[0];  // [B,TE,HE]
    const float* dec = (const float*)d_in[1];  // [B,TD,HD=HE]
    const float* Wa  = (const float*)d_in[2];  // [HE,HE]
    const float* Ua  = (const float*)d_in[3];  // [HD,HE]
    const float* Va  = (const float*)d_in[4];  // [HE,1] -> flat [HE]

    float* out   = (float*)d_out;
    float* c_out = out;                        // [B,TD,HE]
    float* e_out = out + (size_t)BB * TD * HE; // [B,TD,TE]

    char* w = (char*)d_ws;
    float* Ew  = (float*)(w);                                  // 16,777,216 B (exp2'd Ws)
    float* Eu  = (float*)(w + 16777216);                       //  2,097,152 B (exp2'd Uh)
    unsigned short* encAh = (unsigned short*)(w + 18874368);   //  8,388,608 B  (A-k8)
    unsigned short* encAl = (unsigned short*)(w + 27262976);
    unsigned short* encTh = (unsigned short*)(w + 35651584);   //  (B-k8 per batch)
    unsigned short* encTl = (unsigned short*)(w + 44040192);
    unsigned short* decAh = (unsigned short*)(w + 52428800);   //  1,048,576 B
    unsigned short* decAl = (unsigned short*)(w + 53477376);
    unsigned short* WaTh  = (unsigned short*)(w + 54525952);   //    524,288 B
    unsigned short* WaTl  = (unsigned short*)(w + 55050240);
    unsigned short* UaTh  = (unsigned short*)(w + 55574528);
    unsigned short* UaTl  = (unsigned short*)(w + 56098816);
    unsigned short* eh    = (unsigned short*)(w + 56623104);   //  1,048,576 B (A-k8/batch)
    unsigned short* el    = (unsigned short*)(w + 57671680);
    float* part = (float*)(w + 58720256);                      //  8,388,608 B (4 x 2 MB)
    const size_t REQUIRED = 67108864;

    dim3 blk(256);

    if (ws_size >= REQUIRED) {
        // --- split/transpose conversions (k8-interleaved outputs), 2 launches ---
        split_enc_k8<<<dim3(16, 16, BB), blk, 0, stream>>>(enc, encAh, encAl, encTh, encTl);
        split_misc_k8<<<dim3(16, 32, 3), blk, 0, stream>>>(
            dec, decAh, decAl, Wa, WaTh, WaTl, Ua, UaTh, UaTl);

        // Ew = exp2(PRESCALE * enc @ W_a) and Eu = exp2(PRESCALE * dec @ U_a), one launch
        gemm_ws_uh<<<dim3(4, 72, 1), blk, 0, stream>>>(
            encAh, encAl, WaTh, WaTl, Ew, decAh, decAl, UaTh, UaTl, Eu);

        // raw score partials (h-split x4): grid y = d-tile*4 + quarter
        scores_raw<<<dim3(TE / 32, (TD / 32) * 4, BB), blk, 0, stream>>>(Ew, Eu, Va, part);
        softmax_rows<<<dim3(BB * TD / 4), blk, 0, stream>>>(part, e_out, eh, el);

        // c[b] = e[b] @ enc[b]   (M=64 valid of 128-tile, batched)
        gemm_mfma3<<<dim3(4, 1, BB), blk, 0, stream>>>(
            eh, el, encTh, encTl, c_out, TD, HE, TE,
            (long long)TD * TE, (long long)TE * HE, (long long)TD * HE);
    } else {
        // --- fallback: fp32 path (partials after Eu; needs ~27 MB) ---
        float* pf = (float*)(w + 18874368);
        gemm_f32<<<dim3(HE / 64, (BB * TE) / 64, 1), blk, 0, stream>>>(
            enc, Wa, Ew, BB * TE, HE, HE, 0, 0, 0, PRESCALE, 1);
        gemm_f32<<<dim3(HE / 64, (BB * TD) / 64, 1), blk, 0, stream>>>(
            dec, Ua, Eu, BB * TD, HE, HE, 0, 0, 0, PRESCALE, 1);
        scores_raw<<<dim3(TE / 32, (TD / 32) * 4, BB), blk, 0, stream>>>(Ew, Eu, Va, pf);
        softmax_rows<<<dim3(BB * TD / 4), blk, 0, stream>>>(pf, e_out, nullptr, nullptr);
        gemm_f32<<<dim3(HE / 64, TD / 64, BB), blk, 0, stream>>>(
            e_out, enc, c_out, TD, HE, TE,
            (long long)TD * TE, (long long)TE * HE, (long long)TD * HE, 1.0f, 0);
    }
}

// Round 13
// 90.699 us; speedup vs baseline: 3.4726x; 1.0156x over previous
//
#include <hip/hip_runtime.h>
#include <hip/hip_bf16.h>

#define BB 16
#define TE 512
#define TD 64
#define HE 512

// 2*log2(e): folded into Ws/Uh GEMM epilogue (with exp2) so the scores inner
// loop needs no exp at all: tanh term via 1/(Ew*Eu+1).
#define PRESCALE 2.8853900817779268f

typedef __attribute__((ext_vector_type(8))) short bf16x8;
typedef __attribute__((ext_vector_type(4))) float f32x4;

__device__ __forceinline__ float fexp2(float x) {
#if __has_builtin(__builtin_amdgcn_exp2f)
    return __builtin_amdgcn_exp2f(x);
#else
    return exp2f(x);
#endif
}
__device__ __forceinline__ float frcp(float x) {
#if __has_builtin(__builtin_amdgcn_rcpf)
    return __builtin_amdgcn_rcpf(x);
#else
    return __fdividef(1.f, x);
#endif
}

// split fp32 -> bf16 hi + bf16 lo (x ~= hi + lo, ~2^-17 relative)
__device__ __forceinline__ void split2(float x, unsigned short& h, unsigned short& l) {
    __hip_bfloat16 hb = __float2bfloat16(x);
    h = *(unsigned short*)&hb;
    float r = x - __bfloat162float(hb);
    __hip_bfloat16 lb = __float2bfloat16(r);
    l = *(unsigned short*)&lb;
}

__device__ __forceinline__ void gload16(const unsigned short* g, void* l) {
    __builtin_amdgcn_global_load_lds(
        (const __attribute__((address_space(1))) unsigned int*)g,
        (__attribute__((address_space(3))) unsigned int*)l, 16, 0, 0);
}

// ===========================================================================
// k8-interleaved operand layout:  Xp[s][r][j] = X[r][s*8+j],  s = k/8, j = k%8
// flat index = (s*R + r)*8 + j.  Both GEMM staging loads AND the split-kernel
// writes are fully coalesced (1 KB contiguous per wave op).
// ===========================================================================

// --- 64x64 fp32 tile helpers, XOR-swizzled in 16B units: logical float4-col
// c4 of row r lives at physical col (c4 ^ (r&7)). All reads <=2-way banked. ---

__device__ __forceinline__ void tile_load(const float* __restrict__ src, int ld,
                                          float (*tile)[64], int tid)
{
#pragma unroll
    for (int p = 0; p < 4; ++p) {
        const int f = p * 256 + tid;
        const int r = f >> 4, c4 = f & 15;
        const float4 v = *(const float4*)&src[(size_t)r * ld + c4 * 4];
        *(float4*)&tile[r][((c4 ^ (r & 7))) << 2] = v;
    }
}

// A-k8 output: element (m_base+mm, k = 8*(sg_base+s)+j) -> H/L[((sg)*Ms+m)*8+j]
__device__ __forceinline__ void tile_outA(float (*tile)[64],
                                          unsigned short* __restrict__ H,
                                          unsigned short* __restrict__ L,
                                          size_t Ms, size_t sg_base, size_t m_base, int tid)
{
#pragma unroll
    for (int p = 0; p < 2; ++p) {
        const int task = p * 256 + tid;
        const int s = task >> 6, mm = task & 63;
        const float4 x = *(const float4*)&tile[mm][(((s << 1)    ) ^ (mm & 7)) << 2];
        const float4 y = *(const float4*)&tile[mm][(((s << 1) | 1) ^ (mm & 7)) << 2];
        ushort4 ha, la, hb, lb;
        split2(x.x, ha.x, la.x); split2(x.y, ha.y, la.y);
        split2(x.z, ha.z, la.z); split2(x.w, ha.w, la.w);
        split2(y.x, hb.x, lb.x); split2(y.y, hb.y, lb.y);
        split2(y.z, hb.z, lb.z); split2(y.w, hb.w, lb.w);
        const size_t o = ((sg_base + s) * Ms + m_base + mm) * 8;
        *(ushort4*)&H[o] = ha; *(ushort4*)&H[o + 4] = hb;
        *(ushort4*)&L[o] = la; *(ushort4*)&L[o + 4] = lb;
    }
}

// T-k8 output (B-k8 of tile^T): element (n_base+hh, k = 8*(sg_base+s2)+q)
__device__ __forceinline__ void tile_outT(float (*tile)[64],
                                          unsigned short* __restrict__ H,
                                          unsigned short* __restrict__ L,
                                          size_t Ns, size_t sg_base, size_t n_base, int tid)
{
#pragma unroll
    for (int p = 0; p < 2; ++p) {
        const int task = p * 256 + tid;
        const int s2 = task >> 6, hh = task & 63;
        float v[8];
#pragma unroll
        for (int q = 0; q < 8; ++q) {
            const int r = s2 * 8 + q;
            v[q] = tile[r][((((hh >> 2)) ^ (r & 7)) << 2) + (hh & 3)];
        }
        ushort4 ha, la, hb, lb;
        split2(v[0], ha.x, la.x); split2(v[1], ha.y, la.y);
        split2(v[2], ha.z, la.z); split2(v[3], ha.w, la.w);
        split2(v[4], hb.x, lb.x); split2(v[5], hb.y, lb.y);
        split2(v[6], hb.z, lb.z); split2(v[7], hb.w, lb.w);
        const size_t o = ((sg_base + s2) * Ns + n_base + hh) * 8;
        *(ushort4*)&H[o] = ha; *(ushort4*)&H[o + 4] = hb;
        *(ushort4*)&L[o] = la; *(ushort4*)&L[o + 4] = lb;
    }
}

// ---------------------------------------------------------------------------
// split_enc_k8: enc [B][TE][HE] -> A-k8 (fused m=b*TE+t, K=HE) + per-batch
// B-k8 of enc^T (n=h, k=t). Grid (HE/64, TE/64, BB). Coalesced 1KB writes.
// ---------------------------------------------------------------------------
__global__ __launch_bounds__(256)
void split_enc_k8(const float* __restrict__ X,
                  unsigned short* __restrict__ Ah, unsigned short* __restrict__ Al,
                  unsigned short* __restrict__ Th, unsigned short* __restrict__ Tl)
{
    __shared__ float tile[64][64];
    const int tid = threadIdx.x;
    const int h0 = blockIdx.x * 64, t0 = blockIdx.y * 64, b = blockIdx.z;
    const size_t bo = (size_t)b * TE * HE;

    tile_load(X + bo + (size_t)t0 * HE + h0, HE, tile, tid);
    __syncthreads();

    tile_outA(tile, Ah, Al, (size_t)BB * TE, h0 >> 3, (size_t)b * TE + t0, tid);
    tile_outT(tile, Th + bo, Tl + bo, HE, t0 >> 3, h0, tid);
}

// ---------------------------------------------------------------------------
// split_misc_k8: z=0 -> Wa^T B-k8 (y<8), z=1 -> Ua^T B-k8 (y<8), z=2 -> dec A-k8.
// Grid (8, 16, 3). Coalesced writes via the same tile helpers.
// ---------------------------------------------------------------------------
__global__ __launch_bounds__(256)
void split_misc_k8(const float* __restrict__ dec,
                   unsigned short* __restrict__ dH, unsigned short* __restrict__ dL,
                   const float* __restrict__ Wa,
                   unsigned short* __restrict__ wH, unsigned short* __restrict__ wL,
                   const float* __restrict__ Ua,
                   unsigned short* __restrict__ uH, unsigned short* __restrict__ uL)
{
    __shared__ float tile[64][64];
    const int tid = threadIdx.x;
    const int z = blockIdx.z;

    if (z == 2) {
        const int m0 = blockIdx.y * 64, h0 = blockIdx.x * 64;
        tile_load(dec + (size_t)m0 * HE + h0, HE, tile, tid);
        __syncthreads();
        tile_outA(tile, dH, dL, (size_t)BB * TD, h0 >> 3, m0, tid);
        return;
    }
    if (blockIdx.y >= 8) return;
    const float* X = z ? Ua : Wa;
    unsigned short* H = z ? uH : wH;
    unsigned short* L = z ? uL : wL;
    const int r0 = blockIdx.y * 64, c0 = blockIdx.x * 64;
    tile_load(X + (size_t)r0 * HE + c0, HE, tile, tid);
    __syncthreads();
    tile_outT(tile, H, L, HE, r0 >> 3, c0, tid);
}

// ---------------------------------------------------------------------------
// Merged Ws+Uh GEMM: grid (4, 72). y<64 -> Ew tile (M=8192); y>=64 -> Eu
// (M=1024). Split-bf16 MFMA, k8 operands, 2-phase dbuf with COUNTED vmcnt:
// STAGE(next); s_waitcnt vmcnt(8)+s_barrier (cur loads done, next's 8 stay
// in flight); compute; s_barrier (reads done before next overwrite).
// ---------------------------------------------------------------------------
__global__ __launch_bounds__(256)
void gemm_ws_uh(const unsigned short* __restrict__ eAh, const unsigned short* __restrict__ eAl,
                const unsigned short* __restrict__ wBh, const unsigned short* __restrict__ wBl,
                float* __restrict__ Ew,
                const unsigned short* __restrict__ dAh, const unsigned short* __restrict__ dAl,
                const unsigned short* __restrict__ uBh, const unsigned short* __restrict__ uBl,
                float* __restrict__ Eu)
{
    __shared__ char smem[2][32768];

    const int tid  = threadIdx.x;
    const int lane = tid & 63;
    const int wave = tid >> 6;
    const int wr = wave >> 1, wc = wave & 1;
    const int fr = lane & 15, fg = lane >> 4;

    const unsigned short *Ahi, *Alo, *Bhi, *Blo;
    float* C;
    int M, row0;
    if (blockIdx.y < 64) {
        Ahi = eAh; Alo = eAl; Bhi = wBh; Blo = wBl; C = Ew;
        M = BB * TE; row0 = blockIdx.y * 128;
    } else {
        Ahi = dAh; Alo = dAl; Bhi = uBh; Blo = uBl; C = Eu;
        M = BB * TD; row0 = (blockIdx.y - 64) * 128;
    }
    const int N = HE, K = HE;
    const int col0 = blockIdx.x * 128;

    f32x4 acc[4][4];
#pragma unroll
    for (int mi = 0; mi < 4; ++mi)
#pragma unroll
        for (int ni = 0; ni < 4; ++ni)
            acc[mi][ni] = (f32x4){0.f, 0.f, 0.f, 0.f};

    auto STAGE = [&](int buf, int k0) {
#pragma unroll
        for (int c = 0; c < 2; ++c) {
            const int bi  = (c * 4 + wave) * 64 + lane;
            const int g   = bi >> 7;
            const int idx = bi & 127;
            int mrow = row0 + idx; if (mrow >= M) mrow -= M;
            const int ncol = col0 + idx;
            const size_t ao = ((size_t)((k0 >> 3) + g) * M + mrow) * 8;
            const size_t bo = ((size_t)((k0 >> 3) + g) * N + ncol) * 8;
            const int lb = (c * 4 + wave) * 1024;
            gload16(Ahi + ao, smem[buf] + lb);
            gload16(Alo + ao, smem[buf] + 8192 + lb);
            gload16(Bhi + bo, smem[buf] + 16384 + lb);
            gload16(Blo + bo, smem[buf] + 24576 + lb);
        }
    };

    STAGE(0, 0);

    int buf = 0;
    for (int k0 = 0; k0 < K; k0 += 32) {
        if (k0 + 32 < K) {
            STAGE(buf ^ 1, k0 + 32);
            asm volatile("s_waitcnt vmcnt(8)\n\ts_barrier" ::: "memory");
        } else {
            asm volatile("s_waitcnt vmcnt(0)\n\ts_barrier" ::: "memory");
        }

        const int gb = fg << 7;
        bf16x8 ah[4], al[4], bh[4], bl[4];
#pragma unroll
        for (int mi = 0; mi < 4; ++mi) {
            const int off = (gb + wr * 64 + mi * 16 + fr) * 16;
            ah[mi] = *(const bf16x8*)(smem[buf] + off);
            al[mi] = *(const bf16x8*)(smem[buf] + 8192 + off);
        }
#pragma unroll
        for (int ni = 0; ni < 4; ++ni) {
            const int off = (gb + wc * 64 + ni * 16 + fr) * 16;
            bh[ni] = *(const bf16x8*)(smem[buf] + 16384 + off);
            bl[ni] = *(const bf16x8*)(smem[buf] + 24576 + off);
        }
#pragma unroll
        for (int mi = 0; mi < 4; ++mi)
#pragma unroll
            for (int ni = 0; ni < 4; ++ni) {
                acc[mi][ni] = __builtin_amdgcn_mfma_f32_16x16x32_bf16(ah[mi], bh[ni], acc[mi][ni], 0, 0, 0);
                acc[mi][ni] = __builtin_amdgcn_mfma_f32_16x16x32_bf16(ah[mi], bl[ni], acc[mi][ni], 0, 0, 0);
                acc[mi][ni] = __builtin_amdgcn_mfma_f32_16x16x32_bf16(al[mi], bh[ni], acc[mi][ni], 0, 0, 0);
            }
        asm volatile("s_barrier" ::: "memory");
        buf ^= 1;
    }

#pragma unroll
    for (int mi = 0; mi < 4; ++mi) {
        const int rbase = row0 + wr * 64 + mi * 16 + fg * 4;
#pragma unroll
        for (int ni = 0; ni < 4; ++ni) {
            const int col = col0 + wc * 64 + ni * 16 + fr;
#pragma unroll
            for (int r = 0; r < 4; ++r) {
                const int row = rbase + r;
                if (row < M) C[(size_t)row * N + col] = fexp2(acc[mi][ni][r] * PRESCALE);
            }
        }
    }
}

// ---------------------------------------------------------------------------
// Batched context GEMM (same counted-vmcnt structure): C = A @ B^T_layout
// ---------------------------------------------------------------------------
__global__ __launch_bounds__(256)
void gemm_mfma3(const unsigned short* __restrict__ Ahi, const unsigned short* __restrict__ Alo,
                const unsigned short* __restrict__ Bhi, const unsigned short* __restrict__ Blo,
                float* __restrict__ C, int M, int N, int K,
                long long sA, long long sB, long long sC)
{
    __shared__ char smem[2][32768];

    const int tid  = threadIdx.x;
    const int lane = tid & 63;
    const int wave = tid >> 6;
    const int wr = wave >> 1, wc = wave & 1;
    const int fr = lane & 15, fg = lane >> 4;
    const int row0 = blockIdx.y * 128;
    const int col0 = blockIdx.x * 128;

    Ahi += (size_t)blockIdx.z * sA; Alo += (size_t)blockIdx.z * sA;
    Bhi += (size_t)blockIdx.z * sB; Blo += (size_t)blockIdx.z * sB;
    C   += (size_t)blockIdx.z * sC;

    f32x4 acc[4][4];
#pragma unroll
    for (int mi = 0; mi < 4; ++mi)
#pragma unroll
        for (int ni = 0; ni < 4; ++ni)
            acc[mi][ni] = (f32x4){0.f, 0.f, 0.f, 0.f};

    auto STAGE = [&](int buf, int k0) {
#pragma unroll
        for (int c = 0; c < 2; ++c) {
            const int bi  = (c * 4 + wave) * 64 + lane;
            const int g   = bi >> 7;
            const int idx = bi & 127;
            int mrow = row0 + idx; if (mrow >= M) mrow -= M;
            const int ncol = col0 + idx;
            const size_t ao = ((size_t)((k0 >> 3) + g) * M + mrow) * 8;
            const size_t bo = ((size_t)((k0 >> 3) + g) * N + ncol) * 8;
            const int lb = (c * 4 + wave) * 1024;
            gload16(Ahi + ao, smem[buf] + lb);
            gload16(Alo + ao, smem[buf] + 8192 + lb);
            gload16(Bhi + bo, smem[buf] + 16384 + lb);
            gload16(Blo + bo, smem[buf] + 24576 + lb);
        }
    };

    STAGE(0, 0);

    int buf = 0;
    for (int k0 = 0; k0 < K; k0 += 32) {
        if (k0 + 32 < K) {
            STAGE(buf ^ 1, k0 + 32);
            asm volatile("s_waitcnt vmcnt(8)\n\ts_barrier" ::: "memory");
        } else {
            asm volatile("s_waitcnt vmcnt(0)\n\ts_barrier" ::: "memory");
        }

        const int gb = fg << 7;
        bf16x8 ah[4], al[4], bh[4], bl[4];
#pragma unroll
        for (int mi = 0; mi < 4; ++mi) {
            const int off = (gb + wr * 64 + mi * 16 + fr) * 16;
            ah[mi] = *(const bf16x8*)(smem[buf] + off);
            al[mi] = *(const bf16x8*)(smem[buf] + 8192 + off);
        }
#pragma unroll
        for (int ni = 0; ni < 4; ++ni) {
            const int off = (gb + wc * 64 + ni * 16 + fr) * 16;
            bh[ni] = *(const bf16x8*)(smem[buf] + 16384 + off);
            bl[ni] = *(const bf16x8*)(smem[buf] + 24576 + off);
        }
#pragma unroll
        for (int mi = 0; mi < 4; ++mi)
#pragma unroll
            for (int ni = 0; ni < 4; ++ni) {
                acc[mi][ni] = __builtin_amdgcn_mfma_f32_16x16x32_bf16(ah[mi], bh[ni], acc[mi][ni], 0, 0, 0);
                acc[mi][ni] = __builtin_amdgcn_mfma_f32_16x16x32_bf16(ah[mi], bl[ni], acc[mi][ni], 0, 0, 0);
                acc[mi][ni] = __builtin_amdgcn_mfma_f32_16x16x32_bf16(al[mi], bh[ni], acc[mi][ni], 0, 0, 0);
            }
        asm volatile("s_barrier" ::: "memory");
        buf ^= 1;
    }

#pragma unroll
    for (int mi = 0; mi < 4; ++mi) {
        const int rbase = row0 + wr * 64 + mi * 16 + fg * 4;
#pragma unroll
        for (int ni = 0; ni < 4; ++ni) {
            const int col = col0 + wc * 64 + ni * 16 + fr;
#pragma unroll
            for (int r = 0; r < 4; ++r) {
                const int row = rbase + r;
                if (row < M) C[(size_t)row * N + col] = acc[mi][ni][r];
            }
        }
    }
}

// ---------------------------------------------------------------------------
// Fallback fp32 GEMM (used if ws_size is too small)
// ---------------------------------------------------------------------------
__global__ __launch_bounds__(256)
void gemm_f32(const float* __restrict__ A, const float* __restrict__ Bm,
              float* __restrict__ C, int M, int N, int K,
              long long sAb, long long sBb, long long sCb, float scale, int emode)
{
    __shared__ float As[16][68];
    __shared__ float Bs[16][68];

    const int tid = threadIdx.x;
    const int tx  = tid & 15;
    const int ty  = tid >> 4;
    const int row0 = blockIdx.y * 64;
    const int col0 = blockIdx.x * 64;

    A  += (long long)blockIdx.z * sAb;
    Bm += (long long)blockIdx.z * sBb;
    C  += (long long)blockIdx.z * sCb;

    float acc[4][4] = {};

    for (int k0 = 0; k0 < K; k0 += 16) {
        {
            const int r = tid >> 2;
            const int c = (tid & 3) * 4;
            const float4 av = *(const float4*)&A[(long long)(row0 + r) * K + k0 + c];
            As[c + 0][r] = av.x; As[c + 1][r] = av.y;
            As[c + 2][r] = av.z; As[c + 3][r] = av.w;
        }
        {
            const int r = tid >> 4;
            const int c = (tid & 15) * 4;
            *(float4*)&Bs[r][c] = *(const float4*)&Bm[(long long)(k0 + r) * N + col0 + c];
        }
        __syncthreads();

#pragma unroll
        for (int kk = 0; kk < 16; ++kk) {
            const float4 a = *(const float4*)&As[kk][ty * 4];
            const float4 b = *(const float4*)&Bs[kk][tx * 4];
            acc[0][0] += a.x * b.x; acc[0][1] += a.x * b.y; acc[0][2] += a.x * b.z; acc[0][3] += a.x * b.w;
            acc[1][0] += a.y * b.x; acc[1][1] += a.y * b.y; acc[1][2] += a.y * b.z; acc[1][3] += a.y * b.w;
            acc[2][0] += a.z * b.x; acc[2][1] += a.z * b.y; acc[2][2] += a.z * b.z; acc[2][3] += a.z * b.w;
            acc[3][0] += a.w * b.x; acc[3][1] += a.w * b.y; acc[3][2] += a.w * b.z; acc[3][3] += a.w * b.w;
        }
        __syncthreads();
    }

#pragma unroll
    for (int i = 0; i < 4; ++i) {
        float4 o;
        o.x = acc[i][0] * scale; o.y = acc[i][1] * scale;
        o.z = acc[i][2] * scale; o.w = acc[i][3] * scale;
        if (emode) { o.x = fexp2(o.x); o.y = fexp2(o.y); o.z = fexp2(o.z); o.w = fexp2(o.w); }
        *(float4*)&C[(long long)(row0 + ty * 4 + i) * N + col0 + tx * 4] = o;
    }
}

// ---------------------------------------------------------------------------
// Raw score PARTIALS over an h-quarter (proven round-12 structure, 8 blk/CU)
// ---------------------------------------------------------------------------
__global__ __launch_bounds__(256)
void scores_raw(const float* __restrict__ Ew, const float* __restrict__ Eu,
                const float* __restrict__ V, float* __restrict__ part)
{
    __shared__ float Ws_s[32][64];   // [t][h-chunk], col4 ^= (row>>2)&7
    __shared__ float Uh_s[32][64];   // [d][h-chunk], col4 ^= row&7
    __shared__ float Vr_s[HE];       // -2*V

    const int tid = threadIdx.x;
    const int tg  = tid & 7;     // t-group: t = tt0 + tg*4 + i
    const int dg  = tid >> 3;    // d = d0 + dg   (0..31)

    const int tt0  = blockIdx.x * 32;
    const int quar = blockIdx.y & 3;
    const int d0   = (blockIdx.y >> 2) * 32;
    const int b    = blockIdx.z;

    const float* Wsg = Ew + (long long)b * TE * HE;
    const float* Uhg = Eu + ((long long)b * TD + d0) * HE;

    if (tid < 128) {
        const float4 v = *(const float4*)&V[tid * 4];
        float4 o; o.x = -2.f * v.x; o.y = -2.f * v.y; o.z = -2.f * v.z; o.w = -2.f * v.w;
        *(float4*)&Vr_s[tid * 4] = o;
    }

    float acc[4] = {0.f, 0.f, 0.f, 0.f};
    const int wswz = tg & 7;
    const int uswz = dg & 7;
    const int hbase = quar * (HE / 4);

    for (int hc = hbase; hc < hbase + HE / 4; hc += 64) {
        __syncthreads();
#pragma unroll
        for (int k = 0; k < 2; ++k) {
            const int idx = tid + k * 256;
            const int r   = idx >> 4;
            const int c4  = idx & 15;
            const float4 wv = *(const float4*)&Wsg[(long long)(tt0 + r) * HE + hc + c4 * 4];
            *(float4*)&Ws_s[r][(c4 ^ ((r >> 2) & 7)) * 4] = wv;
            const float4 uv = *(const float4*)&Uhg[(long long)r * HE + hc + c4 * 4];
            *(float4*)&Uh_s[r][(c4 ^ (r & 7)) * 4] = uv;
        }
        __syncthreads();

#pragma unroll 4
        for (int hs = 0; hs < 64; hs += 4) {
            const int h4 = hs >> 2;
            const float4 vv = *(const float4*)&Vr_s[hc + hs];
            const float4 u  = *(const float4*)&Uh_s[dg][(h4 ^ uswz) * 4];
#pragma unroll
            for (int i = 0; i < 4; ++i) {
                const float4 w = *(const float4*)&Ws_s[tg * 4 + i][(h4 ^ wswz) * 4];
                acc[i] = fmaf(vv.x, frcp(fmaf(w.x, u.x, 1.f)), acc[i]);
                acc[i] = fmaf(vv.y, frcp(fmaf(w.y, u.y, 1.f)), acc[i]);
                acc[i] = fmaf(vv.z, frcp(fmaf(w.z, u.z, 1.f)), acc[i]);
                acc[i] = fmaf(vv.w, frcp(fmaf(w.w, u.w, 1.f)), acc[i]);
            }
        }
    }

    float* dst = part + (size_t)quar * (BB * TD * TE);
    float4 o; o.x = acc[0]; o.y = acc[1]; o.z = acc[2]; o.w = acc[3];
    *(float4*)&dst[((long long)b * TD + d0 + dg) * TE + tt0 + tg * 4] = o;
}

// ---------------------------------------------------------------------------
// Row softmax over 4 summed partials -> e (fp32) + optional A-k8 bf16 split
// ---------------------------------------------------------------------------
__global__ __launch_bounds__(256)
void softmax_rows(const float* __restrict__ part, float* __restrict__ e,
                  unsigned short* __restrict__ H, unsigned short* __restrict__ L)
{
    const int lane = threadIdx.x & 63;
    const int wave = threadIdx.x >> 6;
    const long long row = blockIdx.x * 4 + wave;

    float4 a = {0.f, 0.f, 0.f, 0.f}, c = {0.f, 0.f, 0.f, 0.f};
#pragma unroll
    for (int q = 0; q < 4; ++q) {
        const float* p = part + (size_t)q * (BB * TD * TE) + row * TE;
        const float4 aq = *(const float4*)&p[lane * 4];
        const float4 cq = *(const float4*)&p[lane * 4 + 256];
        a.x += aq.x; a.y += aq.y; a.z += aq.z; a.w += aq.w;
        c.x += cq.x; c.y += cq.y; c.z += cq.z; c.w += cq.w;
    }

    float m = fmaxf(fmaxf(fmaxf(a.x, a.y), fmaxf(a.z, a.w)),
                    fmaxf(fmaxf(c.x, c.y), fmaxf(c.z, c.w)));
#pragma unroll
    for (int off = 32; off; off >>= 1) m = fmaxf(m, __shfl_xor(m, off));

    a.x = __expf(a.x - m); a.y = __expf(a.y - m); a.z = __expf(a.z - m); a.w = __expf(a.w - m);
    c.x = __expf(c.x - m); c.y = __expf(c.y - m); c.z = __expf(c.z - m); c.w = __expf(c.w - m);

    float s = (a.x + a.y + a.z + a.w) + (c.x + c.y + c.z + c.w);
#pragma unroll
    for (int off = 32; off; off >>= 1) s += __shfl_xor(s, off);

    const float inv = __fdividef(1.f, s);
    a.x *= inv; a.y *= inv; a.z *= inv; a.w *= inv;
    c.x *= inv; c.y *= inv; c.z *= inv; c.w *= inv;
    float* pe = e + row * TE;
    *(float4*)&pe[lane * 4] = a;
    *(float4*)&pe[lane * 4 + 256] = c;

    if (H) {
        const int b = (int)(row >> 6);
        const int d = (int)(row & 63);
        const size_t base = (size_t)b * (TD * TE);
        ushort4 h, l;
        {
            const int t0 = lane * 4;
            const size_t o = base + ((size_t)(t0 >> 3) * TD + d) * 8 + (t0 & 7);
            split2(a.x, h.x, l.x); split2(a.y, h.y, l.y);
            split2(a.z, h.z, l.z); split2(a.w, h.w, l.w);
            *(ushort4*)&H[o] = h;
            *(ushort4*)&L[o] = l;
        }
        {
            const int t0 = lane * 4 + 256;
            const size_t o = base + ((size_t)(t0 >> 3) * TD + d) * 8 + (t0 & 7);
            split2(c.x, h.x, l.x); split2(c.y, h.y, l.y);
            split2(c.z, h.z, l.z); split2(c.w, h.w, l.w);
            *(ushort4*)&H[o] = h;
            *(ushort4*)&L[o] = l;
        }
    }
}

// ---------------------------------------------------------------------------
extern "C" void kernel_launch(void* const* d_in, const int* in_sizes, int n_in,
                              void* d_out, int out_size, void* d_ws, size_t ws_size,
                              hipStream_t stream)
{
    const float* enc = (const float*)d_in[0];  // [B,TE,HE]
    const float* dec = (const float*)d_in[1];  // [B,TD,HD=HE]
    const float* Wa  = (const float*)d_in[2];  // [HE,HE]
    const float* Ua  = (const float*)d_in[3];  // [HD,HE]
    const float* Va  = (const float*)d_in[4];  // [HE,1] -> flat [HE]

    float* out   = (float*)d_out;
    float* c_out = out;                        // [B,TD,HE]
    float* e_out = out + (size_t)BB * TD * HE; // [B,TD,TE]

    char* w = (char*)d_ws;
    float* Ew  = (float*)(w);                                  // 16,777,216 B (exp2'd Ws)
    float* Eu  = (float*)(w + 16777216);                       //  2,097,152 B (exp2'd Uh)
    unsigned short* encAh = (unsigned short*)(w + 18874368);   //  8,388,608 B  (A-k8)
    unsigned short* encAl = (unsigned short*)(w + 27262976);
    unsigned short* encTh = (unsigned short*)(w + 35651584);   //  (B-k8 per batch)
    unsigned short* encTl = (unsigned short*)(w + 44040192);
    unsigned short* decAh = (unsigned short*)(w + 52428800);   //  1,048,576 B
    unsigned short* decAl = (unsigned short*)(w + 53477376);
    unsigned short* WaTh  = (unsigned short*)(w + 54525952);   //    524,288 B
    unsigned short* WaTl  = (unsigned short*)(w + 55050240);
    unsigned short* UaTh  = (unsigned short*)(w + 55574528);
    unsigned short* UaTl  = (unsigned short*)(w + 56098816);
    unsigned short* eh    = (unsigned short*)(w + 56623104);   //  1,048,576 B (A-k8/batch)
    unsigned short* el    = (unsigned short*)(w + 57671680);
    float* part = (float*)(w + 58720256);                      //  8,388,608 B (4 x 2 MB)
    const size_t REQUIRED = 67108864;

    dim3 blk(256);

    if (ws_size >= REQUIRED) {
        // --- split/transpose conversions (k8, coalesced 1KB wave-writes) ---
        split_enc_k8<<<dim3(HE / 64, TE / 64, BB), blk, 0, stream>>>(
            enc, encAh, encAl, encTh, encTl);
        split_misc_k8<<<dim3(8, 16, 3), blk, 0, stream>>>(
            dec, decAh, decAl, Wa, WaTh, WaTl, Ua, UaTh, UaTl);

        // Ew = exp2(PRESCALE * enc @ W_a) and Eu = exp2(PRESCALE * dec @ U_a)
        gemm_ws_uh<<<dim3(4, 72, 1), blk, 0, stream>>>(
            encAh, encAl, WaTh, WaTl, Ew, decAh, decAl, UaTh, UaTl, Eu);

        // raw score partials (h-split x4): grid y = d-tile*4 + quarter
        scores_raw<<<dim3(TE / 32, (TD / 32) * 4, BB), blk, 0, stream>>>(Ew, Eu, Va, part);
        softmax_rows<<<dim3(BB * TD / 4), blk, 0, stream>>>(part, e_out, eh, el);

        // c[b] = e[b] @ enc[b]   (M=64 valid of 128-tile, batched)
        gemm_mfma3<<<dim3(4, 1, BB), blk, 0, stream>>>(
            eh, el, encTh, encTl, c_out, TD, HE, TE,
            (long long)TD * TE, (long long)TE * HE, (long long)TD * HE);
    } else {
        // --- fallback: fp32 path (partials after Eu; needs ~27 MB) ---
        float* pf = (float*)(w + 18874368);
        gemm_f32<<<dim3(HE / 64, (BB * TE) / 64, 1), blk, 0, stream>>>(
            enc, Wa, Ew, BB * TE, HE, HE, 0, 0, 0, PRESCALE, 1);
        gemm_f32<<<dim3(HE / 64, (BB * TD) / 64, 1), blk, 0, stream>>>(
            dec, Ua, Eu, BB * TD, HE, HE, 0, 0, 0, PRESCALE, 1);
        scores_raw<<<dim3(TE / 32, (TD / 32) * 4, BB), blk, 0, stream>>>(Ew, Eu, Va, pf);
        softmax_rows<<<dim3(BB * TD / 4), blk, 0, stream>>>(pf, e_out, nullptr, nullptr);
        gemm_f32<<<dim3(HE / 64, TD / 64, BB), blk, 0, stream>>>(
            e_out, enc, c_out, TD, HE, TE,
            (long long)TD * TE, (long long)TE * HE, (long long)TD * HE, 1.0f, 0);
    }
}

// Round 14
// 90.627 us; speedup vs baseline: 3.4754x; 1.0008x over previous
//
#include <hip/hip_runtime.h>
#include <hip/hip_bf16.h>

#define BB 16
#define TE 512
#define TD 64
#define HE 512

// 2*log2(e): folded into Ws/Uh GEMM epilogue (with exp2) so the scores inner
// loop needs no exp at all: tanh term via 1/(Ew*Eu+1).
#define PRESCALE 2.8853900817779268f

typedef __attribute__((ext_vector_type(8))) short bf16x8;
typedef __attribute__((ext_vector_type(4))) float f32x4;

__device__ __forceinline__ float fexp2(float x) {
#if __has_builtin(__builtin_amdgcn_exp2f)
    return __builtin_amdgcn_exp2f(x);
#else
    return exp2f(x);
#endif
}
__device__ __forceinline__ float frcp(float x) {
#if __has_builtin(__builtin_amdgcn_rcpf)
    return __builtin_amdgcn_rcpf(x);
#else
    return __fdividef(1.f, x);
#endif
}

// split fp32 -> bf16 hi + bf16 lo (x ~= hi + lo, ~2^-17 relative)
__device__ __forceinline__ void split2(float x, unsigned short& h, unsigned short& l) {
    __hip_bfloat16 hb = __float2bfloat16(x);
    h = *(unsigned short*)&hb;
    float r = x - __bfloat162float(hb);
    __hip_bfloat16 lb = __float2bfloat16(r);
    l = *(unsigned short*)&lb;
}

__device__ __forceinline__ void gload16(const unsigned short* g, void* l) {
    __builtin_amdgcn_global_load_lds(
        (const __attribute__((address_space(1))) unsigned int*)g,
        (__attribute__((address_space(3))) unsigned int*)l, 16, 0, 0);
}

// ===========================================================================
// k8-interleaved operand layout:  Xp[s][r][j] = X[r][s*8+j],  s = k/8, j = k%8
// flat index = (s*R + r)*8 + j.  GEMM staging loads and split writes are
// fully coalesced (1 KB contiguous per wave op).
// ===========================================================================

// --- 64x64 fp32 tile helpers, XOR-swizzled in 16B units: logical float4-col
// c4 of row r lives at physical col (c4 ^ (r&7)). All accesses <=2-way banked.

__device__ __forceinline__ void tile_load(const float* __restrict__ src, int ld,
                                          float (*tile)[64], int tid)
{
#pragma unroll
    for (int p = 0; p < 4; ++p) {
        const int f = p * 256 + tid;
        const int r = f >> 4, c4 = f & 15;
        const float4 v = *(const float4*)&src[(size_t)r * ld + c4 * 4];
        *(float4*)&tile[r][((c4 ^ (r & 7))) << 2] = v;
    }
}

// A-k8 output: element (m_base+mm, k = 8*(sg_base+s)+j)
__device__ __forceinline__ void tile_outA(float (*tile)[64],
                                          unsigned short* __restrict__ H,
                                          unsigned short* __restrict__ L,
                                          size_t Ms, size_t sg_base, size_t m_base, int tid)
{
#pragma unroll
    for (int p = 0; p < 2; ++p) {
        const int task = p * 256 + tid;
        const int s = task >> 6, mm = task & 63;
        const float4 x = *(const float4*)&tile[mm][(((s << 1)    ) ^ (mm & 7)) << 2];
        const float4 y = *(const float4*)&tile[mm][(((s << 1) | 1) ^ (mm & 7)) << 2];
        ushort4 ha, la, hb, lb;
        split2(x.x, ha.x, la.x); split2(x.y, ha.y, la.y);
        split2(x.z, ha.z, la.z); split2(x.w, ha.w, la.w);
        split2(y.x, hb.x, lb.x); split2(y.y, hb.y, lb.y);
        split2(y.z, hb.z, lb.z); split2(y.w, hb.w, lb.w);
        const size_t o = ((sg_base + s) * Ms + m_base + mm) * 8;
        *(ushort4*)&H[o] = ha; *(ushort4*)&H[o + 4] = hb;
        *(ushort4*)&L[o] = la; *(ushort4*)&L[o + 4] = lb;
    }
}

// T-k8 output (B-k8 of tile^T): element (n_base+hh, k = 8*(sg_base+s2)+q)
__device__ __forceinline__ void tile_outT(float (*tile)[64],
                                          unsigned short* __restrict__ H,
                                          unsigned short* __restrict__ L,
                                          size_t Ns, size_t sg_base, size_t n_base, int tid)
{
#pragma unroll
    for (int p = 0; p < 2; ++p) {
        const int task = p * 256 + tid;
        const int s2 = task >> 6, hh = task & 63;
        float v[8];
#pragma unroll
        for (int q = 0; q < 8; ++q) {
            const int r = s2 * 8 + q;
            v[q] = tile[r][((((hh >> 2)) ^ (r & 7)) << 2) + (hh & 3)];
        }
        ushort4 ha, la, hb, lb;
        split2(v[0], ha.x, la.x); split2(v[1], ha.y, la.y);
        split2(v[2], ha.z, la.z); split2(v[3], ha.w, la.w);
        split2(v[4], hb.x, lb.x); split2(v[5], hb.y, lb.y);
        split2(v[6], hb.z, lb.z); split2(v[7], hb.w, lb.w);
        const size_t o = ((sg_base + s2) * Ns + n_base + hh) * 8;
        *(ushort4*)&H[o] = ha; *(ushort4*)&H[o + 4] = hb;
        *(ushort4*)&L[o] = la; *(ushort4*)&L[o + 4] = lb;
    }
}

// ---------------------------------------------------------------------------
// split_all: ALL conversions in one launch. grid (8, 16, 17):
//  z<16, y<8  -> enc batch z: A-k8 (m=b*TE+t) + per-batch B-k8 of enc^T
//  z<16, y==8 -> dec row-tile z: A-k8
//  z==16, y<8 -> Wa^T B-k8;  z==16, y>=8 -> Ua^T B-k8
// ---------------------------------------------------------------------------
__global__ __launch_bounds__(256)
void split_all(const float* __restrict__ enc,
               unsigned short* __restrict__ eAh, unsigned short* __restrict__ eAl,
               unsigned short* __restrict__ eTh, unsigned short* __restrict__ eTl,
               const float* __restrict__ dec,
               unsigned short* __restrict__ dH, unsigned short* __restrict__ dL,
               const float* __restrict__ Wa,
               unsigned short* __restrict__ wH, unsigned short* __restrict__ wL,
               const float* __restrict__ Ua,
               unsigned short* __restrict__ uH, unsigned short* __restrict__ uL)
{
    __shared__ float tile[64][64];
    const int tid = threadIdx.x;
    const int x = blockIdx.x, y = blockIdx.y, z = blockIdx.z;

    if (z < 16) {
        if (y < 8) {
            // enc batch z, tile (t0, h0)
            const int h0 = x * 64, t0 = y * 64;
            const size_t bo = (size_t)z * TE * HE;
            tile_load(enc + bo + (size_t)t0 * HE + h0, HE, tile, tid);
            __syncthreads();
            tile_outA(tile, eAh, eAl, (size_t)BB * TE, h0 >> 3, (size_t)z * TE + t0, tid);
            tile_outT(tile, eTh + bo, eTl + bo, HE, t0 >> 3, h0, tid);
        } else if (y == 8) {
            // dec row-tile z
            const int m0 = z * 64, h0 = x * 64;
            tile_load(dec + (size_t)m0 * HE + h0, HE, tile, tid);
            __syncthreads();
            tile_outA(tile, dH, dL, (size_t)BB * TD, h0 >> 3, m0, tid);
        }
        return;
    }
    // z == 16: weights
    const int yy = (y < 8) ? y : y - 8;
    const float* X = (y < 8) ? Wa : Ua;
    unsigned short* H = (y < 8) ? wH : uH;
    unsigned short* L = (y < 8) ? wL : uL;
    const int r0 = yy * 64, c0 = x * 64;
    tile_load(X + (size_t)r0 * HE + c0, HE, tile, tid);
    __syncthreads();
    tile_outT(tile, H, L, HE, r0 >> 3, c0, tid);
}

// ===========================================================================
// Split-bf16 MFMA GEMM core, tile 128(M) x 64(N), BK=32, 4 waves (2x2:
// wave covers 64 rows x 32 cols). LDS 2 x 24 KB -> 3 blocks/CU. Counted
// vmcnt(6): next buffer's 6 loads/thread stay in flight across the barrier.
// ===========================================================================
#define GEMM_BODY(AH, AL, BH, BL, CPTR, MM, NN, KK, ROW0, COL0, EPI)          \
    f32x4 acc[4][2];                                                           \
    _Pragma("unroll") for (int mi = 0; mi < 4; ++mi)                           \
        _Pragma("unroll") for (int ni = 0; ni < 2; ++ni)                       \
            acc[mi][ni] = (f32x4){0.f, 0.f, 0.f, 0.f};                         \
    auto STAGE = [&](int buf, int k0) {                                        \
        const int sg = k0 >> 3;                                                \
        _Pragma("unroll") for (int c = 0; c < 2; ++c) {                        \
            const int task = c * 256 + tid;                                    \
            const int g = task >> 7, idx = task & 127;                         \
            int mrow = (ROW0) + idx; if (mrow >= (MM)) mrow -= (MM);           \
            const size_t ao = ((size_t)(sg + g) * (MM) + mrow) * 8;            \
            gload16((AH) + ao, smem[buf] + task * 16);                         \
            gload16((AL) + ao, smem[buf] + 8192 + task * 16);                  \
        }                                                                      \
        {                                                                      \
            const int g = tid >> 6, idx = tid & 63;                            \
            const size_t bo = ((size_t)(sg + g) * (NN) + (COL0) + idx) * 8;    \
            gload16((BH) + bo, smem[buf] + 16384 + tid * 16);                  \
            gload16((BL) + bo, smem[buf] + 20480 + tid * 16);                  \
        }                                                                      \
    };                                                                         \
    STAGE(0, 0);                                                               \
    int buf = 0;                                                               \
    for (int k0 = 0; k0 < (KK); k0 += 32) {                                    \
        if (k0 + 32 < (KK)) {                                                  \
            STAGE(buf ^ 1, k0 + 32);                                           \
            asm volatile("s_waitcnt vmcnt(6)\n\ts_barrier" ::: "memory");      \
        } else {                                                               \
            asm volatile("s_waitcnt vmcnt(0)\n\ts_barrier" ::: "memory");      \
        }                                                                      \
        bf16x8 ah[4], al[4], bh[2], bl[2];                                     \
        _Pragma("unroll") for (int mi = 0; mi < 4; ++mi) {                     \
            const int off = (fg * 128 + wr * 64 + mi * 16 + fr) * 16;          \
            ah[mi] = *(const bf16x8*)(smem[buf] + off);                        \
            al[mi] = *(const bf16x8*)(smem[buf] + 8192 + off);                 \
        }                                                                      \
        _Pragma("unroll") for (int ni = 0; ni < 2; ++ni) {                     \
            const int off = (fg * 64 + wc * 32 + ni * 16 + fr) * 16;           \
            bh[ni] = *(const bf16x8*)(smem[buf] + 16384 + off);                \
            bl[ni] = *(const bf16x8*)(smem[buf] + 20480 + off);                \
        }                                                                      \
        _Pragma("unroll") for (int mi = 0; mi < 4; ++mi)                       \
            _Pragma("unroll") for (int ni = 0; ni < 2; ++ni) {                 \
                acc[mi][ni] = __builtin_amdgcn_mfma_f32_16x16x32_bf16(ah[mi], bh[ni], acc[mi][ni], 0, 0, 0); \
                acc[mi][ni] = __builtin_amdgcn_mfma_f32_16x16x32_bf16(ah[mi], bl[ni], acc[mi][ni], 0, 0, 0); \
                acc[mi][ni] = __builtin_amdgcn_mfma_f32_16x16x32_bf16(al[mi], bh[ni], acc[mi][ni], 0, 0, 0); \
            }                                                                  \
        asm volatile("s_barrier" ::: "memory");                                \
        buf ^= 1;                                                              \
    }                                                                          \
    _Pragma("unroll") for (int mi = 0; mi < 4; ++mi) {                         \
        const int rbase = (ROW0) + wr * 64 + mi * 16 + fg * 4;                 \
        _Pragma("unroll") for (int ni = 0; ni < 2; ++ni) {                     \
            const int col = (COL0) + wc * 32 + ni * 16 + fr;                   \
            _Pragma("unroll") for (int r = 0; r < 4; ++r) {                    \
                const int row = rbase + r;                                     \
                if (row < (MM)) { float val = EPI(acc[mi][ni][r]);             \
                    (CPTR)[(size_t)row * (NN) + col] = val; }                  \
            }                                                                  \
        }                                                                      \
    }

#define EPI_EXP2(v) fexp2((v) * PRESCALE)
#define EPI_ID(v)   (v)

// ---------------------------------------------------------------------------
// Merged Ws+Uh GEMM: grid (8, 72). y<64 -> Ew tile (M=8192); y>=64 -> Eu
// (M=1024). exp2(PRESCALE*.) epilogue.
// ---------------------------------------------------------------------------
__global__ __launch_bounds__(256)
void gemm_ws_uh(const unsigned short* __restrict__ eAh, const unsigned short* __restrict__ eAl,
                const unsigned short* __restrict__ wBh, const unsigned short* __restrict__ wBl,
                float* __restrict__ Ew,
                const unsigned short* __restrict__ dAh, const unsigned short* __restrict__ dAl,
                const unsigned short* __restrict__ uBh, const unsigned short* __restrict__ uBl,
                float* __restrict__ Eu)
{
    __shared__ char smem[2][24576];
    const int tid  = threadIdx.x;
    const int lane = tid & 63;
    const int wave = tid >> 6;
    const int wr = wave >> 1, wc = wave & 1;
    const int fr = lane & 15, fg = lane >> 4;

    const unsigned short *Ahi, *Alo, *Bhi, *Blo;
    float* C;
    int M, row0;
    if (blockIdx.y < 64) {
        Ahi = eAh; Alo = eAl; Bhi = wBh; Blo = wBl; C = Ew;
        M = BB * TE; row0 = blockIdx.y * 128;
    } else {
        Ahi = dAh; Alo = dAl; Bhi = uBh; Blo = uBl; C = Eu;
        M = BB * TD; row0 = (blockIdx.y - 64) * 128;
    }
    const int N = HE, K = HE;
    const int col0 = blockIdx.x * 64;

    GEMM_BODY(Ahi, Alo, Bhi, Blo, C, M, N, K, row0, col0, EPI_EXP2)
}

// ---------------------------------------------------------------------------
// Batched context GEMM: c[b] = e[b] @ enc[b]. grid (8, 1, 16), M=64 of 128.
// ---------------------------------------------------------------------------
__global__ __launch_bounds__(256)
void gemm_ctx(const unsigned short* __restrict__ Ahi_, const unsigned short* __restrict__ Alo_,
              const unsigned short* __restrict__ Bhi_, const unsigned short* __restrict__ Blo_,
              float* __restrict__ C_, int M, int N, int K,
              long long sA, long long sB, long long sC)
{
    __shared__ char smem[2][24576];
    const int tid  = threadIdx.x;
    const int lane = tid & 63;
    const int wave = tid >> 6;
    const int wr = wave >> 1, wc = wave & 1;
    const int fr = lane & 15, fg = lane >> 4;
    const int row0 = blockIdx.y * 128;
    const int col0 = blockIdx.x * 64;

    const unsigned short* Ahi = Ahi_ + (size_t)blockIdx.z * sA;
    const unsigned short* Alo = Alo_ + (size_t)blockIdx.z * sA;
    const unsigned short* Bhi = Bhi_ + (size_t)blockIdx.z * sB;
    const unsigned short* Blo = Blo_ + (size_t)blockIdx.z * sB;
    float* C = C_ + (size_t)blockIdx.z * sC;

    GEMM_BODY(Ahi, Alo, Bhi, Blo, C, M, N, K, row0, col0, EPI_ID)
}

// ---------------------------------------------------------------------------
// Fallback fp32 GEMM (used if ws_size is too small)
// ---------------------------------------------------------------------------
__global__ __launch_bounds__(256)
void gemm_f32(const float* __restrict__ A, const float* __restrict__ Bm,
              float* __restrict__ C, int M, int N, int K,
              long long sAb, long long sBb, long long sCb, float scale, int emode)
{
    __shared__ float As[16][68];
    __shared__ float Bs[16][68];

    const int tid = threadIdx.x;
    const int tx  = tid & 15;
    const int ty  = tid >> 4;
    const int row0 = blockIdx.y * 64;
    const int col0 = blockIdx.x * 64;

    A  += (long long)blockIdx.z * sAb;
    Bm += (long long)blockIdx.z * sBb;
    C  += (long long)blockIdx.z * sCb;

    float acc[4][4] = {};

    for (int k0 = 0; k0 < K; k0 += 16) {
        {
            const int r = tid >> 2;
            const int c = (tid & 3) * 4;
            const float4 av = *(const float4*)&A[(long long)(row0 + r) * K + k0 + c];
            As[c + 0][r] = av.x; As[c + 1][r] = av.y;
            As[c + 2][r] = av.z; As[c + 3][r] = av.w;
        }
        {
            const int r = tid >> 4;
            const int c = (tid & 15) * 4;
            *(float4*)&Bs[r][c] = *(const float4*)&Bm[(long long)(k0 + r) * N + col0 + c];
        }
        __syncthreads();

#pragma unroll
        for (int kk = 0; kk < 16; ++kk) {
            const float4 a = *(const float4*)&As[kk][ty * 4];
            const float4 b = *(const float4*)&Bs[kk][tx * 4];
            acc[0][0] += a.x * b.x; acc[0][1] += a.x * b.y; acc[0][2] += a.x * b.z; acc[0][3] += a.x * b.w;
            acc[1][0] += a.y * b.x; acc[1][1] += a.y * b.y; acc[1][2] += a.y * b.z; acc[1][3] += a.y * b.w;
            acc[2][0] += a.z * b.x; acc[2][1] += a.z * b.y; acc[2][2] += a.z * b.z; acc[2][3] += a.z * b.w;
            acc[3][0] += a.w * b.x; acc[3][1] += a.w * b.y; acc[3][2] += a.w * b.z; acc[3][3] += a.w * b.w;
        }
        __syncthreads();
    }

#pragma unroll
    for (int i = 0; i < 4; ++i) {
        float4 o;
        o.x = acc[i][0] * scale; o.y = acc[i][1] * scale;
        o.z = acc[i][2] * scale; o.w = acc[i][3] * scale;
        if (emode) { o.x = fexp2(o.x); o.y = fexp2(o.y); o.z = fexp2(o.z); o.w = fexp2(o.w); }
        *(float4*)&C[(long long)(row0 + ty * 4 + i) * N + col0 + tx * 4] = o;
    }
}

// ---------------------------------------------------------------------------
// Raw score PARTIALS over an h-quarter (proven structure, 8 blk/CU)
// ---------------------------------------------------------------------------
__global__ __launch_bounds__(256)
void scores_raw(const float* __restrict__ Ew, const float* __restrict__ Eu,
                const float* __restrict__ V, float* __restrict__ part)
{
    __shared__ float Ws_s[32][64];   // [t][h-chunk], col4 ^= (row>>2)&7
    __shared__ float Uh_s[32][64];   // [d][h-chunk], col4 ^= row&7
    __shared__ float Vr_s[HE];       // -2*V

    const int tid = threadIdx.x;
    const int tg  = tid & 7;     // t-group: t = tt0 + tg*4 + i
    const int dg  = tid >> 3;    // d = d0 + dg   (0..31)

    const int tt0  = blockIdx.x * 32;
    const int quar = blockIdx.y & 3;
    const int d0   = (blockIdx.y >> 2) * 32;
    const int b    = blockIdx.z;

    const float* Wsg = Ew + (long long)b * TE * HE;
    const float* Uhg = Eu + ((long long)b * TD + d0) * HE;

    if (tid < 128) {
        const float4 v = *(const float4*)&V[tid * 4];
        float4 o; o.x = -2.f * v.x; o.y = -2.f * v.y; o.z = -2.f * v.z; o.w = -2.f * v.w;
        *(float4*)&Vr_s[tid * 4] = o;
    }

    float acc[4] = {0.f, 0.f, 0.f, 0.f};
    const int wswz = tg & 7;
    const int uswz = dg & 7;
    const int hbase = quar * (HE / 4);

    for (int hc = hbase; hc < hbase + HE / 4; hc += 64) {
        __syncthreads();
#pragma unroll
        for (int k = 0; k < 2; ++k) {
            const int idx = tid + k * 256;
            const int r   = idx >> 4;
            const int c4  = idx & 15;
            const float4 wv = *(const float4*)&Wsg[(long long)(tt0 + r) * HE + hc + c4 * 4];
            *(float4*)&Ws_s[r][(c4 ^ ((r >> 2) & 7)) * 4] = wv;
            const float4 uv = *(const float4*)&Uhg[(long long)r * HE + hc + c4 * 4];
            *(float4*)&Uh_s[r][(c4 ^ (r & 7)) * 4] = uv;
        }
        __syncthreads();

#pragma unroll 4
        for (int hs = 0; hs < 64; hs += 4) {
            const int h4 = hs >> 2;
            const float4 vv = *(const float4*)&Vr_s[hc + hs];
            const float4 u  = *(const float4*)&Uh_s[dg][(h4 ^ uswz) * 4];
#pragma unroll
            for (int i = 0; i < 4; ++i) {
                const float4 w = *(const float4*)&Ws_s[tg * 4 + i][(h4 ^ wswz) * 4];
                acc[i] = fmaf(vv.x, frcp(fmaf(w.x, u.x, 1.f)), acc[i]);
                acc[i] = fmaf(vv.y, frcp(fmaf(w.y, u.y, 1.f)), acc[i]);
                acc[i] = fmaf(vv.z, frcp(fmaf(w.z, u.z, 1.f)), acc[i]);
                acc[i] = fmaf(vv.w, frcp(fmaf(w.w, u.w, 1.f)), acc[i]);
            }
        }
    }

    float* dst = part + (size_t)quar * (BB * TD * TE);
    float4 o; o.x = acc[0]; o.y = acc[1]; o.z = acc[2]; o.w = acc[3];
    *(float4*)&dst[((long long)b * TD + d0 + dg) * TE + tt0 + tg * 4] = o;
}

// ---------------------------------------------------------------------------
// Row softmax over 4 summed partials -> e (fp32) + optional A-k8 bf16 split
// ---------------------------------------------------------------------------
__global__ __launch_bounds__(256)
void softmax_rows(const float* __restrict__ part, float* __restrict__ e,
                  unsigned short* __restrict__ H, unsigned short* __restrict__ L)
{
    const int lane = threadIdx.x & 63;
    const int wave = threadIdx.x >> 6;
    const long long row = blockIdx.x * 4 + wave;

    float4 a = {0.f, 0.f, 0.f, 0.f}, c = {0.f, 0.f, 0.f, 0.f};
#pragma unroll
    for (int q = 0; q < 4; ++q) {
        const float* p = part + (size_t)q * (BB * TD * TE) + row * TE;
        const float4 aq = *(const float4*)&p[lane * 4];
        const float4 cq = *(const float4*)&p[lane * 4 + 256];
        a.x += aq.x; a.y += aq.y; a.z += aq.z; a.w += aq.w;
        c.x += cq.x; c.y += cq.y; c.z += cq.z; c.w += cq.w;
    }

    float m = fmaxf(fmaxf(fmaxf(a.x, a.y), fmaxf(a.z, a.w)),
                    fmaxf(fmaxf(c.x, c.y), fmaxf(c.z, c.w)));
#pragma unroll
    for (int off = 32; off; off >>= 1) m = fmaxf(m, __shfl_xor(m, off));

    a.x = __expf(a.x - m); a.y = __expf(a.y - m); a.z = __expf(a.z - m); a.w = __expf(a.w - m);
    c.x = __expf(c.x - m); c.y = __expf(c.y - m); c.z = __expf(c.z - m); c.w = __expf(c.w - m);

    float s = (a.x + a.y + a.z + a.w) + (c.x + c.y + c.z + c.w);
#pragma unroll
    for (int off = 32; off; off >>= 1) s += __shfl_xor(s, off);

    const float inv = __fdividef(1.f, s);
    a.x *= inv; a.y *= inv; a.z *= inv; a.w *= inv;
    c.x *= inv; c.y *= inv; c.z *= inv; c.w *= inv;
    float* pe = e + row * TE;
    *(float4*)&pe[lane * 4] = a;
    *(float4*)&pe[lane * 4 + 256] = c;

    if (H) {
        const int b = (int)(row >> 6);
        const int d = (int)(row & 63);
        const size_t base = (size_t)b * (TD * TE);
        ushort4 h, l;
        {
            const int t0 = lane * 4;
            const size_t o = base + ((size_t)(t0 >> 3) * TD + d) * 8 + (t0 & 7);
            split2(a.x, h.x, l.x); split2(a.y, h.y, l.y);
            split2(a.z, h.z, l.z); split2(a.w, h.w, l.w);
            *(ushort4*)&H[o] = h;
            *(ushort4*)&L[o] = l;
        }
        {
            const int t0 = lane * 4 + 256;
            const size_t o = base + ((size_t)(t0 >> 3) * TD + d) * 8 + (t0 & 7);
            split2(c.x, h.x, l.x); split2(c.y, h.y, l.y);
            split2(c.z, h.z, l.z); split2(c.w, h.w, l.w);
            *(ushort4*)&H[o] = h;
            *(ushort4*)&L[o] = l;
        }
    }
}

// ---------------------------------------------------------------------------
extern "C" void kernel_launch(void* const* d_in, const int* in_sizes, int n_in,
                              void* d_out, int out_size, void* d_ws, size_t ws_size,
                              hipStream_t stream)
{
    const float* enc = (const float*)d_in[0];  // [B,TE,HE]
    const float* dec = (const float*)d_in[1];  // [B,TD,HD=HE]
    const float* Wa  = (const float*)d_in[2];  // [HE,HE]
    const float* Ua  = (const float*)d_in[3];  // [HD,HE]
    const float* Va  = (const float*)d_in[4];  // [HE,1] -> flat [HE]

    float* out   = (float*)d_out;
    float* c_out = out;                        // [B,TD,HE]
    float* e_out = out + (size_t)BB * TD * HE; // [B,TD,TE]

    char* w = (char*)d_ws;
    float* Ew  = (float*)(w);                                  // 16,777,216 B (exp2'd Ws)
    float* Eu  = (float*)(w + 16777216);                       //  2,097,152 B (exp2'd Uh)
    unsigned short* encAh = (unsigned short*)(w + 18874368);   //  8,388,608 B  (A-k8)
    unsigned short* encAl = (unsigned short*)(w + 27262976);
    unsigned short* encTh = (unsigned short*)(w + 35651584);   //  (B-k8 per batch)
    unsigned short* encTl = (unsigned short*)(w + 44040192);
    unsigned short* decAh = (unsigned short*)(w + 52428800);   //  1,048,576 B
    unsigned short* decAl = (unsigned short*)(w + 53477376);
    unsigned short* WaTh  = (unsigned short*)(w + 54525952);   //    524,288 B
    unsigned short* WaTl  = (unsigned short*)(w + 55050240);
    unsigned short* UaTh  = (unsigned short*)(w + 55574528);
    unsigned short* UaTl  = (unsigned short*)(w + 56098816);
    unsigned short* eh    = (unsigned short*)(w + 56623104);   //  1,048,576 B (A-k8/batch)
    unsigned short* el    = (unsigned short*)(w + 57671680);
    float* part = (float*)(w + 58720256);                      //  8,388,608 B (4 x 2 MB)
    const size_t REQUIRED = 67108864;

    dim3 blk(256);

    if (ws_size >= REQUIRED) {
        // --- ALL conversions in one launch ---
        split_all<<<dim3(8, 16, 17), blk, 0, stream>>>(
            enc, encAh, encAl, encTh, encTl,
            dec, decAh, decAl, Wa, WaTh, WaTl, Ua, UaTh, UaTl);

        // Ew = exp2(PRESCALE * enc @ W_a), Eu = exp2(PRESCALE * dec @ U_a)
        // tile 128x64 -> 576 blocks (2.25/CU at 48 KB LDS, 3/CU cap)
        gemm_ws_uh<<<dim3(8, 72, 1), blk, 0, stream>>>(
            encAh, encAl, WaTh, WaTl, Ew, decAh, decAl, UaTh, UaTl, Eu);

        // raw score partials (h-split x4)
        scores_raw<<<dim3(TE / 32, (TD / 32) * 4, BB), blk, 0, stream>>>(Ew, Eu, Va, part);
        softmax_rows<<<dim3(BB * TD / 4), blk, 0, stream>>>(part, e_out, eh, el);

        // c[b] = e[b] @ enc[b]   (M=64 of 128-tile, 128 blocks)
        gemm_ctx<<<dim3(8, 1, BB), blk, 0, stream>>>(
            eh, el, encTh, encTl, c_out, TD, HE, TE,
            (long long)TD * TE, (long long)TE * HE, (long long)TD * HE);
    } else {
        // --- fallback: fp32 path (partials after Eu; needs ~27 MB) ---
        float* pf = (float*)(w + 18874368);
        gemm_f32<<<dim3(HE / 64, (BB * TE) / 64, 1), blk, 0, stream>>>(
            enc, Wa, Ew, BB * TE, HE, HE, 0, 0, 0, PRESCALE, 1);
        gemm_f32<<<dim3(HE / 64, (BB * TD) / 64, 1), blk, 0, stream>>>(
            dec, Ua, Eu, BB * TD, HE, HE, 0, 0, 0, PRESCALE, 1);
        scores_raw<<<dim3(TE / 32, (TD / 32) * 4, BB), blk, 0, stream>>>(Ew, Eu, Va, pf);
        softmax_rows<<<dim3(BB * TD / 4), blk, 0, stream>>>(pf, e_out, nullptr, nullptr);
        gemm_f32<<<dim3(HE / 64, TD / 64, BB), blk, 0, stream>>>(
            e_out, enc, c_out, TD, HE, TE,
            (long long)TD * TE, (long long)TE * HE, (long long)TD * HE, 1.0f, 0);
    }
}